// Round 1
// baseline (1829.893 us; speedup 1.0000x reference)
//
#include <hip/hip_runtime.h>
#include <hip/hip_bf16.h>
#include <cfloat>
#include <math.h>

#define BB 64
#define NN 1024
#define KNN 20
#define MM 256
#define CC 64
#define HH 512
#define NCLS 40
#define EPSF 1e-5f
#define CNT1 (BB*NN*KNN)

// workspace offsets (in 4-byte elements)
#define IDX_OFF    0
#define MAXH2_OFF  (IDX_OFF + BB*NN*KNN)      // int idx then floats
#define FIDX_OFF   (MAXH2_OFF + BB*NN*CC)
#define Y_OFF      (FIDX_OFF + BB*MM)
#define ACC_OFF    (Y_OFF + BB*HH)            // 256 floats zeroed: sum1[64],sumsq1[64],sum2[64],sumsq2[64]
#define W2T_OFF    (ACC_OFF + 256)            // 4096 (float4-interleaved [16][64][4])
#define B2F_OFF    (W2T_OFF + CC*CC)
#define S2_OFF     (B2F_OFF + CC)
#define T2_OFF     (S2_OFF + CC)
#define S3_OFF     (T2_OFF + CC)
#define T3_OFF     (S3_OFF + HH)

// ---------------- kNN: top-20 smallest distances per point ----------------
__global__ __launch_bounds__(256) void knn_kernel(const float* __restrict__ pos,
                                                  int* __restrict__ idxg) {
  int b = blockIdx.x >> 2;
  int qc = blockIdx.x & 3;
  __shared__ float4 pj[NN];
  const float* pb = pos + (size_t)b * NN * 3;
  for (int i = threadIdx.x; i < NN; i += 256) {
    float x = pb[i*3+0], y = pb[i*3+1], z = pb[i*3+2];
    pj[i] = make_float4(x, y, z, (x*x + y*y) + z*z);
  }
  __syncthreads();
  int n = qc*256 + threadIdx.x;
  float4 pi = pj[n];
  float xi = pi.x, yi = pi.y, zi = pi.z, sqi = pi.w;
  float aD[KNN]; int aI[KNN];
#pragma unroll
  for (int t = 0; t < KNN; ++t) { aD[t] = FLT_MAX; aI[t] = 0; }
  float wd = FLT_MAX; int wi = 0, wpos = 0;
  for (int j = 0; j < NN; ++j) {
    float4 pw = pj[j];
    float d = sqi + pw.w - 2.0f*(xi*pw.x + yi*pw.y + zi*pw.z);
    if (j != n && d < wd) {
#pragma unroll
      for (int t = 0; t < KNN; ++t) if (t == wpos) { aD[t] = d; aI[t] = j; }
      wd = -FLT_MAX; wi = -1; wpos = 0;
#pragma unroll
      for (int t = 0; t < KNN; ++t) {
        bool worse = (aD[t] > wd) || (aD[t] == wd && aI[t] > wi);
        if (worse) { wd = aD[t]; wi = aI[t]; wpos = t; }
      }
    }
  }
  int* op = idxg + (size_t)(b*NN + n) * KNN;
#pragma unroll
  for (int t = 0; t < KNN; ++t) op[t] = aI[t];
}

// ---------------- FPS (bit-exact distance chain vs numpy) ----------------
__global__ __launch_bounds__(256) void fps_kernel(const float* __restrict__ pos,
                                                  int* __restrict__ fidxg) {
  int b = blockIdx.x;
  __shared__ float4 pj[NN];
  __shared__ float rv[4]; __shared__ int ri[4];
  __shared__ int curs;
  const float* pb = pos + (size_t)b * NN * 3;
  for (int i = threadIdx.x; i < NN; i += 256)
    pj[i] = make_float4(pb[i*3], pb[i*3+1], pb[i*3+2], 0.f);
  float dist[4];
#pragma unroll
  for (int q = 0; q < 4; ++q) dist[q] = 1e38f;
  if (threadIdx.x == 0) { fidxg[b*MM] = 0; curs = 0; }
  __syncthreads();
  int cur = 0;
  int lane = threadIdx.x & 63, wv = threadIdx.x >> 6;
  for (int m = 1; m < MM; ++m) {
    float4 cp = pj[cur];
    float bv = -FLT_MAX; int bi = 0x7fffffff;
#pragma unroll
    for (int q = 0; q < 4; ++q) {
      int j = threadIdx.x + q*256;
      float4 p = pj[j];
      float dx = __fsub_rn(p.x, cp.x);
      float dy = __fsub_rn(p.y, cp.y);
      float dz = __fsub_rn(p.z, cp.z);
      float dd = __fadd_rn(__fadd_rn(__fmul_rn(dx,dx), __fmul_rn(dy,dy)), __fmul_rn(dz,dz));
      float dq = fminf(dist[q], dd);
      dist[q] = dq;
      if ((dq > bv) || (dq == bv && j < bi)) { bv = dq; bi = j; }
    }
#pragma unroll
    for (int off = 32; off >= 1; off >>= 1) {
      float ov = __shfl_down(bv, off, 64);
      int   oi = __shfl_down(bi, off, 64);
      if ((ov > bv) || (ov == bv && oi < bi)) { bv = ov; bi = oi; }
    }
    if (lane == 0) { rv[wv] = bv; ri[wv] = bi; }
    __syncthreads();
    if (threadIdx.x == 0) {
      float V = rv[0]; int I = ri[0];
#pragma unroll
      for (int t = 1; t < 4; ++t)
        if ((rv[t] > V) || (rv[t] == V && ri[t] < I)) { V = rv[t]; I = ri[t]; }
      fidxg[b*MM + m] = I;
      curs = I;
    }
    __syncthreads();
    cur = curs;
  }
}

// ---------------- stats of h1 = relu(rel@w1+b1) ----------------
__global__ __launch_bounds__(256) void stats1_kernel(const float* __restrict__ pos,
    const int* __restrict__ idxg, const float* __restrict__ w1,
    const float* __restrict__ b1, float* __restrict__ acc) {
  int b = blockIdx.x >> 4;
  int nb = blockIdx.x & 15;
  __shared__ float px[NN], py[NN], pz[NN];
  __shared__ float relx[4][KNN], rely[4][KNN], relz[4][KNN];
  __shared__ float red[4][CC];
  const float* pb = pos + (size_t)b*NN*3;
  for (int i = threadIdx.x; i < NN; i += 256) {
    px[i] = pb[i*3+0]; py[i] = pb[i*3+1]; pz[i] = pb[i*3+2];
  }
  int c = threadIdx.x & 63, w = threadIdx.x >> 6;
  float w1x = w1[c*3+0], w1y = w1[c*3+1], w1z = w1[c*3+2], b1c = b1[c];
  float s = 0.f, ss = 0.f;
  __syncthreads();
  for (int it = 0; it < 16; ++it) {
    int n0 = nb*64 + it*4;
    if (threadIdx.x < 80) {
      int wv = threadIdx.x / KNN, k = threadIdx.x % KNN;
      int n = n0 + wv;
      int j = idxg[(size_t)(b*NN + n)*KNN + k];
      relx[wv][k] = px[j] - px[n];
      rely[wv][k] = py[j] - py[n];
      relz[wv][k] = pz[j] - pz[n];
    }
    __syncthreads();
#pragma unroll
    for (int k = 0; k < KNN; ++k) {
      float h = fmaxf(relx[w][k]*w1x + rely[w][k]*w1y + relz[w][k]*w1z + b1c, 0.f);
      s += h; ss += h*h;
    }
    __syncthreads();
  }
  red[w][c] = s; __syncthreads();
  if (w == 0) atomicAdd(&acc[c], red[0][c]+red[1][c]+red[2][c]+red[3][c]);
  __syncthreads();
  red[w][c] = ss; __syncthreads();
  if (w == 0) atomicAdd(&acc[64+c], red[0][c]+red[1][c]+red[2][c]+red[3][c]);
}

// ---------------- fold BN1 into w2 ----------------
__global__ void fold1_kernel(const float* __restrict__ acc, const float* __restrict__ g1,
    const float* __restrict__ be1, const float* __restrict__ w2, const float* __restrict__ b2,
    float* __restrict__ w2t4, float* __restrict__ b2f) {
  __shared__ float s1[CC], t1[CC];
  int c = threadIdx.x;
  float cnt = (float)CNT1;
  float m = acc[c] / cnt;
  float v = acc[64+c] / cnt - m*m;
  float sc = g1[c] * rsqrtf(v + EPSF);
  s1[c] = sc; t1[c] = be1[c] - m*sc;
  __syncthreads();
  int o = c;
  float accb = b2[o];
  for (int ci = 0; ci < CC; ++ci) {
    float wv = w2[o*CC + ci];
    accb += t1[ci]*wv;
    w2t4[((ci>>2)*CC + o)*4 + (ci&3)] = wv * s1[ci];
  }
  b2f[o] = accb;
}

// ---------------- conv2: h2 = relu(h1@w2'+b2'), maxh2 + stats ----------------
__global__ __launch_bounds__(256) void conv2_kernel(const float* __restrict__ pos,
    const int* __restrict__ idxg, const float* __restrict__ w1, const float* __restrict__ b1,
    const float* __restrict__ w2t4g, const float* __restrict__ b2fg,
    float* __restrict__ maxh2, float* __restrict__ acc2) {
  int b = blockIdx.x >> 4;
  int nb = blockIdx.x & 15;
  __shared__ float px[NN], py[NN], pz[NN];
  __shared__ float relx[4][KNN], rely[4][KNN], relz[4][KNN];
  __shared__ __align__(16) float h1s[4][KNN][CC];
  __shared__ float4 w2s[16*CC];
  __shared__ float red[4][CC];
  const float* pb = pos + (size_t)b*NN*3;
  for (int i = threadIdx.x; i < NN; i += 256) {
    px[i] = pb[i*3+0]; py[i] = pb[i*3+1]; pz[i] = pb[i*3+2];
  }
  for (int i = threadIdx.x; i < 16*CC; i += 256) w2s[i] = ((const float4*)w2t4g)[i];
  int c = threadIdx.x & 63, w = threadIdx.x >> 6;
  float w1x = w1[c*3+0], w1y = w1[c*3+1], w1z = w1[c*3+2], b1c = b1[c];
  float b2o = b2fg[c];
  float s2a = 0.f, ss2a = 0.f;
  __syncthreads();
  for (int it = 0; it < 16; ++it) {
    int n0 = nb*64 + it*4;
    if (threadIdx.x < 80) {
      int wv = threadIdx.x / KNN, k = threadIdx.x % KNN;
      int n = n0 + wv;
      int j = idxg[(size_t)(b*NN + n)*KNN + k];
      relx[wv][k] = px[j] - px[n];
      rely[wv][k] = py[j] - py[n];
      relz[wv][k] = pz[j] - pz[n];
    }
    __syncthreads();
#pragma unroll
    for (int k = 0; k < KNN; ++k)
      h1s[w][k][c] = fmaxf(relx[w][k]*w1x + rely[w][k]*w1y + relz[w][k]*w1z + b1c, 0.f);
    __syncthreads();
    float acck[KNN];
#pragma unroll
    for (int k = 0; k < KNN; ++k) acck[k] = b2o;
    for (int cq = 0; cq < 16; ++cq) {
      float4 wv4 = w2s[cq*CC + c];
#pragma unroll
      for (int k = 0; k < KNN; ++k) {
        float4 hv = *((const float4*)&h1s[w][k][cq*4]);
        acck[k] = fmaf(hv.x, wv4.x, acck[k]);
        acck[k] = fmaf(hv.y, wv4.y, acck[k]);
        acck[k] = fmaf(hv.z, wv4.z, acck[k]);
        acck[k] = fmaf(hv.w, wv4.w, acck[k]);
      }
    }
    float mx = 0.f;
#pragma unroll
    for (int k = 0; k < KNN; ++k) {
      float h2 = fmaxf(acck[k], 0.f);
      s2a += h2; ss2a += h2*h2;
      mx = fmaxf(mx, h2);
    }
    int n = n0 + w;
    maxh2[(size_t)(b*NN + n)*CC + c] = mx;
    __syncthreads();
  }
  red[w][c] = s2a; __syncthreads();
  if (w == 0) atomicAdd(&acc2[c], red[0][c]+red[1][c]+red[2][c]+red[3][c]);
  __syncthreads();
  red[w][c] = ss2a; __syncthreads();
  if (w == 0) atomicAdd(&acc2[64+c], red[0][c]+red[1][c]+red[2][c]+red[3][c]);
}

// ---------------- finalize BN2 affine ----------------
__global__ void fold2_kernel(const float* __restrict__ acc2, const float* __restrict__ g2,
    const float* __restrict__ be2, float* __restrict__ s2, float* __restrict__ t2) {
  int c = threadIdx.x;
  float cnt = (float)CNT1;
  float m = acc2[c]/cnt;
  float v = acc2[64+c]/cnt - m*m;
  float sc = g2[c]*rsqrtf(v+EPSF);
  s2[c] = sc;
  t2[c] = be2[c] - m*sc;
}

// ---------------- head: Y[b,h] = relu(max_m(f@w_nn1^T)+b) ----------------
__global__ __launch_bounds__(256) void head_kernel(const float* __restrict__ maxh2,
    const int* __restrict__ fidxg, const float* __restrict__ s2g, const float* __restrict__ t2g,
    const float* __restrict__ wnn1, const float* __restrict__ bnn1, float* __restrict__ Y) {
  int b = blockIdx.x >> 2;
  int hc = blockIdx.x & 3;
  __shared__ __align__(16) float ftile[128][CC];
  __shared__ float red2[2][128];
  int hl = threadIdx.x & 127, mseg = threadIdx.x >> 7;
  int h = hc*128 + hl;
  float4 wv4[16];
  const float4* wr4 = (const float4*)(wnn1 + (size_t)h*CC);
#pragma unroll
  for (int q = 0; q < 16; ++q) wv4[q] = wr4[q];
  float best = -FLT_MAX;
  const int* fb = fidxg + b*MM;
  for (int chunk = 0; chunk < 2; ++chunk) {
    {
      int row = threadIdx.x & 127, chal = threadIdx.x >> 7;
      int fi = fb[chunk*128 + row];
      const float* src = maxh2 + (size_t)(b*NN + fi)*CC;
      for (int ci = chal*32; ci < chal*32+32; ++ci)
        ftile[row][ci] = s2g[ci]*src[ci] + t2g[ci];
    }
    __syncthreads();
    for (int m = mseg*64; m < mseg*64+64; ++m) {
      float acc = 0.f;
#pragma unroll
      for (int cq = 0; cq < 16; ++cq) {
        float4 f = *((const float4*)&ftile[m][cq*4]);
        acc = fmaf(f.x, wv4[cq].x, acc);
        acc = fmaf(f.y, wv4[cq].y, acc);
        acc = fmaf(f.z, wv4[cq].z, acc);
        acc = fmaf(f.w, wv4[cq].w, acc);
      }
      best = fmaxf(best, acc);
    }
    __syncthreads();
  }
  red2[mseg][hl] = best;
  __syncthreads();
  if (mseg == 0) {
    float v = fmaxf(red2[0][hl], red2[1][hl]) + bnn1[h];
    Y[(size_t)b*HH + h] = fmaxf(v, 0.f);
  }
}

// ---------------- BN over batch (two-pass) ----------------
__global__ void bn3_kernel(const float* __restrict__ Y, const float* __restrict__ g,
    const float* __restrict__ be, float* __restrict__ s3, float* __restrict__ t3) {
  int h = blockIdx.x*256 + threadIdx.x;
  float s = 0.f;
  for (int b = 0; b < BB; ++b) s += Y[(size_t)b*HH + h];
  float m = s / (float)BB;
  float v = 0.f;
  for (int b = 0; b < BB; ++b) { float d = Y[(size_t)b*HH + h] - m; v += d*d; }
  v /= (float)BB;
  float sc = g[h] * rsqrtf(v + EPSF);
  s3[h] = sc; t3[h] = be[h] - m*sc;
}

// ---------------- logits + log_softmax ----------------
__global__ __launch_bounds__(256) void logits_kernel(const float* __restrict__ Y,
    const float* __restrict__ s3, const float* __restrict__ t3,
    const float* __restrict__ w4, const float* __restrict__ b4, float* __restrict__ out) {
  int b = blockIdx.x;
  __shared__ float ybn[HH];
  __shared__ float lg[NCLS];
  __shared__ float lse;
  for (int hh = threadIdx.x; hh < HH; hh += 256)
    ybn[hh] = Y[(size_t)b*HH + hh]*s3[hh] + t3[hh];
  __syncthreads();
  if (threadIdx.x < NCLS) {
    int j = threadIdx.x;
    float acc = b4[j];
    const float* wr = w4 + (size_t)j*HH;
    for (int ci = 0; ci < HH; ++ci) acc = fmaf(ybn[ci], wr[ci], acc);
    lg[j] = acc;
  }
  __syncthreads();
  if (threadIdx.x == 0) {
    float mx = -FLT_MAX;
    for (int j = 0; j < NCLS; ++j) mx = fmaxf(mx, lg[j]);
    float s = 0.f;
    for (int j = 0; j < NCLS; ++j) s += expf(lg[j] - mx);
    lse = mx + logf(s);
  }
  __syncthreads();
  if (threadIdx.x < NCLS) out[b*NCLS + threadIdx.x] = lg[threadIdx.x] - lse;
}

extern "C" void kernel_launch(void* const* d_in, const int* in_sizes, int n_in,
                              void* d_out, int out_size, void* d_ws, size_t ws_size,
                              hipStream_t stream) {
  const float* pos  = (const float*)d_in[0];
  const float* w1   = (const float*)d_in[1];
  const float* b1   = (const float*)d_in[2];
  const float* g1   = (const float*)d_in[3];
  const float* be1  = (const float*)d_in[4];
  const float* w2   = (const float*)d_in[5];
  const float* b2   = (const float*)d_in[6];
  const float* g2   = (const float*)d_in[7];
  const float* be2  = (const float*)d_in[8];
  const float* wnn1 = (const float*)d_in[9];
  const float* bnn1 = (const float*)d_in[10];
  const float* gbn2 = (const float*)d_in[11];
  const float* bebn2= (const float*)d_in[12];
  const float* wnn4 = (const float*)d_in[13];
  const float* bnn4 = (const float*)d_in[14];
  float* ws = (float*)d_ws;
  int*   idxg  = (int*)(ws + IDX_OFF);
  float* maxh2 = ws + MAXH2_OFF;
  int*   fidxg = (int*)(ws + FIDX_OFF);
  float* Y     = ws + Y_OFF;
  float* acc1  = ws + ACC_OFF;
  float* acc2  = ws + ACC_OFF + 128;
  float* w2t4  = ws + W2T_OFF;
  float* b2f   = ws + B2F_OFF;
  float* s2    = ws + S2_OFF;
  float* t2    = ws + T2_OFF;
  float* s3    = ws + S3_OFF;
  float* t3    = ws + T3_OFF;
  float* outp  = (float*)d_out;

  hipMemsetAsync((void*)(ws + ACC_OFF), 0, 256*sizeof(float), stream);
  knn_kernel<<<BB*4, 256, 0, stream>>>(pos, idxg);
  fps_kernel<<<BB, 256, 0, stream>>>(pos, fidxg);
  stats1_kernel<<<BB*16, 256, 0, stream>>>(pos, idxg, w1, b1, acc1);
  fold1_kernel<<<1, 64, 0, stream>>>(acc1, g1, be1, w2, b2, w2t4, b2f);
  conv2_kernel<<<BB*16, 256, 0, stream>>>(pos, idxg, w1, b1, w2t4, b2f, maxh2, acc2);
  fold2_kernel<<<1, 64, 0, stream>>>(acc2, g2, be2, s2, t2);
  head_kernel<<<BB*4, 256, 0, stream>>>(maxh2, fidxg, s2, t2, wnn1, bnn1, Y);
  bn3_kernel<<<2, 256, 0, stream>>>(Y, gbn2, bebn2, s3, t3);
  logits_kernel<<<BB, 256, 0, stream>>>(Y, s3, t3, wnn4, bnn4, outp);
}

// Round 2
// 1008.232 us; speedup vs baseline: 1.8150x; 1.8150x over previous
//
#include <hip/hip_runtime.h>
#include <hip/hip_bf16.h>
#include <cfloat>
#include <math.h>

#define BB 64
#define NN 1024
#define KNN 20
#define MM 256
#define CC 64
#define HH 512
#define NCLS 40
#define EPSF 1e-5f
#define CNT1 (BB*NN*KNN)

// workspace offsets (in 4-byte elements)
#define IDX_OFF    0
#define MAXH2_OFF  (IDX_OFF + BB*NN*KNN)      // int idx then floats
#define FIDX_OFF   (MAXH2_OFF + BB*NN*CC)
#define Y_OFF      (FIDX_OFF + BB*MM)
#define ACC_OFF    (Y_OFF + BB*HH)            // 256 floats zeroed: sum1[64],sumsq1[64],sum2[64],sumsq2[64]
#define W2T_OFF    (ACC_OFF + 256)            // 4096 (float4-interleaved [16][64][4])
#define B2F_OFF    (W2T_OFF + CC*CC)
#define S2_OFF     (B2F_OFF + CC)
#define T2_OFF     (S2_OFF + CC)
#define S3_OFF     (T2_OFF + CC)
#define T3_OFF     (S3_OFF + HH)

// ---------------- kNN: wave-cooperative radix/binary-search top-20 ----------------
// One wave per query point. Each lane holds 16 candidate distances (orderable
// uint encoding) in registers; 32 uniform rounds of binary search via
// ballot+popcount find the exact bits of the 20th-smallest; emission via
// ballot prefix sums with index-ordered tie break (lax.top_k stable ties).
__global__ __launch_bounds__(256) void knn_kernel(const float* __restrict__ pos,
                                                  int* __restrict__ idxg) {
  int b  = blockIdx.x >> 4;   // cloud
  int nb = blockIdx.x & 15;   // 64-point segment of the cloud
  __shared__ float4 pj[NN];
  const float* pb = pos + (size_t)b * NN * 3;
  for (int i = threadIdx.x; i < NN; i += 256) {
    float x = pb[i*3+0], y = pb[i*3+1], z = pb[i*3+2];
    pj[i] = make_float4(x, y, z, (x*x + y*y) + z*z);
  }
  __syncthreads();
  int lane = threadIdx.x & 63;
  int wv   = threadIdx.x >> 6;
  unsigned long long lmask_lt = (1ULL << lane) - 1ULL;

  for (int t = 0; t < 16; ++t) {
    int i = nb*64 + wv*16 + t;       // query point (wave-uniform)
    float4 pi = pj[i];               // LDS broadcast
    unsigned u[16];
#pragma unroll
    for (int q = 0; q < 16; ++q) {
      int j = q*64 + lane;
      float4 pw = pj[j];
      float d = pi.w + pw.w - 2.0f*(pi.x*pw.x + pi.y*pw.y + pi.z*pw.z);
      unsigned bits = __float_as_uint(d);
      bits = (bits & 0x80000000u) ? ~bits : (bits | 0x80000000u);
      if (j == i) bits = 0xFFFFFFFFu;   // self excluded (diag = +inf)
      u[q] = bits;
    }
    // binary search for x* = bits of 20th-smallest (smallest x with count(<=x)>=20)
    unsigned lo = 0u, hi = 0xFFFFFFFFu;
    while (lo < hi) {                   // wave-uniform, <=32 rounds
      unsigned mid = lo + ((hi - lo) >> 1);
      int cnt = 0;
#pragma unroll
      for (int q = 0; q < 16; ++q)
        cnt += (int)__popcll(__ballot(u[q] <= mid));
      if (cnt >= KNN) hi = mid; else lo = mid + 1;
    }
    unsigned xstar = lo;
    // emit: all strictly-less, then ties at x* in ascending index order
    int* op = idxg + (size_t)(b*NN + i) * KNN;
    int base = 0;
#pragma unroll
    for (int q = 0; q < 16; ++q) {
      bool pred = (u[q] < xstar);
      unsigned long long mask = __ballot((int)pred);
      if (pred) {
        int pos = base + (int)__popcll(mask & lmask_lt);
        op[pos] = q*64 + lane;
      }
      base += (int)__popcll(mask);
    }
    for (int q = 0; q < 16 && base < KNN; ++q) {  // uniform loop cond
      bool pred = (u[q] == xstar);
      unsigned long long mask = __ballot((int)pred);
      if (pred) {
        int pos = base + (int)__popcll(mask & lmask_lt);
        if (pos < KNN) op[pos] = q*64 + lane;
      }
      base += (int)__popcll(mask);
    }
  }
}

// ---------------- FPS (bit-exact distance chain vs numpy) ----------------
__global__ __launch_bounds__(256) void fps_kernel(const float* __restrict__ pos,
                                                  int* __restrict__ fidxg) {
  int b = blockIdx.x;
  __shared__ float4 pj[NN];
  __shared__ float rv[4]; __shared__ int ri[4];
  __shared__ int curs;
  const float* pb = pos + (size_t)b * NN * 3;
  for (int i = threadIdx.x; i < NN; i += 256)
    pj[i] = make_float4(pb[i*3], pb[i*3+1], pb[i*3+2], 0.f);
  float dist[4];
#pragma unroll
  for (int q = 0; q < 4; ++q) dist[q] = 1e38f;
  if (threadIdx.x == 0) { fidxg[b*MM] = 0; curs = 0; }
  __syncthreads();
  int cur = 0;
  int lane = threadIdx.x & 63, wv = threadIdx.x >> 6;
  for (int m = 1; m < MM; ++m) {
    float4 cp = pj[cur];
    float bv = -FLT_MAX; int bi = 0x7fffffff;
#pragma unroll
    for (int q = 0; q < 4; ++q) {
      int j = threadIdx.x + q*256;
      float4 p = pj[j];
      float dx = __fsub_rn(p.x, cp.x);
      float dy = __fsub_rn(p.y, cp.y);
      float dz = __fsub_rn(p.z, cp.z);
      float dd = __fadd_rn(__fadd_rn(__fmul_rn(dx,dx), __fmul_rn(dy,dy)), __fmul_rn(dz,dz));
      float dq = fminf(dist[q], dd);
      dist[q] = dq;
      if ((dq > bv) || (dq == bv && j < bi)) { bv = dq; bi = j; }
    }
#pragma unroll
    for (int off = 32; off >= 1; off >>= 1) {
      float ov = __shfl_down(bv, off, 64);
      int   oi = __shfl_down(bi, off, 64);
      if ((ov > bv) || (ov == bv && oi < bi)) { bv = ov; bi = oi; }
    }
    if (lane == 0) { rv[wv] = bv; ri[wv] = bi; }
    __syncthreads();
    if (threadIdx.x == 0) {
      float V = rv[0]; int I = ri[0];
#pragma unroll
      for (int t = 1; t < 4; ++t)
        if ((rv[t] > V) || (rv[t] == V && ri[t] < I)) { V = rv[t]; I = ri[t]; }
      fidxg[b*MM + m] = I;
      curs = I;
    }
    __syncthreads();
    cur = curs;
  }
}

// ---------------- stats of h1 = relu(rel@w1+b1) ----------------
__global__ __launch_bounds__(256) void stats1_kernel(const float* __restrict__ pos,
    const int* __restrict__ idxg, const float* __restrict__ w1,
    const float* __restrict__ b1, float* __restrict__ acc) {
  int b = blockIdx.x >> 4;
  int nb = blockIdx.x & 15;
  __shared__ float px[NN], py[NN], pz[NN];
  __shared__ float relx[4][KNN], rely[4][KNN], relz[4][KNN];
  __shared__ float red[4][CC];
  const float* pb = pos + (size_t)b*NN*3;
  for (int i = threadIdx.x; i < NN; i += 256) {
    px[i] = pb[i*3+0]; py[i] = pb[i*3+1]; pz[i] = pb[i*3+2];
  }
  int c = threadIdx.x & 63, w = threadIdx.x >> 6;
  float w1x = w1[c*3+0], w1y = w1[c*3+1], w1z = w1[c*3+2], b1c = b1[c];
  float s = 0.f, ss = 0.f;
  __syncthreads();
  for (int it = 0; it < 16; ++it) {
    int n0 = nb*64 + it*4;
    if (threadIdx.x < 80) {
      int wv = threadIdx.x / KNN, k = threadIdx.x % KNN;
      int n = n0 + wv;
      int j = idxg[(size_t)(b*NN + n)*KNN + k];
      relx[wv][k] = px[j] - px[n];
      rely[wv][k] = py[j] - py[n];
      relz[wv][k] = pz[j] - pz[n];
    }
    __syncthreads();
#pragma unroll
    for (int k = 0; k < KNN; ++k) {
      float h = fmaxf(relx[w][k]*w1x + rely[w][k]*w1y + relz[w][k]*w1z + b1c, 0.f);
      s += h; ss += h*h;
    }
    __syncthreads();
  }
  red[w][c] = s; __syncthreads();
  if (w == 0) atomicAdd(&acc[c], red[0][c]+red[1][c]+red[2][c]+red[3][c]);
  __syncthreads();
  red[w][c] = ss; __syncthreads();
  if (w == 0) atomicAdd(&acc[64+c], red[0][c]+red[1][c]+red[2][c]+red[3][c]);
}

// ---------------- fold BN1 into w2 ----------------
__global__ void fold1_kernel(const float* __restrict__ acc, const float* __restrict__ g1,
    const float* __restrict__ be1, const float* __restrict__ w2, const float* __restrict__ b2,
    float* __restrict__ w2t4, float* __restrict__ b2f) {
  __shared__ float s1[CC], t1[CC];
  int c = threadIdx.x;
  float cnt = (float)CNT1;
  float m = acc[c] / cnt;
  float v = acc[64+c] / cnt - m*m;
  float sc = g1[c] * rsqrtf(v + EPSF);
  s1[c] = sc; t1[c] = be1[c] - m*sc;
  __syncthreads();
  int o = c;
  float accb = b2[o];
  for (int ci = 0; ci < CC; ++ci) {
    float wv = w2[o*CC + ci];
    accb += t1[ci]*wv;
    w2t4[((ci>>2)*CC + o)*4 + (ci&3)] = wv * s1[ci];
  }
  b2f[o] = accb;
}

// ---------------- conv2: h2 = relu(h1@w2'+b2'), maxh2 + stats ----------------
__global__ __launch_bounds__(256) void conv2_kernel(const float* __restrict__ pos,
    const int* __restrict__ idxg, const float* __restrict__ w1, const float* __restrict__ b1,
    const float* __restrict__ w2t4g, const float* __restrict__ b2fg,
    float* __restrict__ maxh2, float* __restrict__ acc2) {
  int b = blockIdx.x >> 4;
  int nb = blockIdx.x & 15;
  __shared__ float px[NN], py[NN], pz[NN];
  __shared__ float relx[4][KNN], rely[4][KNN], relz[4][KNN];
  __shared__ __align__(16) float h1s[4][KNN][CC];
  __shared__ float4 w2s[16*CC];
  __shared__ float red[4][CC];
  const float* pb = pos + (size_t)b*NN*3;
  for (int i = threadIdx.x; i < NN; i += 256) {
    px[i] = pb[i*3+0]; py[i] = pb[i*3+1]; pz[i] = pb[i*3+2];
  }
  for (int i = threadIdx.x; i < 16*CC; i += 256) w2s[i] = ((const float4*)w2t4g)[i];
  int c = threadIdx.x & 63, w = threadIdx.x >> 6;
  float w1x = w1[c*3+0], w1y = w1[c*3+1], w1z = w1[c*3+2], b1c = b1[c];
  float b2o = b2fg[c];
  float s2a = 0.f, ss2a = 0.f;
  __syncthreads();
  for (int it = 0; it < 16; ++it) {
    int n0 = nb*64 + it*4;
    if (threadIdx.x < 80) {
      int wv = threadIdx.x / KNN, k = threadIdx.x % KNN;
      int n = n0 + wv;
      int j = idxg[(size_t)(b*NN + n)*KNN + k];
      relx[wv][k] = px[j] - px[n];
      rely[wv][k] = py[j] - py[n];
      relz[wv][k] = pz[j] - pz[n];
    }
    __syncthreads();
#pragma unroll
    for (int k = 0; k < KNN; ++k)
      h1s[w][k][c] = fmaxf(relx[w][k]*w1x + rely[w][k]*w1y + relz[w][k]*w1z + b1c, 0.f);
    __syncthreads();
    float acck[KNN];
#pragma unroll
    for (int k = 0; k < KNN; ++k) acck[k] = b2o;
    for (int cq = 0; cq < 16; ++cq) {
      float4 wv4 = w2s[cq*CC + c];
#pragma unroll
      for (int k = 0; k < KNN; ++k) {
        float4 hv = *((const float4*)&h1s[w][k][cq*4]);
        acck[k] = fmaf(hv.x, wv4.x, acck[k]);
        acck[k] = fmaf(hv.y, wv4.y, acck[k]);
        acck[k] = fmaf(hv.z, wv4.z, acck[k]);
        acck[k] = fmaf(hv.w, wv4.w, acck[k]);
      }
    }
    float mx = 0.f;
#pragma unroll
    for (int k = 0; k < KNN; ++k) {
      float h2 = fmaxf(acck[k], 0.f);
      s2a += h2; ss2a += h2*h2;
      mx = fmaxf(mx, h2);
    }
    int n = n0 + w;
    maxh2[(size_t)(b*NN + n)*CC + c] = mx;
    __syncthreads();
  }
  red[w][c] = s2a; __syncthreads();
  if (w == 0) atomicAdd(&acc2[c], red[0][c]+red[1][c]+red[2][c]+red[3][c]);
  __syncthreads();
  red[w][c] = ss2a; __syncthreads();
  if (w == 0) atomicAdd(&acc2[64+c], red[0][c]+red[1][c]+red[2][c]+red[3][c]);
}

// ---------------- finalize BN2 affine ----------------
__global__ void fold2_kernel(const float* __restrict__ acc2, const float* __restrict__ g2,
    const float* __restrict__ be2, float* __restrict__ s2, float* __restrict__ t2) {
  int c = threadIdx.x;
  float cnt = (float)CNT1;
  float m = acc2[c]/cnt;
  float v = acc2[64+c]/cnt - m*m;
  float sc = g2[c]*rsqrtf(v+EPSF);
  s2[c] = sc;
  t2[c] = be2[c] - m*sc;
}

// ---------------- head: Y[b,h] = relu(max_m(f@w_nn1^T)+b) ----------------
__global__ __launch_bounds__(256) void head_kernel(const float* __restrict__ maxh2,
    const int* __restrict__ fidxg, const float* __restrict__ s2g, const float* __restrict__ t2g,
    const float* __restrict__ wnn1, const float* __restrict__ bnn1, float* __restrict__ Y) {
  int b = blockIdx.x >> 2;
  int hc = blockIdx.x & 3;
  __shared__ __align__(16) float ftile[128][CC];
  __shared__ float red2[2][128];
  int hl = threadIdx.x & 127, mseg = threadIdx.x >> 7;
  int h = hc*128 + hl;
  float4 wv4[16];
  const float4* wr4 = (const float4*)(wnn1 + (size_t)h*CC);
#pragma unroll
  for (int q = 0; q < 16; ++q) wv4[q] = wr4[q];
  float best = -FLT_MAX;
  const int* fb = fidxg + b*MM;
  for (int chunk = 0; chunk < 2; ++chunk) {
    {
      int row = threadIdx.x & 127, chal = threadIdx.x >> 7;
      int fi = fb[chunk*128 + row];
      const float* src = maxh2 + (size_t)(b*NN + fi)*CC;
      for (int ci = chal*32; ci < chal*32+32; ++ci)
        ftile[row][ci] = s2g[ci]*src[ci] + t2g[ci];
    }
    __syncthreads();
    for (int m = mseg*64; m < mseg*64+64; ++m) {
      float acc = 0.f;
#pragma unroll
      for (int cq = 0; cq < 16; ++cq) {
        float4 f = *((const float4*)&ftile[m][cq*4]);
        acc = fmaf(f.x, wv4[cq].x, acc);
        acc = fmaf(f.y, wv4[cq].y, acc);
        acc = fmaf(f.z, wv4[cq].z, acc);
        acc = fmaf(f.w, wv4[cq].w, acc);
      }
      best = fmaxf(best, acc);
    }
    __syncthreads();
  }
  red2[mseg][hl] = best;
  __syncthreads();
  if (mseg == 0) {
    float v = fmaxf(red2[0][hl], red2[1][hl]) + bnn1[h];
    Y[(size_t)b*HH + h] = fmaxf(v, 0.f);
  }
}

// ---------------- BN over batch (two-pass) ----------------
__global__ void bn3_kernel(const float* __restrict__ Y, const float* __restrict__ g,
    const float* __restrict__ be, float* __restrict__ s3, float* __restrict__ t3) {
  int h = blockIdx.x*256 + threadIdx.x;
  float s = 0.f;
  for (int b = 0; b < BB; ++b) s += Y[(size_t)b*HH + h];
  float m = s / (float)BB;
  float v = 0.f;
  for (int b = 0; b < BB; ++b) { float d = Y[(size_t)b*HH + h] - m; v += d*d; }
  v /= (float)BB;
  float sc = g[h] * rsqrtf(v + EPSF);
  s3[h] = sc; t3[h] = be[h] - m*sc;
}

// ---------------- logits + log_softmax ----------------
__global__ __launch_bounds__(256) void logits_kernel(const float* __restrict__ Y,
    const float* __restrict__ s3, const float* __restrict__ t3,
    const float* __restrict__ w4, const float* __restrict__ b4, float* __restrict__ out) {
  int b = blockIdx.x;
  __shared__ float ybn[HH];
  __shared__ float lg[NCLS];
  __shared__ float lse;
  for (int hh = threadIdx.x; hh < HH; hh += 256)
    ybn[hh] = Y[(size_t)b*HH + hh]*s3[hh] + t3[hh];
  __syncthreads();
  if (threadIdx.x < NCLS) {
    int j = threadIdx.x;
    float acc = b4[j];
    const float* wr = w4 + (size_t)j*HH;
    for (int ci = 0; ci < HH; ++ci) acc = fmaf(ybn[ci], wr[ci], acc);
    lg[j] = acc;
  }
  __syncthreads();
  if (threadIdx.x == 0) {
    float mx = -FLT_MAX;
    for (int j = 0; j < NCLS; ++j) mx = fmaxf(mx, lg[j]);
    float s = 0.f;
    for (int j = 0; j < NCLS; ++j) s += expf(lg[j] - mx);
    lse = mx + logf(s);
  }
  __syncthreads();
  if (threadIdx.x < NCLS) out[b*NCLS + threadIdx.x] = lg[threadIdx.x] - lse;
}

extern "C" void kernel_launch(void* const* d_in, const int* in_sizes, int n_in,
                              void* d_out, int out_size, void* d_ws, size_t ws_size,
                              hipStream_t stream) {
  const float* pos  = (const float*)d_in[0];
  const float* w1   = (const float*)d_in[1];
  const float* b1   = (const float*)d_in[2];
  const float* g1   = (const float*)d_in[3];
  const float* be1  = (const float*)d_in[4];
  const float* w2   = (const float*)d_in[5];
  const float* b2   = (const float*)d_in[6];
  const float* g2   = (const float*)d_in[7];
  const float* be2  = (const float*)d_in[8];
  const float* wnn1 = (const float*)d_in[9];
  const float* bnn1 = (const float*)d_in[10];
  const float* gbn2 = (const float*)d_in[11];
  const float* bebn2= (const float*)d_in[12];
  const float* wnn4 = (const float*)d_in[13];
  const float* bnn4 = (const float*)d_in[14];
  float* ws = (float*)d_ws;
  int*   idxg  = (int*)(ws + IDX_OFF);
  float* maxh2 = ws + MAXH2_OFF;
  int*   fidxg = (int*)(ws + FIDX_OFF);
  float* Y     = ws + Y_OFF;
  float* acc1  = ws + ACC_OFF;
  float* acc2  = ws + ACC_OFF + 128;
  float* w2t4  = ws + W2T_OFF;
  float* b2f   = ws + B2F_OFF;
  float* s2    = ws + S2_OFF;
  float* t2    = ws + T2_OFF;
  float* s3    = ws + S3_OFF;
  float* t3    = ws + T3_OFF;
  float* outp  = (float*)d_out;

  hipMemsetAsync((void*)(ws + ACC_OFF), 0, 256*sizeof(float), stream);
  knn_kernel<<<BB*16, 256, 0, stream>>>(pos, idxg);
  fps_kernel<<<BB, 256, 0, stream>>>(pos, fidxg);
  stats1_kernel<<<BB*16, 256, 0, stream>>>(pos, idxg, w1, b1, acc1);
  fold1_kernel<<<1, 64, 0, stream>>>(acc1, g1, be1, w2, b2, w2t4, b2f);
  conv2_kernel<<<BB*16, 256, 0, stream>>>(pos, idxg, w1, b1, w2t4, b2f, maxh2, acc2);
  fold2_kernel<<<1, 64, 0, stream>>>(acc2, g2, be2, s2, t2);
  head_kernel<<<BB*4, 256, 0, stream>>>(maxh2, fidxg, s2, t2, wnn1, bnn1, Y);
  bn3_kernel<<<2, 256, 0, stream>>>(Y, gbn2, bebn2, s3, t3);
  logits_kernel<<<BB, 256, 0, stream>>>(Y, s3, t3, wnn4, bnn4, outp);
}

// Round 3
// 768.639 us; speedup vs baseline: 2.3807x; 1.3117x over previous
//
#include <hip/hip_runtime.h>
#include <hip/hip_bf16.h>
#include <cfloat>
#include <math.h>

#define BB 64
#define NN 1024
#define KNN 20
#define MM 256
#define CC 64
#define HH 512
#define NCLS 40
#define EPSF 1e-5f
#define CNT1 (BB*NN*KNN)

// workspace offsets (in 4-byte elements)
#define IDX_OFF    0
#define MAXH2_OFF  (IDX_OFF + BB*NN*KNN)      // int idx then floats
#define FIDX_OFF   (MAXH2_OFF + BB*NN*CC)
#define Y_OFF      (FIDX_OFF + BB*MM)
#define ACC_OFF    (Y_OFF + BB*HH)            // 256 floats zeroed: sum1[64],sumsq1[64],sum2[64],sumsq2[64]
#define W2T_OFF    (ACC_OFF + 256)            // w2' bf16 B-frags (2048 ushorts) + b2f
#define B2F_OFF    (W2T_OFF + CC*CC)
#define S2_OFF     (B2F_OFF + CC)
#define T2_OFF     (S2_OFF + CC)
#define S3_OFF     (T2_OFF + CC)
#define T3_OFF     (S3_OFF + HH)

typedef __attribute__((ext_vector_type(8)))  short short8;
typedef __attribute__((ext_vector_type(16))) float f32x16;

static __device__ __forceinline__ unsigned short f2bf(float f) {
  unsigned u = __float_as_uint(f);
  unsigned r = (u + 0x7fffu + ((u >> 16) & 1u)) >> 16;   // RNE
  return (unsigned short)r;
}

// ---------------- kNN: wave-cooperative radix/binary-search top-20 ----------------
__global__ __launch_bounds__(256) void knn_kernel(const float* __restrict__ pos,
                                                  int* __restrict__ idxg) {
  int b  = blockIdx.x >> 4;   // cloud
  int nb = blockIdx.x & 15;   // 64-point segment of the cloud
  __shared__ float4 pj[NN];
  const float* pb = pos + (size_t)b * NN * 3;
  for (int i = threadIdx.x; i < NN; i += 256) {
    float x = pb[i*3+0], y = pb[i*3+1], z = pb[i*3+2];
    pj[i] = make_float4(x, y, z, (x*x + y*y) + z*z);
  }
  __syncthreads();
  int lane = threadIdx.x & 63;
  int wv   = threadIdx.x >> 6;
  unsigned long long lmask_lt = (1ULL << lane) - 1ULL;

  for (int t = 0; t < 16; ++t) {
    int i = nb*64 + wv*16 + t;       // query point (wave-uniform)
    float4 pi = pj[i];               // LDS broadcast
    unsigned u[16];
#pragma unroll
    for (int q = 0; q < 16; ++q) {
      int j = q*64 + lane;
      float4 pw = pj[j];
      float d = pi.w + pw.w - 2.0f*(pi.x*pw.x + pi.y*pw.y + pi.z*pw.z);
      unsigned bits = __float_as_uint(d);
      bits = (bits & 0x80000000u) ? ~bits : (bits | 0x80000000u);
      if (j == i) bits = 0xFFFFFFFFu;   // self excluded (diag = +inf)
      u[q] = bits;
    }
    unsigned lo = 0u, hi = 0xFFFFFFFFu;
    while (lo < hi) {                   // wave-uniform, <=32 rounds
      unsigned mid = lo + ((hi - lo) >> 1);
      int cnt = 0;
#pragma unroll
      for (int q = 0; q < 16; ++q)
        cnt += (int)__popcll(__ballot(u[q] <= mid));
      if (cnt >= KNN) hi = mid; else lo = mid + 1;
    }
    unsigned xstar = lo;
    int* op = idxg + (size_t)(b*NN + i) * KNN;
    int base = 0;
#pragma unroll
    for (int q = 0; q < 16; ++q) {
      bool pred = (u[q] < xstar);
      unsigned long long mask = __ballot((int)pred);
      if (pred) {
        int pos = base + (int)__popcll(mask & lmask_lt);
        op[pos] = q*64 + lane;
      }
      base += (int)__popcll(mask);
    }
    for (int q = 0; q < 16 && base < KNN; ++q) {
      bool pred = (u[q] == xstar);
      unsigned long long mask = __ballot((int)pred);
      if (pred) {
        int pos = base + (int)__popcll(mask & lmask_lt);
        if (pos < KNN) op[pos] = q*64 + lane;
      }
      base += (int)__popcll(mask);
    }
  }
}

// ---------------- FPS (bit-exact distance chain vs numpy) ----------------
__global__ __launch_bounds__(256) void fps_kernel(const float* __restrict__ pos,
                                                  int* __restrict__ fidxg) {
  int b = blockIdx.x;
  __shared__ float4 pj[NN];
  __shared__ float rv[4]; __shared__ int ri[4];
  __shared__ int curs;
  const float* pb = pos + (size_t)b * NN * 3;
  for (int i = threadIdx.x; i < NN; i += 256)
    pj[i] = make_float4(pb[i*3], pb[i*3+1], pb[i*3+2], 0.f);
  float dist[4];
#pragma unroll
  for (int q = 0; q < 4; ++q) dist[q] = 1e38f;
  if (threadIdx.x == 0) { fidxg[b*MM] = 0; curs = 0; }
  __syncthreads();
  int cur = 0;
  int lane = threadIdx.x & 63, wv = threadIdx.x >> 6;
  for (int m = 1; m < MM; ++m) {
    float4 cp = pj[cur];
    float bv = -FLT_MAX; int bi = 0x7fffffff;
#pragma unroll
    for (int q = 0; q < 4; ++q) {
      int j = threadIdx.x + q*256;
      float4 p = pj[j];
      float dx = __fsub_rn(p.x, cp.x);
      float dy = __fsub_rn(p.y, cp.y);
      float dz = __fsub_rn(p.z, cp.z);
      float dd = __fadd_rn(__fadd_rn(__fmul_rn(dx,dx), __fmul_rn(dy,dy)), __fmul_rn(dz,dz));
      float dq = fminf(dist[q], dd);
      dist[q] = dq;
      if ((dq > bv) || (dq == bv && j < bi)) { bv = dq; bi = j; }
    }
#pragma unroll
    for (int off = 32; off >= 1; off >>= 1) {
      float ov = __shfl_down(bv, off, 64);
      int   oi = __shfl_down(bi, off, 64);
      if ((ov > bv) || (ov == bv && oi < bi)) { bv = ov; bi = oi; }
    }
    if (lane == 0) { rv[wv] = bv; ri[wv] = bi; }
    __syncthreads();
    if (threadIdx.x == 0) {
      float V = rv[0]; int I = ri[0];
#pragma unroll
      for (int t = 1; t < 4; ++t)
        if ((rv[t] > V) || (rv[t] == V && ri[t] < I)) { V = rv[t]; I = ri[t]; }
      fidxg[b*MM + m] = I;
      curs = I;
    }
    __syncthreads();
    cur = curs;
  }
}

// ---------------- stats of h1 = relu(rel@w1+b1) ----------------
__global__ __launch_bounds__(256) void stats1_kernel(const float* __restrict__ pos,
    const int* __restrict__ idxg, const float* __restrict__ w1,
    const float* __restrict__ b1, float* __restrict__ acc) {
  int b = blockIdx.x >> 4;
  int nb = blockIdx.x & 15;
  __shared__ float px[NN], py[NN], pz[NN];
  __shared__ float relx[4][KNN], rely[4][KNN], relz[4][KNN];
  __shared__ float red[4][CC];
  const float* pb = pos + (size_t)b*NN*3;
  for (int i = threadIdx.x; i < NN; i += 256) {
    px[i] = pb[i*3+0]; py[i] = pb[i*3+1]; pz[i] = pb[i*3+2];
  }
  int c = threadIdx.x & 63, w = threadIdx.x >> 6;
  float w1x = w1[c*3+0], w1y = w1[c*3+1], w1z = w1[c*3+2], b1c = b1[c];
  float s = 0.f, ss = 0.f;
  __syncthreads();
  for (int it = 0; it < 16; ++it) {
    int n0 = nb*64 + it*4;
    if (threadIdx.x < 80) {
      int wv = threadIdx.x / KNN, k = threadIdx.x % KNN;
      int n = n0 + wv;
      int j = idxg[(size_t)(b*NN + n)*KNN + k];
      relx[wv][k] = px[j] - px[n];
      rely[wv][k] = py[j] - py[n];
      relz[wv][k] = pz[j] - pz[n];
    }
    __syncthreads();
#pragma unroll
    for (int k = 0; k < KNN; ++k) {
      float h = fmaxf(relx[w][k]*w1x + rely[w][k]*w1y + relz[w][k]*w1z + b1c, 0.f);
      s += h; ss += h*h;
    }
    __syncthreads();
  }
  red[w][c] = s; __syncthreads();
  if (w == 0) atomicAdd(&acc[c], red[0][c]+red[1][c]+red[2][c]+red[3][c]);
  __syncthreads();
  red[w][c] = ss; __syncthreads();
  if (w == 0) atomicAdd(&acc[64+c], red[0][c]+red[1][c]+red[2][c]+red[3][c]);
}

// ---------------- fold BN1 into w2 (bf16 B-fragment layout) ----------------
// w2bf[((nt*4+ks)*64 + lane)*8 + j] = bf16(w2[cout][cin] * s1[cin])
//   cout = nt*32 + (lane&31), cin = ks*16 + (lane>>5)*8 + j
__global__ void fold1_kernel(const float* __restrict__ acc, const float* __restrict__ g1,
    const float* __restrict__ be1, const float* __restrict__ w2, const float* __restrict__ b2,
    unsigned short* __restrict__ w2bf, float* __restrict__ b2f) {
  __shared__ float s1[CC], t1[CC];
  int tid = threadIdx.x;  // 512 threads
  if (tid < CC) {
    float cnt = (float)CNT1;
    float m = acc[tid] / cnt;
    float v = acc[64+tid] / cnt - m*m;
    float sc = g1[tid] * rsqrtf(v + EPSF);
    s1[tid] = sc; t1[tid] = be1[tid] - m*sc;
  }
  __syncthreads();
  int frag = tid >> 6;        // 0..7  (nt = frag>>2, ks = frag&3)
  int lane = tid & 63;
  int nt = frag >> 2, ks = frag & 3;
  int cout = nt*32 + (lane & 31);
  int cin0 = ks*16 + (lane >> 5)*8;
  for (int j = 0; j < 8; ++j) {
    int cin = cin0 + j;
    w2bf[((size_t)frag*64 + lane)*8 + j] = f2bf(w2[cout*CC + cin] * s1[cin]);
  }
  if (tid < CC) {
    float accb = b2[tid];
    for (int ci = 0; ci < CC; ++ci) accb += t1[ci]*w2[tid*CC + ci];
    b2f[tid] = accb;
  }
}

// ---------------- conv2 via MFMA: h2 = relu(h1@w2'+b2'), maxh2 + stats ----------------
// One wave per point n per iteration: 32-row M-tile (rows 0-19 = neighbors,
// 20-31 = zero pad, statically masked in epilogue), N=64 (2 N-tiles in reg
// B-frags), K=64 (4 K-steps of 16). All LDS traffic wave-private: no barriers
// in the main loop. h1 LDS layout: [g=cin/8][row][8cin] bf16, g-stride 528B
// (33*16B) -> conflict-free ds_read_b128 A-loads.
__global__ __launch_bounds__(256, 4) void conv2_kernel(const float* __restrict__ pos,
    const int* __restrict__ idxg, const float* __restrict__ w1, const float* __restrict__ b1,
    const unsigned short* __restrict__ w2bf, const float* __restrict__ b2fg,
    float* __restrict__ maxh2, float* __restrict__ acc2) {
  int b = blockIdx.x >> 4;
  int nb = blockIdx.x & 15;
  __shared__ float px[NN], py[NN], pz[NN];
  __shared__ float4 relw[4][KNN];
  __shared__ __align__(16) unsigned short h1s[4][2112];  // 8 groups * 264 ushorts
  __shared__ float redbuf[4][2*CC];
  const float* pb = pos + (size_t)b*NN*3;
  for (int i = threadIdx.x; i < NN; i += 256) {
    px[i] = pb[i*3+0]; py[i] = pb[i*3+1]; pz[i] = pb[i*3+2];
  }
  int lane = threadIdx.x & 63, w = threadIdx.x >> 6;
  int half = lane >> 5, l31 = lane & 31;
  // B fragments (weights) in registers, shared across all 16 n-iterations
  short8 Bf[2][4];
#pragma unroll
  for (int nt = 0; nt < 2; ++nt)
#pragma unroll
    for (int ks = 0; ks < 4; ++ks)
      Bf[nt][ks] = *(const short8*)&w2bf[((size_t)(nt*4+ks)*64 + lane)*8];
  float b2o0 = b2fg[l31], b2o1 = b2fg[32 + l31];
  float w1x = w1[lane*3+0], w1y = w1[lane*3+1], w1z = w1[lane*3+2], b1c = b1[lane];
  unsigned short* hw = h1s[w];
  // zero the 12 pad rows of each of the 8 k-groups (once; reused every iter)
  {
    short8 zz = {0,0,0,0,0,0,0,0};
    for (int z = lane; z < 96; z += 64) {
      int g = z / 12, r = 20 + z % 12;
      *(short8*)&hw[g*264 + r*8] = zz;
    }
  }
  float sA = 0.f, ssA = 0.f, sB = 0.f, ssB = 0.f;
  __syncthreads();
  for (int t = 0; t < 16; ++t) {
    int n = nb*64 + w*16 + t;
    if (lane < KNN) {
      int j = idxg[(size_t)(b*NN + n)*KNN + lane];
      relw[w][lane] = make_float4(px[j]-px[n], py[j]-py[n], pz[j]-pz[n], 0.f);
    }
    // h1 rows 0..19, this lane's channel = lane
    int gbase = (lane >> 3)*264 + (lane & 7);
#pragma unroll
    for (int k = 0; k < KNN; ++k) {
      float4 r4 = relw[w][k];   // wave-uniform broadcast read
      float h = fmaxf(fmaf(r4.x, w1x, fmaf(r4.y, w1y, fmaf(r4.z, w1z, b1c))), 0.f);
      hw[gbase + k*8] = f2bf(h);
    }
    f32x16 acc0 = {}; f32x16 acc1 = {};
#pragma unroll
    for (int ks = 0; ks < 4; ++ks) {
      short8 A = *(const short8*)&hw[(ks*2 + half)*264 + l31*8];
      acc0 = __builtin_amdgcn_mfma_f32_32x32x16_bf16(A, Bf[0][ks], acc0, 0, 0, 0);
      acc1 = __builtin_amdgcn_mfma_f32_32x32x16_bf16(A, Bf[1][ks], acc1, 0, 0, 0);
    }
    // epilogue: rows real iff (q<2) or (q==2 && half==0)
    float mx0 = 0.f, mx1 = 0.f;
#pragma unroll
    for (int reg = 0; reg < 8; ++reg) {
      float v0 = fmaxf(acc0[reg] + b2o0, 0.f);
      float v1 = fmaxf(acc1[reg] + b2o1, 0.f);
      sA += v0; ssA += v0*v0; sB += v1; ssB += v1*v1;
      mx0 = fmaxf(mx0, v0); mx1 = fmaxf(mx1, v1);
    }
    if (half == 0) {
#pragma unroll
      for (int reg = 8; reg < 12; ++reg) {
        float v0 = fmaxf(acc0[reg] + b2o0, 0.f);
        float v1 = fmaxf(acc1[reg] + b2o1, 0.f);
        sA += v0; ssA += v0*v0; sB += v1; ssB += v1*v1;
        mx0 = fmaxf(mx0, v0); mx1 = fmaxf(mx1, v1);
      }
    }
    mx0 = fmaxf(mx0, __shfl_xor(mx0, 32, 64));
    mx1 = fmaxf(mx1, __shfl_xor(mx1, 32, 64));
    if (half == 0) {
      float* mp = maxh2 + (size_t)(b*NN + n)*CC;
      mp[l31] = mx0; mp[32 + l31] = mx1;
    }
  }
  // stats reduce: fold halves, then per-block, then atomics
  sA += __shfl_xor(sA, 32, 64); ssA += __shfl_xor(ssA, 32, 64);
  sB += __shfl_xor(sB, 32, 64); ssB += __shfl_xor(ssB, 32, 64);
  if (half == 0) { redbuf[w][l31] = sA; redbuf[w][32 + l31] = sB; }
  __syncthreads();
  if (w == 0) atomicAdd(&acc2[lane], redbuf[0][lane]+redbuf[1][lane]+redbuf[2][lane]+redbuf[3][lane]);
  __syncthreads();
  if (half == 0) { redbuf[w][l31] = ssA; redbuf[w][32 + l31] = ssB; }
  __syncthreads();
  if (w == 0) atomicAdd(&acc2[64+lane], redbuf[0][lane]+redbuf[1][lane]+redbuf[2][lane]+redbuf[3][lane]);
}

// ---------------- finalize BN2 affine ----------------
__global__ void fold2_kernel(const float* __restrict__ acc2, const float* __restrict__ g2,
    const float* __restrict__ be2, float* __restrict__ s2, float* __restrict__ t2) {
  int c = threadIdx.x;
  float cnt = (float)CNT1;
  float m = acc2[c]/cnt;
  float v = acc2[64+c]/cnt - m*m;
  float sc = g2[c]*rsqrtf(v+EPSF);
  s2[c] = sc;
  t2[c] = be2[c] - m*sc;
}

// ---------------- head: Y[b,h] = relu(max_m(f@w_nn1^T)+b) ----------------
__global__ __launch_bounds__(256) void head_kernel(const float* __restrict__ maxh2,
    const int* __restrict__ fidxg, const float* __restrict__ s2g, const float* __restrict__ t2g,
    const float* __restrict__ wnn1, const float* __restrict__ bnn1, float* __restrict__ Y) {
  int b = blockIdx.x >> 2;
  int hc = blockIdx.x & 3;
  __shared__ __align__(16) float ftile[128][CC];
  __shared__ float red2[2][128];
  int hl = threadIdx.x & 127, mseg = threadIdx.x >> 7;
  int h = hc*128 + hl;
  float4 wv4[16];
  const float4* wr4 = (const float4*)(wnn1 + (size_t)h*CC);
#pragma unroll
  for (int q = 0; q < 16; ++q) wv4[q] = wr4[q];
  float best = -FLT_MAX;
  const int* fb = fidxg + b*MM;
  for (int chunk = 0; chunk < 2; ++chunk) {
    {
      int row = threadIdx.x & 127, chal = threadIdx.x >> 7;
      int fi = fb[chunk*128 + row];
      const float* src = maxh2 + (size_t)(b*NN + fi)*CC;
      for (int ci = chal*32; ci < chal*32+32; ++ci)
        ftile[row][ci] = s2g[ci]*src[ci] + t2g[ci];
    }
    __syncthreads();
    for (int m = mseg*64; m < mseg*64+64; ++m) {
      float acc = 0.f;
#pragma unroll
      for (int cq = 0; cq < 16; ++cq) {
        float4 f = *((const float4*)&ftile[m][cq*4]);
        acc = fmaf(f.x, wv4[cq].x, acc);
        acc = fmaf(f.y, wv4[cq].y, acc);
        acc = fmaf(f.z, wv4[cq].z, acc);
        acc = fmaf(f.w, wv4[cq].w, acc);
      }
      best = fmaxf(best, acc);
    }
    __syncthreads();
  }
  red2[mseg][hl] = best;
  __syncthreads();
  if (mseg == 0) {
    float v = fmaxf(red2[0][hl], red2[1][hl]) + bnn1[h];
    Y[(size_t)b*HH + h] = fmaxf(v, 0.f);
  }
}

// ---------------- BN over batch (two-pass) ----------------
__global__ void bn3_kernel(const float* __restrict__ Y, const float* __restrict__ g,
    const float* __restrict__ be, float* __restrict__ s3, float* __restrict__ t3) {
  int h = blockIdx.x*256 + threadIdx.x;
  float s = 0.f;
  for (int b = 0; b < BB; ++b) s += Y[(size_t)b*HH + h];
  float m = s / (float)BB;
  float v = 0.f;
  for (int b = 0; b < BB; ++b) { float d = Y[(size_t)b*HH + h] - m; v += d*d; }
  v /= (float)BB;
  float sc = g[h] * rsqrtf(v + EPSF);
  s3[h] = sc; t3[h] = be[h] - m*sc;
}

// ---------------- logits + log_softmax ----------------
__global__ __launch_bounds__(256) void logits_kernel(const float* __restrict__ Y,
    const float* __restrict__ s3, const float* __restrict__ t3,
    const float* __restrict__ w4, const float* __restrict__ b4, float* __restrict__ out) {
  int b = blockIdx.x;
  __shared__ float ybn[HH];
  __shared__ float lg[NCLS];
  __shared__ float lse;
  for (int hh = threadIdx.x; hh < HH; hh += 256)
    ybn[hh] = Y[(size_t)b*HH + hh]*s3[hh] + t3[hh];
  __syncthreads();
  if (threadIdx.x < NCLS) {
    int j = threadIdx.x;
    float acc = b4[j];
    const float* wr = w4 + (size_t)j*HH;
    for (int ci = 0; ci < HH; ++ci) acc = fmaf(ybn[ci], wr[ci], acc);
    lg[j] = acc;
  }
  __syncthreads();
  if (threadIdx.x == 0) {
    float mx = -FLT_MAX;
    for (int j = 0; j < NCLS; ++j) mx = fmaxf(mx, lg[j]);
    float s = 0.f;
    for (int j = 0; j < NCLS; ++j) s += expf(lg[j] - mx);
    lse = mx + logf(s);
  }
  __syncthreads();
  if (threadIdx.x < NCLS) out[b*NCLS + threadIdx.x] = lg[threadIdx.x] - lse;
}

extern "C" void kernel_launch(void* const* d_in, const int* in_sizes, int n_in,
                              void* d_out, int out_size, void* d_ws, size_t ws_size,
                              hipStream_t stream) {
  const float* pos  = (const float*)d_in[0];
  const float* w1   = (const float*)d_in[1];
  const float* b1   = (const float*)d_in[2];
  const float* g1   = (const float*)d_in[3];
  const float* be1  = (const float*)d_in[4];
  const float* w2   = (const float*)d_in[5];
  const float* b2   = (const float*)d_in[6];
  const float* g2   = (const float*)d_in[7];
  const float* be2  = (const float*)d_in[8];
  const float* wnn1 = (const float*)d_in[9];
  const float* bnn1 = (const float*)d_in[10];
  const float* gbn2 = (const float*)d_in[11];
  const float* bebn2= (const float*)d_in[12];
  const float* wnn4 = (const float*)d_in[13];
  const float* bnn4 = (const float*)d_in[14];
  float* ws = (float*)d_ws;
  int*   idxg  = (int*)(ws + IDX_OFF);
  float* maxh2 = ws + MAXH2_OFF;
  int*   fidxg = (int*)(ws + FIDX_OFF);
  float* Y     = ws + Y_OFF;
  float* acc1  = ws + ACC_OFF;
  float* acc2  = ws + ACC_OFF + 128;
  unsigned short* w2bf = (unsigned short*)(ws + W2T_OFF);
  float* b2f   = ws + B2F_OFF;
  float* s2    = ws + S2_OFF;
  float* t2    = ws + T2_OFF;
  float* s3    = ws + S3_OFF;
  float* t3    = ws + T3_OFF;
  float* outp  = (float*)d_out;

  hipMemsetAsync((void*)(ws + ACC_OFF), 0, 256*sizeof(float), stream);
  knn_kernel<<<BB*16, 256, 0, stream>>>(pos, idxg);
  fps_kernel<<<BB, 256, 0, stream>>>(pos, fidxg);
  stats1_kernel<<<BB*16, 256, 0, stream>>>(pos, idxg, w1, b1, acc1);
  fold1_kernel<<<1, 512, 0, stream>>>(acc1, g1, be1, w2, b2, w2bf, b2f);
  conv2_kernel<<<BB*16, 256, 0, stream>>>(pos, idxg, w1, b1, w2bf, b2f, maxh2, acc2);
  fold2_kernel<<<1, 64, 0, stream>>>(acc2, g2, be2, s2, t2);
  head_kernel<<<BB*4, 256, 0, stream>>>(maxh2, fidxg, s2, t2, wnn1, bnn1, Y);
  bn3_kernel<<<2, 256, 0, stream>>>(Y, gbn2, bebn2, s3, t3);
  logits_kernel<<<BB, 256, 0, stream>>>(Y, s3, t3, wnn4, bnn4, outp);
}

// Round 4
// 563.289 us; speedup vs baseline: 3.2486x; 1.3646x over previous
//
#include <hip/hip_runtime.h>
#include <hip/hip_bf16.h>
#include <cfloat>
#include <math.h>

#define BB 64
#define NN 1024
#define KNN 20
#define MM 256
#define CC 64
#define HH 512
#define NCLS 40
#define EPSF 1e-5f
#define CNT1 (BB*NN*KNN)

// workspace offsets (in 4-byte elements)
#define IDX_OFF    0
#define MAXH2_OFF  (IDX_OFF + BB*NN*KNN)      // int idx then floats
#define FIDX_OFF   (MAXH2_OFF + BB*NN*CC)
#define Y_OFF      (FIDX_OFF + BB*MM)
#define ACC_OFF    (Y_OFF + BB*HH)            // 256 floats zeroed: sum1[64],sumsq1[64],sum2[64],sumsq2[64]
#define W2T_OFF    (ACC_OFF + 256)            // w2' bf16 B-frags (2048 ushorts) + b2f
#define B2F_OFF    (W2T_OFF + CC*CC)
#define S2_OFF     (B2F_OFF + CC)
#define T2_OFF     (S2_OFF + CC)
#define S3_OFF     (T2_OFF + CC)
#define T3_OFF     (S3_OFF + HH)

typedef __attribute__((ext_vector_type(8)))  short short8;
typedef __attribute__((ext_vector_type(16))) float f32x16;

static __device__ __forceinline__ unsigned short f2bf(float f) {
  unsigned u = __float_as_uint(f);
  unsigned r = (u + 0x7fffu + ((u >> 16) & 1u)) >> 16;   // RNE
  return (unsigned short)r;
}

// ---------------- fused kNN + FPS ----------------
// blocks [0, BB*16): wave-cooperative binary-search top-20 kNN (one wave/query)
// blocks [BB*16, BB*16+BB): single-wave FPS, one wave per cloud, zero barriers
// in the serial loop. FPS is latency-bound with idle pipes, so co-residency
// hides it behind kNN's VALU work.
__global__ __launch_bounds__(256) void knn_fps_kernel(const float* __restrict__ pos,
                                                      int* __restrict__ idxg,
                                                      int* __restrict__ fidxg) {
  __shared__ float4 pj[NN];
  if (blockIdx.x < BB*16) {
    // ---------------- kNN branch ----------------
    int b  = blockIdx.x >> 4;   // cloud
    int nb = blockIdx.x & 15;   // 64-point segment of the cloud
    const float* pb = pos + (size_t)b * NN * 3;
    for (int i = threadIdx.x; i < NN; i += 256) {
      float x = pb[i*3+0], y = pb[i*3+1], z = pb[i*3+2];
      pj[i] = make_float4(x, y, z, (x*x + y*y) + z*z);
    }
    __syncthreads();
    int lane = threadIdx.x & 63;
    int wv   = threadIdx.x >> 6;
    unsigned long long lmask_lt = (1ULL << lane) - 1ULL;

    for (int t = 0; t < 16; ++t) {
      int i = nb*64 + wv*16 + t;       // query point (wave-uniform)
      float4 pi = pj[i];               // LDS broadcast
      unsigned u[16];
#pragma unroll
      for (int q = 0; q < 16; ++q) {
        int j = q*64 + lane;
        float4 pw = pj[j];
        float d = pi.w + pw.w - 2.0f*(pi.x*pw.x + pi.y*pw.y + pi.z*pw.z);
        unsigned bits = __float_as_uint(d);
        bits = (bits & 0x80000000u) ? ~bits : (bits | 0x80000000u);
        if (j == i) bits = 0xFFFFFFFFu;   // self excluded (diag = +inf)
        u[q] = bits;
      }
      unsigned lo = 0u, hi = 0xFFFFFFFFu;
      while (lo < hi) {                   // wave-uniform, <=32 rounds
        unsigned mid = lo + ((hi - lo) >> 1);
        int cnt = 0;
#pragma unroll
        for (int q = 0; q < 16; ++q)
          cnt += (int)__popcll(__ballot(u[q] <= mid));
        if (cnt >= KNN) hi = mid; else lo = mid + 1;
      }
      unsigned xstar = lo;
      int* op = idxg + (size_t)(b*NN + i) * KNN;
      int base = 0;
#pragma unroll
      for (int q = 0; q < 16; ++q) {
        bool pred = (u[q] < xstar);
        unsigned long long mask = __ballot((int)pred);
        if (pred) {
          int pos_ = base + (int)__popcll(mask & lmask_lt);
          op[pos_] = q*64 + lane;
        }
        base += (int)__popcll(mask);
      }
      for (int q = 0; q < 16 && base < KNN; ++q) {
        bool pred = (u[q] == xstar);
        unsigned long long mask = __ballot((int)pred);
        if (pred) {
          int pos_ = base + (int)__popcll(mask & lmask_lt);
          if (pos_ < KNN) op[pos_] = q*64 + lane;
        }
        base += (int)__popcll(mask);
      }
    }
  } else {
    // ---------------- FPS branch: single wave, registers, no barriers ----------------
    int b = blockIdx.x - BB*16;
    const float* pb = pos + (size_t)b * NN * 3;
    for (int i = threadIdx.x; i < NN; i += 256)
      pj[i] = make_float4(pb[i*3], pb[i*3+1], pb[i*3+2], 0.f);
    __syncthreads();
    if (threadIdx.x >= 64) return;   // waves 1-3 done (after barrier)
    int lane = threadIdx.x;
    float px[16], py[16], pz[16], dist[16];
#pragma unroll
    for (int q = 0; q < 16; ++q) {
      float4 p = pj[q*64 + lane];
      px[q] = p.x; py[q] = p.y; pz[q] = p.z;
      dist[q] = 1e38f;
    }
    if (lane == 0) fidxg[b*MM] = 0;
    int cur = 0;
    for (int m = 1; m < MM; ++m) {
      float4 cp = pj[cur];             // wave-uniform LDS broadcast
      unsigned long long key[16];
#pragma unroll
      for (int q = 0; q < 16; ++q) {
        float dx = __fsub_rn(px[q], cp.x);
        float dy = __fsub_rn(py[q], cp.y);
        float dz = __fsub_rn(pz[q], cp.z);
        float dd = __fadd_rn(__fadd_rn(__fmul_rn(dx,dx), __fmul_rn(dy,dy)), __fmul_rn(dz,dz));
        float dq = fminf(dist[q], dd);
        dist[q] = dq;
        key[q] = ((unsigned long long)__float_as_uint(dq) << 32)
               | (unsigned)(NN - 1 - (q*64 + lane));
      }
      // in-register tree max (max dist; ties -> smallest index)
#pragma unroll
      for (int s = 8; s >= 1; s >>= 1)
#pragma unroll
        for (int q = 0; q < s; ++q)
          if (key[q + s] > key[q]) key[q] = key[q + s];
      unsigned long long best = key[0];
#pragma unroll
      for (int off = 32; off >= 1; off >>= 1) {
        unsigned long long o = __shfl_xor(best, off, 64);
        if (o > best) best = o;
      }
      cur = NN - 1 - (int)(best & 0xFFFFFFFFu);
      if (lane == 0) fidxg[b*MM + m] = cur;
    }
  }
}

// ---------------- stats of h1 = relu(rel@w1+b1) ----------------
__global__ __launch_bounds__(256) void stats1_kernel(const float* __restrict__ pos,
    const int* __restrict__ idxg, const float* __restrict__ w1,
    const float* __restrict__ b1, float* __restrict__ acc) {
  int b = blockIdx.x >> 4;
  int nb = blockIdx.x & 15;
  __shared__ float px[NN], py[NN], pz[NN];
  __shared__ float relx[4][KNN], rely[4][KNN], relz[4][KNN];
  __shared__ float red[4][CC];
  const float* pb = pos + (size_t)b*NN*3;
  for (int i = threadIdx.x; i < NN; i += 256) {
    px[i] = pb[i*3+0]; py[i] = pb[i*3+1]; pz[i] = pb[i*3+2];
  }
  int c = threadIdx.x & 63, w = threadIdx.x >> 6;
  float w1x = w1[c*3+0], w1y = w1[c*3+1], w1z = w1[c*3+2], b1c = b1[c];
  float s = 0.f, ss = 0.f;
  __syncthreads();
  for (int it = 0; it < 16; ++it) {
    int n0 = nb*64 + it*4;
    if (threadIdx.x < 80) {
      int wv = threadIdx.x / KNN, k = threadIdx.x % KNN;
      int n = n0 + wv;
      int j = idxg[(size_t)(b*NN + n)*KNN + k];
      relx[wv][k] = px[j] - px[n];
      rely[wv][k] = py[j] - py[n];
      relz[wv][k] = pz[j] - pz[n];
    }
    __syncthreads();
#pragma unroll
    for (int k = 0; k < KNN; ++k) {
      float h = fmaxf(relx[w][k]*w1x + rely[w][k]*w1y + relz[w][k]*w1z + b1c, 0.f);
      s += h; ss += h*h;
    }
    __syncthreads();
  }
  red[w][c] = s; __syncthreads();
  if (w == 0) atomicAdd(&acc[c], red[0][c]+red[1][c]+red[2][c]+red[3][c]);
  __syncthreads();
  red[w][c] = ss; __syncthreads();
  if (w == 0) atomicAdd(&acc[64+c], red[0][c]+red[1][c]+red[2][c]+red[3][c]);
}

// ---------------- fold BN1 into w2 (bf16 B-fragment layout) ----------------
// w2bf[((nt*4+ks)*64 + lane)*8 + j] = bf16(w2[cout][cin] * s1[cin])
//   cout = nt*32 + (lane&31), cin = ks*16 + (lane>>5)*8 + j
__global__ void fold1_kernel(const float* __restrict__ acc, const float* __restrict__ g1,
    const float* __restrict__ be1, const float* __restrict__ w2, const float* __restrict__ b2,
    unsigned short* __restrict__ w2bf, float* __restrict__ b2f) {
  __shared__ float s1[CC], t1[CC];
  int tid = threadIdx.x;  // 512 threads
  if (tid < CC) {
    float cnt = (float)CNT1;
    float m = acc[tid] / cnt;
    float v = acc[64+tid] / cnt - m*m;
    float sc = g1[tid] * rsqrtf(v + EPSF);
    s1[tid] = sc; t1[tid] = be1[tid] - m*sc;
  }
  __syncthreads();
  int frag = tid >> 6;        // 0..7  (nt = frag>>2, ks = frag&3)
  int lane = tid & 63;
  int nt = frag >> 2, ks = frag & 3;
  int cout = nt*32 + (lane & 31);
  int cin0 = ks*16 + (lane >> 5)*8;
  for (int j = 0; j < 8; ++j) {
    int cin = cin0 + j;
    w2bf[((size_t)frag*64 + lane)*8 + j] = f2bf(w2[cout*CC + cin] * s1[cin]);
  }
  if (tid < CC) {
    float accb = b2[tid];
    for (int ci = 0; ci < CC; ++ci) accb += t1[ci]*w2[tid*CC + ci];
    b2f[tid] = accb;
  }
}

// ---------------- conv2 via MFMA: h2 = relu(h1@w2'+b2'), maxh2 + stats ----------------
__global__ __launch_bounds__(256, 4) void conv2_kernel(const float* __restrict__ pos,
    const int* __restrict__ idxg, const float* __restrict__ w1, const float* __restrict__ b1,
    const unsigned short* __restrict__ w2bf, const float* __restrict__ b2fg,
    float* __restrict__ maxh2, float* __restrict__ acc2) {
  int b = blockIdx.x >> 4;
  int nb = blockIdx.x & 15;
  __shared__ float px[NN], py[NN], pz[NN];
  __shared__ float4 relw[4][KNN];
  __shared__ __align__(16) unsigned short h1s[4][2112];  // 8 groups * 264 ushorts
  __shared__ float redbuf[4][2*CC];
  const float* pb = pos + (size_t)b*NN*3;
  for (int i = threadIdx.x; i < NN; i += 256) {
    px[i] = pb[i*3+0]; py[i] = pb[i*3+1]; pz[i] = pb[i*3+2];
  }
  int lane = threadIdx.x & 63, w = threadIdx.x >> 6;
  int half = lane >> 5, l31 = lane & 31;
  short8 Bf[2][4];
#pragma unroll
  for (int nt = 0; nt < 2; ++nt)
#pragma unroll
    for (int ks = 0; ks < 4; ++ks)
      Bf[nt][ks] = *(const short8*)&w2bf[((size_t)(nt*4+ks)*64 + lane)*8];
  float b2o0 = b2fg[l31], b2o1 = b2fg[32 + l31];
  float w1x = w1[lane*3+0], w1y = w1[lane*3+1], w1z = w1[lane*3+2], b1c = b1[lane];
  unsigned short* hw = h1s[w];
  {
    short8 zz = {0,0,0,0,0,0,0,0};
    for (int z = lane; z < 96; z += 64) {
      int g = z / 12, r = 20 + z % 12;
      *(short8*)&hw[g*264 + r*8] = zz;
    }
  }
  float sA = 0.f, ssA = 0.f, sB = 0.f, ssB = 0.f;
  __syncthreads();
  for (int t = 0; t < 16; ++t) {
    int n = nb*64 + w*16 + t;
    if (lane < KNN) {
      int j = idxg[(size_t)(b*NN + n)*KNN + lane];
      relw[w][lane] = make_float4(px[j]-px[n], py[j]-py[n], pz[j]-pz[n], 0.f);
    }
    int gbase = (lane >> 3)*264 + (lane & 7);
#pragma unroll
    for (int k = 0; k < KNN; ++k) {
      float4 r4 = relw[w][k];   // wave-uniform broadcast read
      float h = fmaxf(fmaf(r4.x, w1x, fmaf(r4.y, w1y, fmaf(r4.z, w1z, b1c))), 0.f);
      hw[gbase + k*8] = f2bf(h);
    }
    f32x16 acc0 = {}; f32x16 acc1 = {};
#pragma unroll
    for (int ks = 0; ks < 4; ++ks) {
      short8 A = *(const short8*)&hw[(ks*2 + half)*264 + l31*8];
      acc0 = __builtin_amdgcn_mfma_f32_32x32x16_bf16(A, Bf[0][ks], acc0, 0, 0, 0);
      acc1 = __builtin_amdgcn_mfma_f32_32x32x16_bf16(A, Bf[1][ks], acc1, 0, 0, 0);
    }
    float mx0 = 0.f, mx1 = 0.f;
#pragma unroll
    for (int reg = 0; reg < 8; ++reg) {
      float v0 = fmaxf(acc0[reg] + b2o0, 0.f);
      float v1 = fmaxf(acc1[reg] + b2o1, 0.f);
      sA += v0; ssA += v0*v0; sB += v1; ssB += v1*v1;
      mx0 = fmaxf(mx0, v0); mx1 = fmaxf(mx1, v1);
    }
    if (half == 0) {
#pragma unroll
      for (int reg = 8; reg < 12; ++reg) {
        float v0 = fmaxf(acc0[reg] + b2o0, 0.f);
        float v1 = fmaxf(acc1[reg] + b2o1, 0.f);
        sA += v0; ssA += v0*v0; sB += v1; ssB += v1*v1;
        mx0 = fmaxf(mx0, v0); mx1 = fmaxf(mx1, v1);
      }
    }
    mx0 = fmaxf(mx0, __shfl_xor(mx0, 32, 64));
    mx1 = fmaxf(mx1, __shfl_xor(mx1, 32, 64));
    if (half == 0) {
      float* mp = maxh2 + (size_t)(b*NN + n)*CC;
      mp[l31] = mx0; mp[32 + l31] = mx1;
    }
  }
  sA += __shfl_xor(sA, 32, 64); ssA += __shfl_xor(ssA, 32, 64);
  sB += __shfl_xor(sB, 32, 64); ssB += __shfl_xor(ssB, 32, 64);
  if (half == 0) { redbuf[w][l31] = sA; redbuf[w][32 + l31] = sB; }
  __syncthreads();
  if (w == 0) atomicAdd(&acc2[lane], redbuf[0][lane]+redbuf[1][lane]+redbuf[2][lane]+redbuf[3][lane]);
  __syncthreads();
  if (half == 0) { redbuf[w][l31] = ssA; redbuf[w][32 + l31] = ssB; }
  __syncthreads();
  if (w == 0) atomicAdd(&acc2[64+lane], redbuf[0][lane]+redbuf[1][lane]+redbuf[2][lane]+redbuf[3][lane]);
}

// ---------------- finalize BN2 affine ----------------
__global__ void fold2_kernel(const float* __restrict__ acc2, const float* __restrict__ g2,
    const float* __restrict__ be2, float* __restrict__ s2, float* __restrict__ t2) {
  int c = threadIdx.x;
  float cnt = (float)CNT1;
  float m = acc2[c]/cnt;
  float v = acc2[64+c]/cnt - m*m;
  float sc = g2[c]*rsqrtf(v+EPSF);
  s2[c] = sc;
  t2[c] = be2[c] - m*sc;
}

// ---------------- head: Y[b,h] = relu(max_m(f@w_nn1^T)+b) ----------------
__global__ __launch_bounds__(256) void head_kernel(const float* __restrict__ maxh2,
    const int* __restrict__ fidxg, const float* __restrict__ s2g, const float* __restrict__ t2g,
    const float* __restrict__ wnn1, const float* __restrict__ bnn1, float* __restrict__ Y) {
  int b = blockIdx.x >> 2;
  int hc = blockIdx.x & 3;
  __shared__ __align__(16) float ftile[128][CC];
  __shared__ float red2[2][128];
  int hl = threadIdx.x & 127, mseg = threadIdx.x >> 7;
  int h = hc*128 + hl;
  float4 wv4[16];
  const float4* wr4 = (const float4*)(wnn1 + (size_t)h*CC);
#pragma unroll
  for (int q = 0; q < 16; ++q) wv4[q] = wr4[q];
  float best = -FLT_MAX;
  const int* fb = fidxg + b*MM;
  for (int chunk = 0; chunk < 2; ++chunk) {
    {
      int row = threadIdx.x & 127, chal = threadIdx.x >> 7;
      int fi = fb[chunk*128 + row];
      const float* src = maxh2 + (size_t)(b*NN + fi)*CC;
      for (int ci = chal*32; ci < chal*32+32; ++ci)
        ftile[row][ci] = s2g[ci]*src[ci] + t2g[ci];
    }
    __syncthreads();
    for (int m = mseg*64; m < mseg*64+64; ++m) {
      float acc = 0.f;
#pragma unroll
      for (int cq = 0; cq < 16; ++cq) {
        float4 f = *((const float4*)&ftile[m][cq*4]);
        acc = fmaf(f.x, wv4[cq].x, acc);
        acc = fmaf(f.y, wv4[cq].y, acc);
        acc = fmaf(f.z, wv4[cq].z, acc);
        acc = fmaf(f.w, wv4[cq].w, acc);
      }
      best = fmaxf(best, acc);
    }
    __syncthreads();
  }
  red2[mseg][hl] = best;
  __syncthreads();
  if (mseg == 0) {
    float v = fmaxf(red2[0][hl], red2[1][hl]) + bnn1[h];
    Y[(size_t)b*HH + h] = fmaxf(v, 0.f);
  }
}

// ---------------- BN over batch (two-pass) ----------------
__global__ void bn3_kernel(const float* __restrict__ Y, const float* __restrict__ g,
    const float* __restrict__ be, float* __restrict__ s3, float* __restrict__ t3) {
  int h = blockIdx.x*256 + threadIdx.x;
  float s = 0.f;
  for (int b = 0; b < BB; ++b) s += Y[(size_t)b*HH + h];
  float m = s / (float)BB;
  float v = 0.f;
  for (int b = 0; b < BB; ++b) { float d = Y[(size_t)b*HH + h] - m; v += d*d; }
  v /= (float)BB;
  float sc = g[h] * rsqrtf(v + EPSF);
  s3[h] = sc; t3[h] = be[h] - m*sc;
}

// ---------------- logits + log_softmax ----------------
__global__ __launch_bounds__(256) void logits_kernel(const float* __restrict__ Y,
    const float* __restrict__ s3, const float* __restrict__ t3,
    const float* __restrict__ w4, const float* __restrict__ b4, float* __restrict__ out) {
  int b = blockIdx.x;
  __shared__ float ybn[HH];
  __shared__ float lg[NCLS];
  __shared__ float lse;
  for (int hh = threadIdx.x; hh < HH; hh += 256)
    ybn[hh] = Y[(size_t)b*HH + hh]*s3[hh] + t3[hh];
  __syncthreads();
  if (threadIdx.x < NCLS) {
    int j = threadIdx.x;
    float acc = b4[j];
    const float* wr = w4 + (size_t)j*HH;
    for (int ci = 0; ci < HH; ++ci) acc = fmaf(ybn[ci], wr[ci], acc);
    lg[j] = acc;
  }
  __syncthreads();
  if (threadIdx.x == 0) {
    float mx = -FLT_MAX;
    for (int j = 0; j < NCLS; ++j) mx = fmaxf(mx, lg[j]);
    float s = 0.f;
    for (int j = 0; j < NCLS; ++j) s += expf(lg[j] - mx);
    lse = mx + logf(s);
  }
  __syncthreads();
  if (threadIdx.x < NCLS) out[b*NCLS + threadIdx.x] = lg[threadIdx.x] - lse;
}

extern "C" void kernel_launch(void* const* d_in, const int* in_sizes, int n_in,
                              void* d_out, int out_size, void* d_ws, size_t ws_size,
                              hipStream_t stream) {
  const float* pos  = (const float*)d_in[0];
  const float* w1   = (const float*)d_in[1];
  const float* b1   = (const float*)d_in[2];
  const float* g1   = (const float*)d_in[3];
  const float* be1  = (const float*)d_in[4];
  const float* w2   = (const float*)d_in[5];
  const float* b2   = (const float*)d_in[6];
  const float* g2   = (const float*)d_in[7];
  const float* be2  = (const float*)d_in[8];
  const float* wnn1 = (const float*)d_in[9];
  const float* bnn1 = (const float*)d_in[10];
  const float* gbn2 = (const float*)d_in[11];
  const float* bebn2= (const float*)d_in[12];
  const float* wnn4 = (const float*)d_in[13];
  const float* bnn4 = (const float*)d_in[14];
  float* ws = (float*)d_ws;
  int*   idxg  = (int*)(ws + IDX_OFF);
  float* maxh2 = ws + MAXH2_OFF;
  int*   fidxg = (int*)(ws + FIDX_OFF);
  float* Y     = ws + Y_OFF;
  float* acc1  = ws + ACC_OFF;
  float* acc2  = ws + ACC_OFF + 128;
  unsigned short* w2bf = (unsigned short*)(ws + W2T_OFF);
  float* b2f   = ws + B2F_OFF;
  float* s2    = ws + S2_OFF;
  float* t2    = ws + T2_OFF;
  float* s3    = ws + S3_OFF;
  float* t3    = ws + T3_OFF;
  float* outp  = (float*)d_out;

  hipMemsetAsync((void*)(ws + ACC_OFF), 0, 256*sizeof(float), stream);
  knn_fps_kernel<<<BB*16 + BB, 256, 0, stream>>>(pos, idxg, fidxg);
  stats1_kernel<<<BB*16, 256, 0, stream>>>(pos, idxg, w1, b1, acc1);
  fold1_kernel<<<1, 512, 0, stream>>>(acc1, g1, be1, w2, b2, w2bf, b2f);
  conv2_kernel<<<BB*16, 256, 0, stream>>>(pos, idxg, w1, b1, w2bf, b2f, maxh2, acc2);
  fold2_kernel<<<1, 64, 0, stream>>>(acc2, g2, be2, s2, t2);
  head_kernel<<<BB*4, 256, 0, stream>>>(maxh2, fidxg, s2, t2, wnn1, bnn1, Y);
  bn3_kernel<<<2, 256, 0, stream>>>(Y, gbn2, bebn2, s3, t3);
  logits_kernel<<<BB, 256, 0, stream>>>(Y, s3, t3, wnn4, bnn4, outp);
}

// Round 5
// 528.997 us; speedup vs baseline: 3.4592x; 1.0648x over previous
//
#include <hip/hip_runtime.h>
#include <hip/hip_bf16.h>
#include <cfloat>
#include <math.h>

#define BB 64
#define NN 1024
#define KNN 20
#define MM 256
#define CC 64
#define HH 512
#define NCLS 40
#define EPSF 1e-5f
#define CNT1 (BB*NN*KNN)

// workspace offsets (in 4-byte elements)
#define IDX_OFF    0
#define MAXH2_OFF  (IDX_OFF + BB*NN*KNN)      // int idx then floats
#define FIDX_OFF   (MAXH2_OFF + BB*NN*CC)
#define Y_OFF      (FIDX_OFF + BB*MM)
#define ACC_OFF    (Y_OFF + BB*HH)            // 256 floats zeroed: sum1[64],sumsq1[64],sum2[64],sumsq2[64]
#define W2T_OFF    (ACC_OFF + 256)            // w2' bf16 B-frags (2048 ushorts) + b2f
#define B2F_OFF    (W2T_OFF + CC*CC)
#define S2_OFF     (B2F_OFF + CC)
#define T2_OFF     (S2_OFF + CC)
#define S3_OFF     (T2_OFF + CC)
#define T3_OFF     (S3_OFF + HH)

typedef __attribute__((ext_vector_type(8)))  short short8;
typedef __attribute__((ext_vector_type(16))) float f32x16;

static __device__ __forceinline__ unsigned short f2bf(float f) {
  unsigned u = __float_as_uint(f);
  unsigned r = (u + 0x7fffu + ((u >> 16) & 1u)) >> 16;   // RNE
  return (unsigned short)r;
}

// ---------------- fused kNN + FPS ----------------
// blocks [0, BB*32): kNN, one wave per 8 queries. Top-20 selection via
// 16-step binary search on the TOP 16 BITS of the orderable-uint distance;
// if the <=bucket_top count is exactly 20 the set is exact (downstream is
// set-symmetric over k), else exact (value,index) extraction from the
// boundary bucket — matches lax.top_k tie semantics bit-exactly.
// blocks [BB*32, BB*32+BB): single-wave FPS (registers, no barriers).
__global__ __launch_bounds__(256) void knn_fps_kernel(const float* __restrict__ pos,
                                                      int* __restrict__ idxg,
                                                      int* __restrict__ fidxg) {
  __shared__ float4 pj[NN];
  if (blockIdx.x < BB*32) {
    // ---------------- kNN branch ----------------
    int b  = blockIdx.x >> 5;   // cloud
    int nb = blockIdx.x & 31;   // 32-point segment of the cloud
    const float* pb = pos + (size_t)b * NN * 3;
    for (int i = threadIdx.x; i < NN; i += 256) {
      float x = pb[i*3+0], y = pb[i*3+1], z = pb[i*3+2];
      pj[i] = make_float4(x, y, z, (x*x + y*y) + z*z);
    }
    __syncthreads();
    int lane = threadIdx.x & 63;
    int wv   = threadIdx.x >> 6;
    unsigned long long lmask_lt = (1ULL << lane) - 1ULL;

    for (int t = 0; t < 8; ++t) {
      int i = nb*32 + wv*8 + t;        // query point (wave-uniform)
      float4 pi = pj[i];               // LDS broadcast
      unsigned u[16];
#pragma unroll
      for (int q = 0; q < 16; ++q) {
        int j = q*64 + lane;
        float4 pw = pj[j];
        float d = pi.w + pw.w - 2.0f*(pi.x*pw.x + pi.y*pw.y + pi.z*pw.z);
        unsigned bits = __float_as_uint(d);
        bits = (bits & 0x80000000u) ? ~bits : (bits | 0x80000000u);
        if (j == i) bits = 0xFFFFFFFFu;   // self excluded (diag = +inf)
        u[q] = bits;
      }
      // 16-step binary search over the top-16-bit prefix
      unsigned plo = 0u, phi = 0xFFFFu;
      while (plo < phi) {                 // wave-uniform, <=16 rounds
        unsigned pmid = (plo + phi) >> 1;
        unsigned tmid = (pmid << 16) | 0xFFFFu;
        int cnt = 0;
#pragma unroll
        for (int q = 0; q < 16; ++q)
          cnt += (int)__popcll(__ballot(u[q] <= tmid));
        if (cnt >= KNN) phi = pmid; else plo = pmid + 1;
      }
      unsigned tstar = (plo << 16) | 0xFFFFu;  // bucket top
      unsigned bbase = plo << 16;              // bucket base
      int* op = idxg + (size_t)(b*NN + i) * KNN;
      int cnt20 = 0;
#pragma unroll
      for (int q = 0; q < 16; ++q)
        cnt20 += (int)__popcll(__ballot(u[q] <= tstar));
      if (cnt20 == KNN) {
        // exact set: emit all <= tstar (index order; set-equivalent)
        int base = 0;
#pragma unroll
        for (int q = 0; q < 16; ++q) {
          bool pred = (u[q] <= tstar);
          unsigned long long mask = __ballot((int)pred);
          if (pred) op[base + (int)__popcll(mask & lmask_lt)] = q*64 + lane;
          base += (int)__popcll(mask);
        }
      } else {
        // slow path: strictly-below-bucket all in; extract rest from bucket
        int base = 0;
        unsigned bmask = 0u;
#pragma unroll
        for (int q = 0; q < 16; ++q) {
          bool pred = (u[q] < bbase);
          unsigned long long mask = __ballot((int)pred);
          if (pred) op[base + (int)__popcll(mask & lmask_lt)] = q*64 + lane;
          base += (int)__popcll(mask);
          if (u[q] >= bbase && u[q] <= tstar) bmask |= (1u << q);
        }
        for (int r = base; r < KNN; ++r) {   // exact (value,index) extraction
          unsigned long long lkey = 0xFFFFFFFFFFFFFFFFULL;
#pragma unroll
          for (int q = 0; q < 16; ++q) {
            if (bmask & (1u << q)) {
              unsigned long long k2 = ((unsigned long long)u[q] << 32)
                                    | (unsigned)(q*64 + lane);
              if (k2 < lkey) lkey = k2;
            }
          }
#pragma unroll
          for (int off = 32; off >= 1; off >>= 1) {
            unsigned long long o = __shfl_xor(lkey, off, 64);
            if (o < lkey) lkey = o;
          }
          int jj = (int)(lkey & 0xFFFFFFFFULL);
          if (lane == 0) op[r] = jj;
#pragma unroll
          for (int q = 0; q < 16; ++q)
            if ((q*64 + lane) == jj) bmask &= ~(1u << q);
        }
      }
    }
  } else {
    // ---------------- FPS branch: single wave, registers, no barriers ----------------
    int b = blockIdx.x - BB*32;
    const float* pb = pos + (size_t)b * NN * 3;
    for (int i = threadIdx.x; i < NN; i += 256)
      pj[i] = make_float4(pb[i*3], pb[i*3+1], pb[i*3+2], 0.f);
    __syncthreads();
    if (threadIdx.x >= 64) return;   // waves 1-3 done (after barrier)
    int lane = threadIdx.x;
    float px[16], py[16], pz[16], dist[16];
#pragma unroll
    for (int q = 0; q < 16; ++q) {
      float4 p = pj[q*64 + lane];
      px[q] = p.x; py[q] = p.y; pz[q] = p.z;
      dist[q] = 1e38f;
    }
    if (lane == 0) fidxg[b*MM] = 0;
    int cur = 0;
    for (int m = 1; m < MM; ++m) {
      float4 cp = pj[cur];             // wave-uniform LDS broadcast
      unsigned long long key[16];
#pragma unroll
      for (int q = 0; q < 16; ++q) {
        float dx = __fsub_rn(px[q], cp.x);
        float dy = __fsub_rn(py[q], cp.y);
        float dz = __fsub_rn(pz[q], cp.z);
        float dd = __fadd_rn(__fadd_rn(__fmul_rn(dx,dx), __fmul_rn(dy,dy)), __fmul_rn(dz,dz));
        float dq = fminf(dist[q], dd);
        dist[q] = dq;
        key[q] = ((unsigned long long)__float_as_uint(dq) << 32)
               | (unsigned)(NN - 1 - (q*64 + lane));
      }
#pragma unroll
      for (int s = 8; s >= 1; s >>= 1)
#pragma unroll
        for (int q = 0; q < s; ++q)
          if (key[q + s] > key[q]) key[q] = key[q + s];
      unsigned long long best = key[0];
#pragma unroll
      for (int off = 32; off >= 1; off >>= 1) {
        unsigned long long o = __shfl_xor(best, off, 64);
        if (o > best) best = o;
      }
      cur = NN - 1 - (int)(best & 0xFFFFFFFFu);
      if (lane == 0) fidxg[b*MM + m] = cur;
    }
  }
}

// ---------------- stats of h1 = relu(rel@w1+b1) ----------------
__global__ __launch_bounds__(256) void stats1_kernel(const float* __restrict__ pos,
    const int* __restrict__ idxg, const float* __restrict__ w1,
    const float* __restrict__ b1, float* __restrict__ acc) {
  int b = blockIdx.x >> 4;
  int nb = blockIdx.x & 15;
  __shared__ float px[NN], py[NN], pz[NN];
  __shared__ float relx[4][KNN], rely[4][KNN], relz[4][KNN];
  __shared__ float red[4][CC];
  const float* pb = pos + (size_t)b*NN*3;
  for (int i = threadIdx.x; i < NN; i += 256) {
    px[i] = pb[i*3+0]; py[i] = pb[i*3+1]; pz[i] = pb[i*3+2];
  }
  int c = threadIdx.x & 63, w = threadIdx.x >> 6;
  float w1x = w1[c*3+0], w1y = w1[c*3+1], w1z = w1[c*3+2], b1c = b1[c];
  float s = 0.f, ss = 0.f;
  __syncthreads();
  for (int it = 0; it < 16; ++it) {
    int n0 = nb*64 + it*4;
    if (threadIdx.x < 80) {
      int wv = threadIdx.x / KNN, k = threadIdx.x % KNN;
      int n = n0 + wv;
      int j = idxg[(size_t)(b*NN + n)*KNN + k];
      relx[wv][k] = px[j] - px[n];
      rely[wv][k] = py[j] - py[n];
      relz[wv][k] = pz[j] - pz[n];
    }
    __syncthreads();
#pragma unroll
    for (int k = 0; k < KNN; ++k) {
      float h = fmaxf(relx[w][k]*w1x + rely[w][k]*w1y + relz[w][k]*w1z + b1c, 0.f);
      s += h; ss += h*h;
    }
    __syncthreads();
  }
  red[w][c] = s; __syncthreads();
  if (w == 0) atomicAdd(&acc[c], red[0][c]+red[1][c]+red[2][c]+red[3][c]);
  __syncthreads();
  red[w][c] = ss; __syncthreads();
  if (w == 0) atomicAdd(&acc[64+c], red[0][c]+red[1][c]+red[2][c]+red[3][c]);
}

// ---------------- fold BN1 into w2 (bf16 B-fragment layout) ----------------
// w2bf[((nt*4+ks)*64 + lane)*8 + j] = bf16(w2[cout][cin] * s1[cin])
//   cout = nt*32 + (lane&31), cin = ks*16 + (lane>>5)*8 + j
__global__ void fold1_kernel(const float* __restrict__ acc, const float* __restrict__ g1,
    const float* __restrict__ be1, const float* __restrict__ w2, const float* __restrict__ b2,
    unsigned short* __restrict__ w2bf, float* __restrict__ b2f) {
  __shared__ float s1[CC], t1[CC];
  int tid = threadIdx.x;  // 512 threads
  if (tid < CC) {
    float cnt = (float)CNT1;
    float m = acc[tid] / cnt;
    float v = acc[64+tid] / cnt - m*m;
    float sc = g1[tid] * rsqrtf(v + EPSF);
    s1[tid] = sc; t1[tid] = be1[tid] - m*sc;
  }
  __syncthreads();
  int frag = tid >> 6;        // 0..7  (nt = frag>>2, ks = frag&3)
  int lane = tid & 63;
  int nt = frag >> 2, ks = frag & 3;
  int cout = nt*32 + (lane & 31);
  int cin0 = ks*16 + (lane >> 5)*8;
  for (int j = 0; j < 8; ++j) {
    int cin = cin0 + j;
    w2bf[((size_t)frag*64 + lane)*8 + j] = f2bf(w2[cout*CC + cin] * s1[cin]);
  }
  if (tid < CC) {
    float accb = b2[tid];
    for (int ci = 0; ci < CC; ++ci) accb += t1[ci]*w2[tid*CC + ci];
    b2f[tid] = accb;
  }
}

// ---------------- conv2 via MFMA: h2 = relu(h1@w2'+b2'), maxh2 + stats ----------------
__global__ __launch_bounds__(256, 4) void conv2_kernel(const float* __restrict__ pos,
    const int* __restrict__ idxg, const float* __restrict__ w1, const float* __restrict__ b1,
    const unsigned short* __restrict__ w2bf, const float* __restrict__ b2fg,
    float* __restrict__ maxh2, float* __restrict__ acc2) {
  int b = blockIdx.x >> 4;
  int nb = blockIdx.x & 15;
  __shared__ float px[NN], py[NN], pz[NN];
  __shared__ float4 relw[4][KNN];
  __shared__ __align__(16) unsigned short h1s[4][2112];  // 8 groups * 264 ushorts
  __shared__ float redbuf[4][2*CC];
  const float* pb = pos + (size_t)b*NN*3;
  for (int i = threadIdx.x; i < NN; i += 256) {
    px[i] = pb[i*3+0]; py[i] = pb[i*3+1]; pz[i] = pb[i*3+2];
  }
  int lane = threadIdx.x & 63, w = threadIdx.x >> 6;
  int half = lane >> 5, l31 = lane & 31;
  short8 Bf[2][4];
#pragma unroll
  for (int nt = 0; nt < 2; ++nt)
#pragma unroll
    for (int ks = 0; ks < 4; ++ks)
      Bf[nt][ks] = *(const short8*)&w2bf[((size_t)(nt*4+ks)*64 + lane)*8];
  float b2o0 = b2fg[l31], b2o1 = b2fg[32 + l31];
  float w1x = w1[lane*3+0], w1y = w1[lane*3+1], w1z = w1[lane*3+2], b1c = b1[lane];
  unsigned short* hw = h1s[w];
  {
    short8 zz = {0,0,0,0,0,0,0,0};
    for (int z = lane; z < 96; z += 64) {
      int g = z / 12, r = 20 + z % 12;
      *(short8*)&hw[g*264 + r*8] = zz;
    }
  }
  float sA = 0.f, ssA = 0.f, sB = 0.f, ssB = 0.f;
  __syncthreads();
  for (int t = 0; t < 16; ++t) {
    int n = nb*64 + w*16 + t;
    if (lane < KNN) {
      int j = idxg[(size_t)(b*NN + n)*KNN + lane];
      relw[w][lane] = make_float4(px[j]-px[n], py[j]-py[n], pz[j]-pz[n], 0.f);
    }
    int gbase = (lane >> 3)*264 + (lane & 7);
#pragma unroll
    for (int k = 0; k < KNN; ++k) {
      float4 r4 = relw[w][k];   // wave-uniform broadcast read
      float h = fmaxf(fmaf(r4.x, w1x, fmaf(r4.y, w1y, fmaf(r4.z, w1z, b1c))), 0.f);
      hw[gbase + k*8] = f2bf(h);
    }
    f32x16 acc0 = {}; f32x16 acc1 = {};
#pragma unroll
    for (int ks = 0; ks < 4; ++ks) {
      short8 A = *(const short8*)&hw[(ks*2 + half)*264 + l31*8];
      acc0 = __builtin_amdgcn_mfma_f32_32x32x16_bf16(A, Bf[0][ks], acc0, 0, 0, 0);
      acc1 = __builtin_amdgcn_mfma_f32_32x32x16_bf16(A, Bf[1][ks], acc1, 0, 0, 0);
    }
    float mx0 = 0.f, mx1 = 0.f;
#pragma unroll
    for (int reg = 0; reg < 8; ++reg) {
      float v0 = fmaxf(acc0[reg] + b2o0, 0.f);
      float v1 = fmaxf(acc1[reg] + b2o1, 0.f);
      sA += v0; ssA += v0*v0; sB += v1; ssB += v1*v1;
      mx0 = fmaxf(mx0, v0); mx1 = fmaxf(mx1, v1);
    }
    if (half == 0) {
#pragma unroll
      for (int reg = 8; reg < 12; ++reg) {
        float v0 = fmaxf(acc0[reg] + b2o0, 0.f);
        float v1 = fmaxf(acc1[reg] + b2o1, 0.f);
        sA += v0; ssA += v0*v0; sB += v1; ssB += v1*v1;
        mx0 = fmaxf(mx0, v0); mx1 = fmaxf(mx1, v1);
      }
    }
    mx0 = fmaxf(mx0, __shfl_xor(mx0, 32, 64));
    mx1 = fmaxf(mx1, __shfl_xor(mx1, 32, 64));
    if (half == 0) {
      float* mp = maxh2 + (size_t)(b*NN + n)*CC;
      mp[l31] = mx0; mp[32 + l31] = mx1;
    }
  }
  sA += __shfl_xor(sA, 32, 64); ssA += __shfl_xor(ssA, 32, 64);
  sB += __shfl_xor(sB, 32, 64); ssB += __shfl_xor(ssB, 32, 64);
  if (half == 0) { redbuf[w][l31] = sA; redbuf[w][32 + l31] = sB; }
  __syncthreads();
  if (w == 0) atomicAdd(&acc2[lane], redbuf[0][lane]+redbuf[1][lane]+redbuf[2][lane]+redbuf[3][lane]);
  __syncthreads();
  if (half == 0) { redbuf[w][l31] = ssA; redbuf[w][32 + l31] = ssB; }
  __syncthreads();
  if (w == 0) atomicAdd(&acc2[64+lane], redbuf[0][lane]+redbuf[1][lane]+redbuf[2][lane]+redbuf[3][lane]);
}

// ---------------- finalize BN2 affine ----------------
__global__ void fold2_kernel(const float* __restrict__ acc2, const float* __restrict__ g2,
    const float* __restrict__ be2, float* __restrict__ s2, float* __restrict__ t2) {
  int c = threadIdx.x;
  float cnt = (float)CNT1;
  float m = acc2[c]/cnt;
  float v = acc2[64+c]/cnt - m*m;
  float sc = g2[c]*rsqrtf(v+EPSF);
  s2[c] = sc;
  t2[c] = be2[c] - m*sc;
}

// ---------------- head: Y[b,h] = relu(max_m(f@w_nn1^T)+b) ----------------
__global__ __launch_bounds__(256) void head_kernel(const float* __restrict__ maxh2,
    const int* __restrict__ fidxg, const float* __restrict__ s2g, const float* __restrict__ t2g,
    const float* __restrict__ wnn1, const float* __restrict__ bnn1, float* __restrict__ Y) {
  int b = blockIdx.x >> 2;
  int hc = blockIdx.x & 3;
  __shared__ __align__(16) float ftile[128][CC];
  __shared__ float red2[2][128];
  int hl = threadIdx.x & 127, mseg = threadIdx.x >> 7;
  int h = hc*128 + hl;
  float4 wv4[16];
  const float4* wr4 = (const float4*)(wnn1 + (size_t)h*CC);
#pragma unroll
  for (int q = 0; q < 16; ++q) wv4[q] = wr4[q];
  float best = -FLT_MAX;
  const int* fb = fidxg + b*MM;
  for (int chunk = 0; chunk < 2; ++chunk) {
    {
      int row = threadIdx.x & 127, chal = threadIdx.x >> 7;
      int fi = fb[chunk*128 + row];
      const float* src = maxh2 + (size_t)(b*NN + fi)*CC;
      for (int ci = chal*32; ci < chal*32+32; ++ci)
        ftile[row][ci] = s2g[ci]*src[ci] + t2g[ci];
    }
    __syncthreads();
    for (int m = mseg*64; m < mseg*64+64; ++m) {
      float acc = 0.f;
#pragma unroll
      for (int cq = 0; cq < 16; ++cq) {
        float4 f = *((const float4*)&ftile[m][cq*4]);
        acc = fmaf(f.x, wv4[cq].x, acc);
        acc = fmaf(f.y, wv4[cq].y, acc);
        acc = fmaf(f.z, wv4[cq].z, acc);
        acc = fmaf(f.w, wv4[cq].w, acc);
      }
      best = fmaxf(best, acc);
    }
    __syncthreads();
  }
  red2[mseg][hl] = best;
  __syncthreads();
  if (mseg == 0) {
    float v = fmaxf(red2[0][hl], red2[1][hl]) + bnn1[h];
    Y[(size_t)b*HH + h] = fmaxf(v, 0.f);
  }
}

// ---------------- BN over batch (two-pass) ----------------
__global__ void bn3_kernel(const float* __restrict__ Y, const float* __restrict__ g,
    const float* __restrict__ be, float* __restrict__ s3, float* __restrict__ t3) {
  int h = blockIdx.x*256 + threadIdx.x;
  float s = 0.f;
  for (int b = 0; b < BB; ++b) s += Y[(size_t)b*HH + h];
  float m = s / (float)BB;
  float v = 0.f;
  for (int b = 0; b < BB; ++b) { float d = Y[(size_t)b*HH + h] - m; v += d*d; }
  v /= (float)BB;
  float sc = g[h] * rsqrtf(v + EPSF);
  s3[h] = sc; t3[h] = be[h] - m*sc;
}

// ---------------- logits + log_softmax ----------------
__global__ __launch_bounds__(256) void logits_kernel(const float* __restrict__ Y,
    const float* __restrict__ s3, const float* __restrict__ t3,
    const float* __restrict__ w4, const float* __restrict__ b4, float* __restrict__ out) {
  int b = blockIdx.x;
  __shared__ float ybn[HH];
  __shared__ float lg[NCLS];
  __shared__ float lse;
  for (int hh = threadIdx.x; hh < HH; hh += 256)
    ybn[hh] = Y[(size_t)b*HH + hh]*s3[hh] + t3[hh];
  __syncthreads();
  if (threadIdx.x < NCLS) {
    int j = threadIdx.x;
    float acc = b4[j];
    const float* wr = w4 + (size_t)j*HH;
    for (int ci = 0; ci < HH; ++ci) acc = fmaf(ybn[ci], wr[ci], acc);
    lg[j] = acc;
  }
  __syncthreads();
  if (threadIdx.x == 0) {
    float mx = -FLT_MAX;
    for (int j = 0; j < NCLS; ++j) mx = fmaxf(mx, lg[j]);
    float s = 0.f;
    for (int j = 0; j < NCLS; ++j) s += expf(lg[j] - mx);
    lse = mx + logf(s);
  }
  __syncthreads();
  if (threadIdx.x < NCLS) out[b*NCLS + threadIdx.x] = lg[threadIdx.x] - lse;
}

extern "C" void kernel_launch(void* const* d_in, const int* in_sizes, int n_in,
                              void* d_out, int out_size, void* d_ws, size_t ws_size,
                              hipStream_t stream) {
  const float* pos  = (const float*)d_in[0];
  const float* w1   = (const float*)d_in[1];
  const float* b1   = (const float*)d_in[2];
  const float* g1   = (const float*)d_in[3];
  const float* be1  = (const float*)d_in[4];
  const float* w2   = (const float*)d_in[5];
  const float* b2   = (const float*)d_in[6];
  const float* g2   = (const float*)d_in[7];
  const float* be2  = (const float*)d_in[8];
  const float* wnn1 = (const float*)d_in[9];
  const float* bnn1 = (const float*)d_in[10];
  const float* gbn2 = (const float*)d_in[11];
  const float* bebn2= (const float*)d_in[12];
  const float* wnn4 = (const float*)d_in[13];
  const float* bnn4 = (const float*)d_in[14];
  float* ws = (float*)d_ws;
  int*   idxg  = (int*)(ws + IDX_OFF);
  float* maxh2 = ws + MAXH2_OFF;
  int*   fidxg = (int*)(ws + FIDX_OFF);
  float* Y     = ws + Y_OFF;
  float* acc1  = ws + ACC_OFF;
  float* acc2  = ws + ACC_OFF + 128;
  unsigned short* w2bf = (unsigned short*)(ws + W2T_OFF);
  float* b2f   = ws + B2F_OFF;
  float* s2    = ws + S2_OFF;
  float* t2    = ws + T2_OFF;
  float* s3    = ws + S3_OFF;
  float* t3    = ws + T3_OFF;
  float* outp  = (float*)d_out;

  hipMemsetAsync((void*)(ws + ACC_OFF), 0, 256*sizeof(float), stream);
  knn_fps_kernel<<<BB*32 + BB, 256, 0, stream>>>(pos, idxg, fidxg);
  stats1_kernel<<<BB*16, 256, 0, stream>>>(pos, idxg, w1, b1, acc1);
  fold1_kernel<<<1, 512, 0, stream>>>(acc1, g1, be1, w2, b2, w2bf, b2f);
  conv2_kernel<<<BB*16, 256, 0, stream>>>(pos, idxg, w1, b1, w2bf, b2f, maxh2, acc2);
  fold2_kernel<<<1, 64, 0, stream>>>(acc2, g2, be2, s2, t2);
  head_kernel<<<BB*4, 256, 0, stream>>>(maxh2, fidxg, s2, t2, wnn1, bnn1, Y);
  bn3_kernel<<<2, 256, 0, stream>>>(Y, gbn2, bebn2, s3, t3);
  logits_kernel<<<BB, 256, 0, stream>>>(Y, s3, t3, wnn4, bnn4, outp);
}

// Round 6
// 436.808 us; speedup vs baseline: 4.1892x; 1.2111x over previous
//
#include <hip/hip_runtime.h>
#include <hip/hip_bf16.h>
#include <cfloat>
#include <math.h>

#define BB 64
#define NN 1024
#define KNN 20
#define MM 256
#define CC 64
#define HH 512
#define NCLS 40
#define EPSF 1e-5f
#define CNT1 (BB*NN*KNN)

// workspace offsets (in 4-byte elements)
#define IDX_OFF    0
#define MAXH2_OFF  (IDX_OFF + BB*NN*KNN)      // int idx then floats
#define FIDX_OFF   (MAXH2_OFF + BB*NN*CC)
#define Y_OFF      (FIDX_OFF + BB*MM)
#define ACC_OFF    (Y_OFF + BB*HH)            // 256 floats zeroed: sum1[64],sumsq1[64],sum2[64],sumsq2[64]
#define W2T_OFF    (ACC_OFF + 256)            // w2' bf16 B-frags (2048 ushorts) + b2f
#define B2F_OFF    (W2T_OFF + CC*CC)
#define S2_OFF     (B2F_OFF + CC)
#define T2_OFF     (S2_OFF + CC)
#define S3_OFF     (T2_OFF + CC)
#define T3_OFF     (S3_OFF + HH)

typedef __attribute__((ext_vector_type(8)))  short short8;
typedef __attribute__((ext_vector_type(16))) float f32x16;

static __device__ __forceinline__ unsigned short f2bf(float f) {
  unsigned u = __float_as_uint(f);
  unsigned r = (u + 0x7fffu + ((u >> 16) & 1u)) >> 16;   // RNE
  return (unsigned short)r;
}

// ---------------- fused FPS + kNN ----------------
// blocks [0, BB): single-wave FPS (registers, DPP cross-lane reduce, no
// barriers in the serial loop). Placed FIRST so the serial chains start
// immediately and hide under the kNN blocks.
// blocks [BB, BB + BB*32): kNN, one wave per 8 queries. 16-step binary
// search on the top-16-bit prefix; exact-count fast path emits directly,
// slow path refines the low 16 bits (exact 20th value) + two-pass emission.
__global__ __launch_bounds__(256) void knn_fps_kernel(const float* __restrict__ pos,
                                                      int* __restrict__ idxg,
                                                      int* __restrict__ fidxg) {
  __shared__ float4 pj[NN];
  if (blockIdx.x >= BB) {
    // ---------------- kNN branch ----------------
    int blk = blockIdx.x - BB;
    int b  = blk >> 5;   // cloud
    int nb = blk & 31;   // 32-point segment of the cloud
    const float* pb = pos + (size_t)b * NN * 3;
    for (int i = threadIdx.x; i < NN; i += 256) {
      float x = pb[i*3+0], y = pb[i*3+1], z = pb[i*3+2];
      pj[i] = make_float4(x, y, z, (x*x + y*y) + z*z);
    }
    __syncthreads();
    int lane = threadIdx.x & 63;
    int wv   = threadIdx.x >> 6;
    unsigned long long lmask_lt = (1ULL << lane) - 1ULL;

    for (int t = 0; t < 8; ++t) {
      int i = nb*32 + wv*8 + t;        // query point (wave-uniform)
      float4 pi = pj[i];               // LDS broadcast
      unsigned u[16];
#pragma unroll
      for (int q = 0; q < 16; ++q) {
        int j = q*64 + lane;
        float4 pw = pj[j];
        float d = pi.w + pw.w - 2.0f*(pi.x*pw.x + pi.y*pw.y + pi.z*pw.z);
        unsigned bits = __float_as_uint(d);
        bits = (bits & 0x80000000u) ? ~bits : (bits | 0x80000000u);
        if (j == i) bits = 0xFFFFFFFFu;   // self excluded (diag = +inf)
        u[q] = bits;
      }
      // 16-step binary search over the top-16-bit prefix
      unsigned plo = 0u, phi = 0xFFFFu;
      while (plo < phi) {                 // wave-uniform, <=16 rounds
        unsigned pmid = (plo + phi) >> 1;
        unsigned tmid = (pmid << 16) | 0xFFFFu;
        int cnt = 0;
#pragma unroll
        for (int q = 0; q < 16; ++q)
          cnt += (int)__popcll(__ballot(u[q] <= tmid));
        if (cnt >= KNN) phi = pmid; else plo = pmid + 1;
      }
      unsigned tstar = (plo << 16) | 0xFFFFu;  // bucket top
      unsigned bbase = plo << 16;              // bucket base
      int* op = idxg + (size_t)(b*NN + i) * KNN;
      int cnt20 = 0;
#pragma unroll
      for (int q = 0; q < 16; ++q)
        cnt20 += (int)__popcll(__ballot(u[q] <= tstar));
      if (cnt20 == KNN) {
        // exact set: emit all <= tstar (index order; set-equivalent)
        int base = 0;
#pragma unroll
        for (int q = 0; q < 16; ++q) {
          bool pred = (u[q] <= tstar);
          unsigned long long mask = __ballot((int)pred);
          if (pred) op[base + (int)__popcll(mask & lmask_lt)] = q*64 + lane;
          base += (int)__popcll(mask);
        }
      } else {
        // slow path: refine low 16 bits -> exact 20th value xstar
        unsigned lo2 = bbase, hi2 = tstar;
        while (lo2 < hi2) {
          unsigned mid = lo2 + ((hi2 - lo2) >> 1);
          int cnt = 0;
#pragma unroll
          for (int q = 0; q < 16; ++q)
            cnt += (int)__popcll(__ballot(u[q] <= mid));
          if (cnt >= KNN) hi2 = mid; else lo2 = mid + 1;
        }
        unsigned xstar = lo2;
        int base = 0;
#pragma unroll
        for (int q = 0; q < 16; ++q) {
          bool pred = (u[q] < xstar);
          unsigned long long mask = __ballot((int)pred);
          if (pred) op[base + (int)__popcll(mask & lmask_lt)] = q*64 + lane;
          base += (int)__popcll(mask);
        }
        for (int q = 0; q < 16 && base < KNN; ++q) {  // ties, ascending index
          bool pred = (u[q] == xstar);
          unsigned long long mask = __ballot((int)pred);
          if (pred) {
            int pos_ = base + (int)__popcll(mask & lmask_lt);
            if (pos_ < KNN) op[pos_] = q*64 + lane;
          }
          base += (int)__popcll(mask);
        }
      }
    }
  } else {
    // ---------------- FPS branch: single wave, DPP reduce, no barriers ----------------
    int b = blockIdx.x;
    const float* pb = pos + (size_t)b * NN * 3;
    for (int i = threadIdx.x; i < NN; i += 256)
      pj[i] = make_float4(pb[i*3], pb[i*3+1], pb[i*3+2], 0.f);
    __syncthreads();
    if (threadIdx.x >= 64) return;   // waves 1-3 done (after barrier)
    int lane = threadIdx.x;
    float px[16], py[16], pz[16], dist[16];
#pragma unroll
    for (int q = 0; q < 16; ++q) {
      float4 p = pj[q*64 + lane];
      px[q] = p.x; py[q] = p.y; pz[q] = p.z;
      dist[q] = 1e38f;
    }
    if (lane == 0) fidxg[b*MM] = 0;
    int cur = 0;
    for (int m = 1; m < MM; ++m) {
      float4 cp = pj[cur];             // wave-uniform LDS broadcast
      unsigned long long key[16];
#pragma unroll
      for (int q = 0; q < 16; ++q) {
        float dx = __fsub_rn(px[q], cp.x);
        float dy = __fsub_rn(py[q], cp.y);
        float dz = __fsub_rn(pz[q], cp.z);
        float dd = __fadd_rn(__fadd_rn(__fmul_rn(dx,dx), __fmul_rn(dy,dy)), __fmul_rn(dz,dz));
        float dq = fminf(dist[q], dd);
        dist[q] = dq;
        key[q] = ((unsigned long long)__float_as_uint(dq) << 32)
               | (unsigned)(NN - 1 - (q*64 + lane));
      }
      // in-register tree max (max dist; ties -> smallest index)
#pragma unroll
      for (int s = 8; s >= 1; s >>= 1)
#pragma unroll
        for (int q = 0; q < s; ++q)
          if (key[q + s] > key[q]) key[q] = key[q + s];
      // cross-lane max via DPP (row_shr 1/2/4/8 + row_bcast 15/31), result in lane 63
      unsigned klo = (unsigned)key[0], khi = (unsigned)(key[0] >> 32);
#define FPS_DPP_STEP(C) { \
      unsigned tlo = (unsigned)__builtin_amdgcn_update_dpp((int)klo, (int)klo, (C), 0xf, 0xf, false); \
      unsigned thi = (unsigned)__builtin_amdgcn_update_dpp((int)khi, (int)khi, (C), 0xf, 0xf, false); \
      if (thi > khi || (thi == khi && tlo > klo)) { khi = thi; klo = tlo; } }
      FPS_DPP_STEP(0x111)   // row_shr:1
      FPS_DPP_STEP(0x112)   // row_shr:2
      FPS_DPP_STEP(0x114)   // row_shr:4
      FPS_DPP_STEP(0x118)   // row_shr:8
      FPS_DPP_STEP(0x142)   // row_bcast:15
      FPS_DPP_STEP(0x143)   // row_bcast:31
#undef FPS_DPP_STEP
      unsigned wlo = (unsigned)__builtin_amdgcn_readlane((int)klo, 63);
      cur = (NN - 1) - (int)wlo;
      if (lane == 0) fidxg[b*MM + m] = cur;
    }
  }
}

// ---------------- stats of h1 = relu(rel@w1+b1) ----------------
__global__ __launch_bounds__(256) void stats1_kernel(const float* __restrict__ pos,
    const int* __restrict__ idxg, const float* __restrict__ w1,
    const float* __restrict__ b1, float* __restrict__ acc) {
  int b = blockIdx.x >> 4;
  int nb = blockIdx.x & 15;
  __shared__ float px[NN], py[NN], pz[NN];
  __shared__ float relx[4][KNN], rely[4][KNN], relz[4][KNN];
  __shared__ float red[4][CC];
  const float* pb = pos + (size_t)b*NN*3;
  for (int i = threadIdx.x; i < NN; i += 256) {
    px[i] = pb[i*3+0]; py[i] = pb[i*3+1]; pz[i] = pb[i*3+2];
  }
  int c = threadIdx.x & 63, w = threadIdx.x >> 6;
  float w1x = w1[c*3+0], w1y = w1[c*3+1], w1z = w1[c*3+2], b1c = b1[c];
  float s = 0.f, ss = 0.f;
  __syncthreads();
  for (int it = 0; it < 16; ++it) {
    int n0 = nb*64 + it*4;
    if (threadIdx.x < 80) {
      int wv = threadIdx.x / KNN, k = threadIdx.x % KNN;
      int n = n0 + wv;
      int j = idxg[(size_t)(b*NN + n)*KNN + k];
      relx[wv][k] = px[j] - px[n];
      rely[wv][k] = py[j] - py[n];
      relz[wv][k] = pz[j] - pz[n];
    }
    __syncthreads();
#pragma unroll
    for (int k = 0; k < KNN; ++k) {
      float h = fmaxf(relx[w][k]*w1x + rely[w][k]*w1y + relz[w][k]*w1z + b1c, 0.f);
      s += h; ss += h*h;
    }
    __syncthreads();
  }
  red[w][c] = s; __syncthreads();
  if (w == 0) atomicAdd(&acc[c], red[0][c]+red[1][c]+red[2][c]+red[3][c]);
  __syncthreads();
  red[w][c] = ss; __syncthreads();
  if (w == 0) atomicAdd(&acc[64+c], red[0][c]+red[1][c]+red[2][c]+red[3][c]);
}

// ---------------- fold BN1 into w2 (bf16 B-fragment layout) ----------------
// w2bf[((nt*4+ks)*64 + lane)*8 + j] = bf16(w2[cout][cin] * s1[cin])
//   cout = nt*32 + (lane&31), cin = ks*16 + (lane>>5)*8 + j
__global__ void fold1_kernel(const float* __restrict__ acc, const float* __restrict__ g1,
    const float* __restrict__ be1, const float* __restrict__ w2, const float* __restrict__ b2,
    unsigned short* __restrict__ w2bf, float* __restrict__ b2f) {
  __shared__ float s1[CC], t1[CC];
  int tid = threadIdx.x;  // 512 threads
  if (tid < CC) {
    float cnt = (float)CNT1;
    float m = acc[tid] / cnt;
    float v = acc[64+tid] / cnt - m*m;
    float sc = g1[tid] * rsqrtf(v + EPSF);
    s1[tid] = sc; t1[tid] = be1[tid] - m*sc;
  }
  __syncthreads();
  int frag = tid >> 6;        // 0..7  (nt = frag>>2, ks = frag&3)
  int lane = tid & 63;
  int nt = frag >> 2, ks = frag & 3;
  int cout = nt*32 + (lane & 31);
  int cin0 = ks*16 + (lane >> 5)*8;
  for (int j = 0; j < 8; ++j) {
    int cin = cin0 + j;
    w2bf[((size_t)frag*64 + lane)*8 + j] = f2bf(w2[cout*CC + cin] * s1[cin]);
  }
  if (tid < CC) {
    float accb = b2[tid];
    for (int ci = 0; ci < CC; ++ci) accb += t1[ci]*w2[tid*CC + ci];
    b2f[tid] = accb;
  }
}

// ---------------- conv2 via MFMA: h2 = relu(h1@w2'+b2'), maxh2 + stats ----------------
__global__ __launch_bounds__(256, 4) void conv2_kernel(const float* __restrict__ pos,
    const int* __restrict__ idxg, const float* __restrict__ w1, const float* __restrict__ b1,
    const unsigned short* __restrict__ w2bf, const float* __restrict__ b2fg,
    float* __restrict__ maxh2, float* __restrict__ acc2) {
  int b = blockIdx.x >> 4;
  int nb = blockIdx.x & 15;
  __shared__ float px[NN], py[NN], pz[NN];
  __shared__ float4 relw[4][KNN];
  __shared__ __align__(16) unsigned short h1s[4][2112];  // 8 groups * 264 ushorts
  __shared__ float redbuf[4][2*CC];
  const float* pb = pos + (size_t)b*NN*3;
  for (int i = threadIdx.x; i < NN; i += 256) {
    px[i] = pb[i*3+0]; py[i] = pb[i*3+1]; pz[i] = pb[i*3+2];
  }
  int lane = threadIdx.x & 63, w = threadIdx.x >> 6;
  int half = lane >> 5, l31 = lane & 31;
  short8 Bf[2][4];
#pragma unroll
  for (int nt = 0; nt < 2; ++nt)
#pragma unroll
    for (int ks = 0; ks < 4; ++ks)
      Bf[nt][ks] = *(const short8*)&w2bf[((size_t)(nt*4+ks)*64 + lane)*8];
  float b2o0 = b2fg[l31], b2o1 = b2fg[32 + l31];
  float w1x = w1[lane*3+0], w1y = w1[lane*3+1], w1z = w1[lane*3+2], b1c = b1[lane];
  unsigned short* hw = h1s[w];
  {
    short8 zz = {0,0,0,0,0,0,0,0};
    for (int z = lane; z < 96; z += 64) {
      int g = z / 12, r = 20 + z % 12;
      *(short8*)&hw[g*264 + r*8] = zz;
    }
  }
  float sA = 0.f, ssA = 0.f, sB = 0.f, ssB = 0.f;
  __syncthreads();
  for (int t = 0; t < 16; ++t) {
    int n = nb*64 + w*16 + t;
    if (lane < KNN) {
      int j = idxg[(size_t)(b*NN + n)*KNN + lane];
      relw[w][lane] = make_float4(px[j]-px[n], py[j]-py[n], pz[j]-pz[n], 0.f);
    }
    int gbase = (lane >> 3)*264 + (lane & 7);
#pragma unroll
    for (int k = 0; k < KNN; ++k) {
      float4 r4 = relw[w][k];   // wave-uniform broadcast read
      float h = fmaxf(fmaf(r4.x, w1x, fmaf(r4.y, w1y, fmaf(r4.z, w1z, b1c))), 0.f);
      hw[gbase + k*8] = f2bf(h);
    }
    f32x16 acc0 = {}; f32x16 acc1 = {};
#pragma unroll
    for (int ks = 0; ks < 4; ++ks) {
      short8 A = *(const short8*)&hw[(ks*2 + half)*264 + l31*8];
      acc0 = __builtin_amdgcn_mfma_f32_32x32x16_bf16(A, Bf[0][ks], acc0, 0, 0, 0);
      acc1 = __builtin_amdgcn_mfma_f32_32x32x16_bf16(A, Bf[1][ks], acc1, 0, 0, 0);
    }
    float mx0 = 0.f, mx1 = 0.f;
#pragma unroll
    for (int reg = 0; reg < 8; ++reg) {
      float v0 = fmaxf(acc0[reg] + b2o0, 0.f);
      float v1 = fmaxf(acc1[reg] + b2o1, 0.f);
      sA += v0; ssA += v0*v0; sB += v1; ssB += v1*v1;
      mx0 = fmaxf(mx0, v0); mx1 = fmaxf(mx1, v1);
    }
    if (half == 0) {
#pragma unroll
      for (int reg = 8; reg < 12; ++reg) {
        float v0 = fmaxf(acc0[reg] + b2o0, 0.f);
        float v1 = fmaxf(acc1[reg] + b2o1, 0.f);
        sA += v0; ssA += v0*v0; sB += v1; ssB += v1*v1;
        mx0 = fmaxf(mx0, v0); mx1 = fmaxf(mx1, v1);
      }
    }
    mx0 = fmaxf(mx0, __shfl_xor(mx0, 32, 64));
    mx1 = fmaxf(mx1, __shfl_xor(mx1, 32, 64));
    if (half == 0) {
      float* mp = maxh2 + (size_t)(b*NN + n)*CC;
      mp[l31] = mx0; mp[32 + l31] = mx1;
    }
  }
  sA += __shfl_xor(sA, 32, 64); ssA += __shfl_xor(ssA, 32, 64);
  sB += __shfl_xor(sB, 32, 64); ssB += __shfl_xor(ssB, 32, 64);
  if (half == 0) { redbuf[w][l31] = sA; redbuf[w][32 + l31] = sB; }
  __syncthreads();
  if (w == 0) atomicAdd(&acc2[lane], redbuf[0][lane]+redbuf[1][lane]+redbuf[2][lane]+redbuf[3][lane]);
  __syncthreads();
  if (half == 0) { redbuf[w][l31] = ssA; redbuf[w][32 + l31] = ssB; }
  __syncthreads();
  if (w == 0) atomicAdd(&acc2[64+lane], redbuf[0][lane]+redbuf[1][lane]+redbuf[2][lane]+redbuf[3][lane]);
}

// ---------------- finalize BN2 affine ----------------
__global__ void fold2_kernel(const float* __restrict__ acc2, const float* __restrict__ g2,
    const float* __restrict__ be2, float* __restrict__ s2, float* __restrict__ t2) {
  int c = threadIdx.x;
  float cnt = (float)CNT1;
  float m = acc2[c]/cnt;
  float v = acc2[64+c]/cnt - m*m;
  float sc = g2[c]*rsqrtf(v+EPSF);
  s2[c] = sc;
  t2[c] = be2[c] - m*sc;
}

// ---------------- head: Y[b,h] = relu(max_m(f@w_nn1^T)+b) ----------------
__global__ __launch_bounds__(256) void head_kernel(const float* __restrict__ maxh2,
    const int* __restrict__ fidxg, const float* __restrict__ s2g, const float* __restrict__ t2g,
    const float* __restrict__ wnn1, const float* __restrict__ bnn1, float* __restrict__ Y) {
  int b = blockIdx.x >> 2;
  int hc = blockIdx.x & 3;
  __shared__ __align__(16) float ftile[128][CC];
  __shared__ float red2[2][128];
  int hl = threadIdx.x & 127, mseg = threadIdx.x >> 7;
  int h = hc*128 + hl;
  float4 wv4[16];
  const float4* wr4 = (const float4*)(wnn1 + (size_t)h*CC);
#pragma unroll
  for (int q = 0; q < 16; ++q) wv4[q] = wr4[q];
  float best = -FLT_MAX;
  const int* fb = fidxg + b*MM;
  for (int chunk = 0; chunk < 2; ++chunk) {
    {
      int row = threadIdx.x & 127, chal = threadIdx.x >> 7;
      int fi = fb[chunk*128 + row];
      const float* src = maxh2 + (size_t)(b*NN + fi)*CC;
      for (int ci = chal*32; ci < chal*32+32; ++ci)
        ftile[row][ci] = s2g[ci]*src[ci] + t2g[ci];
    }
    __syncthreads();
    for (int m = mseg*64; m < mseg*64+64; ++m) {
      float acc = 0.f;
#pragma unroll
      for (int cq = 0; cq < 16; ++cq) {
        float4 f = *((const float4*)&ftile[m][cq*4]);
        acc = fmaf(f.x, wv4[cq].x, acc);
        acc = fmaf(f.y, wv4[cq].y, acc);
        acc = fmaf(f.z, wv4[cq].z, acc);
        acc = fmaf(f.w, wv4[cq].w, acc);
      }
      best = fmaxf(best, acc);
    }
    __syncthreads();
  }
  red2[mseg][hl] = best;
  __syncthreads();
  if (mseg == 0) {
    float v = fmaxf(red2[0][hl], red2[1][hl]) + bnn1[h];
    Y[(size_t)b*HH + h] = fmaxf(v, 0.f);
  }
}

// ---------------- BN over batch (two-pass) ----------------
__global__ void bn3_kernel(const float* __restrict__ Y, const float* __restrict__ g,
    const float* __restrict__ be, float* __restrict__ s3, float* __restrict__ t3) {
  int h = blockIdx.x*256 + threadIdx.x;
  float s = 0.f;
  for (int b = 0; b < BB; ++b) s += Y[(size_t)b*HH + h];
  float m = s / (float)BB;
  float v = 0.f;
  for (int b = 0; b < BB; ++b) { float d = Y[(size_t)b*HH + h] - m; v += d*d; }
  v /= (float)BB;
  float sc = g[h] * rsqrtf(v + EPSF);
  s3[h] = sc; t3[h] = be[h] - m*sc;
}

// ---------------- logits + log_softmax ----------------
__global__ __launch_bounds__(256) void logits_kernel(const float* __restrict__ Y,
    const float* __restrict__ s3, const float* __restrict__ t3,
    const float* __restrict__ w4, const float* __restrict__ b4, float* __restrict__ out) {
  int b = blockIdx.x;
  __shared__ float ybn[HH];
  __shared__ float lg[NCLS];
  __shared__ float lse;
  for (int hh = threadIdx.x; hh < HH; hh += 256)
    ybn[hh] = Y[(size_t)b*HH + hh]*s3[hh] + t3[hh];
  __syncthreads();
  if (threadIdx.x < NCLS) {
    int j = threadIdx.x;
    float acc = b4[j];
    const float* wr = w4 + (size_t)j*HH;
    for (int ci = 0; ci < HH; ++ci) acc = fmaf(ybn[ci], wr[ci], acc);
    lg[j] = acc;
  }
  __syncthreads();
  if (threadIdx.x == 0) {
    float mx = -FLT_MAX;
    for (int j = 0; j < NCLS; ++j) mx = fmaxf(mx, lg[j]);
    float s = 0.f;
    for (int j = 0; j < NCLS; ++j) s += expf(lg[j] - mx);
    lse = mx + logf(s);
  }
  __syncthreads();
  if (threadIdx.x < NCLS) out[b*NCLS + threadIdx.x] = lg[threadIdx.x] - lse;
}

extern "C" void kernel_launch(void* const* d_in, const int* in_sizes, int n_in,
                              void* d_out, int out_size, void* d_ws, size_t ws_size,
                              hipStream_t stream) {
  const float* pos  = (const float*)d_in[0];
  const float* w1   = (const float*)d_in[1];
  const float* b1   = (const float*)d_in[2];
  const float* g1   = (const float*)d_in[3];
  const float* be1  = (const float*)d_in[4];
  const float* w2   = (const float*)d_in[5];
  const float* b2   = (const float*)d_in[6];
  const float* g2   = (const float*)d_in[7];
  const float* be2  = (const float*)d_in[8];
  const float* wnn1 = (const float*)d_in[9];
  const float* bnn1 = (const float*)d_in[10];
  const float* gbn2 = (const float*)d_in[11];
  const float* bebn2= (const float*)d_in[12];
  const float* wnn4 = (const float*)d_in[13];
  const float* bnn4 = (const float*)d_in[14];
  float* ws = (float*)d_ws;
  int*   idxg  = (int*)(ws + IDX_OFF);
  float* maxh2 = ws + MAXH2_OFF;
  int*   fidxg = (int*)(ws + FIDX_OFF);
  float* Y     = ws + Y_OFF;
  float* acc1  = ws + ACC_OFF;
  float* acc2  = ws + ACC_OFF + 128;
  unsigned short* w2bf = (unsigned short*)(ws + W2T_OFF);
  float* b2f   = ws + B2F_OFF;
  float* s2    = ws + S2_OFF;
  float* t2    = ws + T2_OFF;
  float* s3    = ws + S3_OFF;
  float* t3    = ws + T3_OFF;
  float* outp  = (float*)d_out;

  hipMemsetAsync((void*)(ws + ACC_OFF), 0, 256*sizeof(float), stream);
  knn_fps_kernel<<<BB + BB*32, 256, 0, stream>>>(pos, idxg, fidxg);
  stats1_kernel<<<BB*16, 256, 0, stream>>>(pos, idxg, w1, b1, acc1);
  fold1_kernel<<<1, 512, 0, stream>>>(acc1, g1, be1, w2, b2, w2bf, b2f);
  conv2_kernel<<<BB*16, 256, 0, stream>>>(pos, idxg, w1, b1, w2bf, b2f, maxh2, acc2);
  fold2_kernel<<<1, 64, 0, stream>>>(acc2, g2, be2, s2, t2);
  head_kernel<<<BB*4, 256, 0, stream>>>(maxh2, fidxg, s2, t2, wnn1, bnn1, Y);
  bn3_kernel<<<2, 256, 0, stream>>>(Y, gbn2, bebn2, s3, t3);
  logits_kernel<<<BB, 256, 0, stream>>>(Y, s3, t3, wnn4, bnn4, outp);
}

// Round 7
// 422.685 us; speedup vs baseline: 4.3292x; 1.0334x over previous
//
#include <hip/hip_runtime.h>
#include <hip/hip_bf16.h>
#include <cfloat>
#include <math.h>

#define BB 64
#define NN 1024
#define KNN 20
#define MM 256
#define CC 64
#define HH 512
#define NCLS 40
#define EPSF 1e-5f
#define CNT1 (BB*NN*KNN)

// workspace offsets (in 4-byte elements)
#define IDX_OFF    0
#define MAXH2_OFF  (IDX_OFF + BB*NN*KNN)      // int idx then floats
#define FIDX_OFF   (MAXH2_OFF + BB*NN*CC)
#define Y_OFF      (FIDX_OFF + BB*MM)
#define ACC_OFF    (Y_OFF + BB*HH)            // 256 floats zeroed: sum1[64],sumsq1[64],sum2[64],sumsq2[64]
#define W2T_OFF    (ACC_OFF + 256)            // w2' bf16 B-frags (2048 ushorts) + b2f
#define B2F_OFF    (W2T_OFF + CC*CC)
#define S2_OFF     (B2F_OFF + CC)
#define T2_OFF     (S2_OFF + CC)
#define S3_OFF     (T2_OFF + CC)
#define T3_OFF     (S3_OFF + HH)

typedef __attribute__((ext_vector_type(8)))  short short8;
typedef __attribute__((ext_vector_type(16))) float f32x16;

static __device__ __forceinline__ unsigned short f2bf(float f) {
  unsigned u = __float_as_uint(f);
  unsigned r = (u + 0x7fffu + ((u >> 16) & 1u)) >> 16;   // RNE
  return (unsigned short)r;
}

// ---------------- fused FPS + kNN ----------------
// blocks [0, BB): single-wave FPS (registers, DPP cross-lane reduce, no
// barriers in the serial loop). Placed FIRST so the serial chains start
// immediately and hide under the kNN blocks.
// blocks [BB, BB + BB*32): kNN, one wave per 8 queries. Range-narrowed
// binary search on the top-16-bit prefix: bounds from wave-min and
// max-over-lanes(lane-min) via DPP (count(<=max-of-lane-mins) >= 64 >= 20,
// so it's a valid hi). Exact-count fast path emits directly; slow path
// refines the low 16 bits (exact 20th value) + two-pass emission.
__global__ __launch_bounds__(256) void knn_fps_kernel(const float* __restrict__ pos,
                                                      int* __restrict__ idxg,
                                                      int* __restrict__ fidxg) {
  __shared__ float4 pj[NN];
  if (blockIdx.x >= BB) {
    // ---------------- kNN branch ----------------
    int blk = blockIdx.x - BB;
    int b  = blk >> 5;   // cloud
    int nb = blk & 31;   // 32-point segment of the cloud
    const float* pb = pos + (size_t)b * NN * 3;
    for (int i = threadIdx.x; i < NN; i += 256) {
      float x = pb[i*3+0], y = pb[i*3+1], z = pb[i*3+2];
      pj[i] = make_float4(x, y, z, (x*x + y*y) + z*z);
    }
    __syncthreads();
    int lane = threadIdx.x & 63;
    int wv   = threadIdx.x >> 6;
    unsigned long long lmask_lt = (1ULL << lane) - 1ULL;

    for (int t = 0; t < 8; ++t) {
      int i = nb*32 + wv*8 + t;        // query point (wave-uniform)
      float4 pi = pj[i];               // LDS broadcast
      unsigned u[16];
#pragma unroll
      for (int q = 0; q < 16; ++q) {
        int j = q*64 + lane;
        float4 pw = pj[j];
        float d = pi.w + pw.w - 2.0f*(pi.x*pw.x + pi.y*pw.y + pi.z*pw.z);
        unsigned bits = __float_as_uint(d);
        bits = (bits & 0x80000000u) ? ~bits : (bits | 0x80000000u);
        if (j == i) bits = 0xFFFFFFFFu;   // self excluded (diag = +inf)
        u[q] = bits;
      }
      // per-lane min of 16, then wave-min and wave-max-of-lane-mins via DPP
      unsigned lmin = u[0];
#pragma unroll
      for (int q = 1; q < 16; ++q) lmin = (u[q] < lmin) ? u[q] : lmin;
      unsigned rmin = lmin, rmax = lmin;
#define KNN_DPP_STEP(C) { \
      unsigned t1 = (unsigned)__builtin_amdgcn_update_dpp((int)rmin, (int)rmin, (C), 0xf, 0xf, false); \
      unsigned t2 = (unsigned)__builtin_amdgcn_update_dpp((int)rmax, (int)rmax, (C), 0xf, 0xf, false); \
      rmin = (t1 < rmin) ? t1 : rmin; rmax = (t2 > rmax) ? t2 : rmax; }
      KNN_DPP_STEP(0x111)   // row_shr:1
      KNN_DPP_STEP(0x112)   // row_shr:2
      KNN_DPP_STEP(0x114)   // row_shr:4
      KNN_DPP_STEP(0x118)   // row_shr:8
      KNN_DPP_STEP(0x142)   // row_bcast:15
      KNN_DPP_STEP(0x143)   // row_bcast:31
#undef KNN_DPP_STEP
      unsigned plo = ((unsigned)__builtin_amdgcn_readlane((int)rmin, 63)) >> 16;
      unsigned phi = ((unsigned)__builtin_amdgcn_readlane((int)rmax, 63)) >> 16;
      // narrowed binary search; carry the count measured at the final phi
      int cntHi = -1;
      while (plo < phi) {                 // wave-uniform
        unsigned pmid = (plo + phi) >> 1;
        unsigned tmid = (pmid << 16) | 0xFFFFu;
        int cnt = 0;
#pragma unroll
        for (int q = 0; q < 16; ++q)
          cnt += (int)__popcll(__ballot(u[q] <= tmid));
        if (cnt >= KNN) { phi = pmid; cntHi = cnt; } else plo = pmid + 1;
      }
      unsigned tstar = (phi << 16) | 0xFFFFu;  // bucket top
      unsigned bbase = phi << 16;              // bucket base
      int* op = idxg + (size_t)(b*NN + i) * KNN;
      if (cntHi < 0) {   // phi never measured (rare): recount
        cntHi = 0;
#pragma unroll
        for (int q = 0; q < 16; ++q)
          cntHi += (int)__popcll(__ballot(u[q] <= tstar));
      }
      if (cntHi == KNN) {
        // exact set: emit all <= tstar (index order; set-equivalent)
        int base = 0;
#pragma unroll
        for (int q = 0; q < 16; ++q) {
          bool pred = (u[q] <= tstar);
          unsigned long long mask = __ballot((int)pred);
          if (pred) op[base + (int)__popcll(mask & lmask_lt)] = q*64 + lane;
          base += (int)__popcll(mask);
        }
      } else {
        // slow path: refine low 16 bits -> exact 20th value xstar
        unsigned lo2 = bbase, hi2 = tstar;
        while (lo2 < hi2) {
          unsigned mid = lo2 + ((hi2 - lo2) >> 1);
          int cnt = 0;
#pragma unroll
          for (int q = 0; q < 16; ++q)
            cnt += (int)__popcll(__ballot(u[q] <= mid));
          if (cnt >= KNN) hi2 = mid; else lo2 = mid + 1;
        }
        unsigned xstar = lo2;
        int base = 0;
#pragma unroll
        for (int q = 0; q < 16; ++q) {
          bool pred = (u[q] < xstar);
          unsigned long long mask = __ballot((int)pred);
          if (pred) op[base + (int)__popcll(mask & lmask_lt)] = q*64 + lane;
          base += (int)__popcll(mask);
        }
        for (int q = 0; q < 16 && base < KNN; ++q) {  // ties, ascending index
          bool pred = (u[q] == xstar);
          unsigned long long mask = __ballot((int)pred);
          if (pred) {
            int pos_ = base + (int)__popcll(mask & lmask_lt);
            if (pos_ < KNN) op[pos_] = q*64 + lane;
          }
          base += (int)__popcll(mask);
        }
      }
    }
  } else {
    // ---------------- FPS branch: single wave, DPP reduce, no barriers ----------------
    int b = blockIdx.x;
    const float* pb = pos + (size_t)b * NN * 3;
    for (int i = threadIdx.x; i < NN; i += 256)
      pj[i] = make_float4(pb[i*3], pb[i*3+1], pb[i*3+2], 0.f);
    __syncthreads();
    if (threadIdx.x >= 64) return;   // waves 1-3 done (after barrier)
    int lane = threadIdx.x;
    float px[16], py[16], pz[16], dist[16];
#pragma unroll
    for (int q = 0; q < 16; ++q) {
      float4 p = pj[q*64 + lane];
      px[q] = p.x; py[q] = p.y; pz[q] = p.z;
      dist[q] = 1e38f;
    }
    if (lane == 0) fidxg[b*MM] = 0;
    int cur = 0;
    for (int m = 1; m < MM; ++m) {
      float4 cp = pj[cur];             // wave-uniform LDS broadcast
      unsigned long long key[16];
#pragma unroll
      for (int q = 0; q < 16; ++q) {
        float dx = __fsub_rn(px[q], cp.x);
        float dy = __fsub_rn(py[q], cp.y);
        float dz = __fsub_rn(pz[q], cp.z);
        float dd = __fadd_rn(__fadd_rn(__fmul_rn(dx,dx), __fmul_rn(dy,dy)), __fmul_rn(dz,dz));
        float dq = fminf(dist[q], dd);
        dist[q] = dq;
        key[q] = ((unsigned long long)__float_as_uint(dq) << 32)
               | (unsigned)(NN - 1 - (q*64 + lane));
      }
      // in-register tree max (max dist; ties -> smallest index)
#pragma unroll
      for (int s = 8; s >= 1; s >>= 1)
#pragma unroll
        for (int q = 0; q < s; ++q)
          if (key[q + s] > key[q]) key[q] = key[q + s];
      // cross-lane max via DPP (row_shr 1/2/4/8 + row_bcast 15/31), result in lane 63
      unsigned klo = (unsigned)key[0], khi = (unsigned)(key[0] >> 32);
#define FPS_DPP_STEP(C) { \
      unsigned tlo = (unsigned)__builtin_amdgcn_update_dpp((int)klo, (int)klo, (C), 0xf, 0xf, false); \
      unsigned thi = (unsigned)__builtin_amdgcn_update_dpp((int)khi, (int)khi, (C), 0xf, 0xf, false); \
      if (thi > khi || (thi == khi && tlo > klo)) { khi = thi; klo = tlo; } }
      FPS_DPP_STEP(0x111)   // row_shr:1
      FPS_DPP_STEP(0x112)   // row_shr:2
      FPS_DPP_STEP(0x114)   // row_shr:4
      FPS_DPP_STEP(0x118)   // row_shr:8
      FPS_DPP_STEP(0x142)   // row_bcast:15
      FPS_DPP_STEP(0x143)   // row_bcast:31
#undef FPS_DPP_STEP
      unsigned wlo = (unsigned)__builtin_amdgcn_readlane((int)klo, 63);
      cur = (NN - 1) - (int)wlo;
      if (lane == 0) fidxg[b*MM + m] = cur;
    }
  }
}

// ---------------- stats of h1 = relu(rel@w1+b1) ----------------
__global__ __launch_bounds__(256) void stats1_kernel(const float* __restrict__ pos,
    const int* __restrict__ idxg, const float* __restrict__ w1,
    const float* __restrict__ b1, float* __restrict__ acc) {
  int b = blockIdx.x >> 4;
  int nb = blockIdx.x & 15;
  __shared__ float px[NN], py[NN], pz[NN];
  __shared__ float relx[4][KNN], rely[4][KNN], relz[4][KNN];
  __shared__ float red[4][CC];
  const float* pb = pos + (size_t)b*NN*3;
  for (int i = threadIdx.x; i < NN; i += 256) {
    px[i] = pb[i*3+0]; py[i] = pb[i*3+1]; pz[i] = pb[i*3+2];
  }
  int c = threadIdx.x & 63, w = threadIdx.x >> 6;
  float w1x = w1[c*3+0], w1y = w1[c*3+1], w1z = w1[c*3+2], b1c = b1[c];
  float s = 0.f, ss = 0.f;
  __syncthreads();
  for (int it = 0; it < 16; ++it) {
    int n0 = nb*64 + it*4;
    if (threadIdx.x < 80) {
      int wv = threadIdx.x / KNN, k = threadIdx.x % KNN;
      int n = n0 + wv;
      int j = idxg[(size_t)(b*NN + n)*KNN + k];
      relx[wv][k] = px[j] - px[n];
      rely[wv][k] = py[j] - py[n];
      relz[wv][k] = pz[j] - pz[n];
    }
    __syncthreads();
#pragma unroll
    for (int k = 0; k < KNN; ++k) {
      float h = fmaxf(relx[w][k]*w1x + rely[w][k]*w1y + relz[w][k]*w1z + b1c, 0.f);
      s += h; ss += h*h;
    }
    __syncthreads();
  }
  red[w][c] = s; __syncthreads();
  if (w == 0) atomicAdd(&acc[c], red[0][c]+red[1][c]+red[2][c]+red[3][c]);
  __syncthreads();
  red[w][c] = ss; __syncthreads();
  if (w == 0) atomicAdd(&acc[64+c], red[0][c]+red[1][c]+red[2][c]+red[3][c]);
}

// ---------------- fold BN1 into w2 (bf16 B-fragment layout) ----------------
// w2bf[((nt*4+ks)*64 + lane)*8 + j] = bf16(w2[cout][cin] * s1[cin])
//   cout = nt*32 + (lane&31), cin = ks*16 + (lane>>5)*8 + j
__global__ void fold1_kernel(const float* __restrict__ acc, const float* __restrict__ g1,
    const float* __restrict__ be1, const float* __restrict__ w2, const float* __restrict__ b2,
    unsigned short* __restrict__ w2bf, float* __restrict__ b2f) {
  __shared__ float s1[CC], t1[CC];
  int tid = threadIdx.x;  // 512 threads
  if (tid < CC) {
    float cnt = (float)CNT1;
    float m = acc[tid] / cnt;
    float v = acc[64+tid] / cnt - m*m;
    float sc = g1[tid] * rsqrtf(v + EPSF);
    s1[tid] = sc; t1[tid] = be1[tid] - m*sc;
  }
  __syncthreads();
  int frag = tid >> 6;        // 0..7  (nt = frag>>2, ks = frag&3)
  int lane = tid & 63;
  int nt = frag >> 2, ks = frag & 3;
  int cout = nt*32 + (lane & 31);
  int cin0 = ks*16 + (lane >> 5)*8;
  for (int j = 0; j < 8; ++j) {
    int cin = cin0 + j;
    w2bf[((size_t)frag*64 + lane)*8 + j] = f2bf(w2[cout*CC + cin] * s1[cin]);
  }
  if (tid < CC) {
    float accb = b2[tid];
    for (int ci = 0; ci < CC; ++ci) accb += t1[ci]*w2[tid*CC + ci];
    b2f[tid] = accb;
  }
}

// ---------------- conv2 via MFMA: h2 = relu(h1@w2'+b2'), maxh2 + stats ----------------
__global__ __launch_bounds__(256, 4) void conv2_kernel(const float* __restrict__ pos,
    const int* __restrict__ idxg, const float* __restrict__ w1, const float* __restrict__ b1,
    const unsigned short* __restrict__ w2bf, const float* __restrict__ b2fg,
    float* __restrict__ maxh2, float* __restrict__ acc2) {
  int b = blockIdx.x >> 4;
  int nb = blockIdx.x & 15;
  __shared__ float px[NN], py[NN], pz[NN];
  __shared__ float4 relw[4][KNN];
  __shared__ __align__(16) unsigned short h1s[4][2112];  // 8 groups * 264 ushorts
  __shared__ float redbuf[4][2*CC];
  const float* pb = pos + (size_t)b*NN*3;
  for (int i = threadIdx.x; i < NN; i += 256) {
    px[i] = pb[i*3+0]; py[i] = pb[i*3+1]; pz[i] = pb[i*3+2];
  }
  int lane = threadIdx.x & 63, w = threadIdx.x >> 6;
  int half = lane >> 5, l31 = lane & 31;
  short8 Bf[2][4];
#pragma unroll
  for (int nt = 0; nt < 2; ++nt)
#pragma unroll
    for (int ks = 0; ks < 4; ++ks)
      Bf[nt][ks] = *(const short8*)&w2bf[((size_t)(nt*4+ks)*64 + lane)*8];
  float b2o0 = b2fg[l31], b2o1 = b2fg[32 + l31];
  float w1x = w1[lane*3+0], w1y = w1[lane*3+1], w1z = w1[lane*3+2], b1c = b1[lane];
  unsigned short* hw = h1s[w];
  {
    short8 zz = {0,0,0,0,0,0,0,0};
    for (int z = lane; z < 96; z += 64) {
      int g = z / 12, r = 20 + z % 12;
      *(short8*)&hw[g*264 + r*8] = zz;
    }
  }
  float sA = 0.f, ssA = 0.f, sB = 0.f, ssB = 0.f;
  __syncthreads();
  for (int t = 0; t < 16; ++t) {
    int n = nb*64 + w*16 + t;
    if (lane < KNN) {
      int j = idxg[(size_t)(b*NN + n)*KNN + lane];
      relw[w][lane] = make_float4(px[j]-px[n], py[j]-py[n], pz[j]-pz[n], 0.f);
    }
    int gbase = (lane >> 3)*264 + (lane & 7);
#pragma unroll
    for (int k = 0; k < KNN; ++k) {
      float4 r4 = relw[w][k];   // wave-uniform broadcast read
      float h = fmaxf(fmaf(r4.x, w1x, fmaf(r4.y, w1y, fmaf(r4.z, w1z, b1c))), 0.f);
      hw[gbase + k*8] = f2bf(h);
    }
    f32x16 acc0 = {}; f32x16 acc1 = {};
#pragma unroll
    for (int ks = 0; ks < 4; ++ks) {
      short8 A = *(const short8*)&hw[(ks*2 + half)*264 + l31*8];
      acc0 = __builtin_amdgcn_mfma_f32_32x32x16_bf16(A, Bf[0][ks], acc0, 0, 0, 0);
      acc1 = __builtin_amdgcn_mfma_f32_32x32x16_bf16(A, Bf[1][ks], acc1, 0, 0, 0);
    }
    float mx0 = 0.f, mx1 = 0.f;
#pragma unroll
    for (int reg = 0; reg < 8; ++reg) {
      float v0 = fmaxf(acc0[reg] + b2o0, 0.f);
      float v1 = fmaxf(acc1[reg] + b2o1, 0.f);
      sA += v0; ssA += v0*v0; sB += v1; ssB += v1*v1;
      mx0 = fmaxf(mx0, v0); mx1 = fmaxf(mx1, v1);
    }
    if (half == 0) {
#pragma unroll
      for (int reg = 8; reg < 12; ++reg) {
        float v0 = fmaxf(acc0[reg] + b2o0, 0.f);
        float v1 = fmaxf(acc1[reg] + b2o1, 0.f);
        sA += v0; ssA += v0*v0; sB += v1; ssB += v1*v1;
        mx0 = fmaxf(mx0, v0); mx1 = fmaxf(mx1, v1);
      }
    }
    mx0 = fmaxf(mx0, __shfl_xor(mx0, 32, 64));
    mx1 = fmaxf(mx1, __shfl_xor(mx1, 32, 64));
    if (half == 0) {
      float* mp = maxh2 + (size_t)(b*NN + n)*CC;
      mp[l31] = mx0; mp[32 + l31] = mx1;
    }
  }
  sA += __shfl_xor(sA, 32, 64); ssA += __shfl_xor(ssA, 32, 64);
  sB += __shfl_xor(sB, 32, 64); ssB += __shfl_xor(ssB, 32, 64);
  if (half == 0) { redbuf[w][l31] = sA; redbuf[w][32 + l31] = sB; }
  __syncthreads();
  if (w == 0) atomicAdd(&acc2[lane], redbuf[0][lane]+redbuf[1][lane]+redbuf[2][lane]+redbuf[3][lane]);
  __syncthreads();
  if (half == 0) { redbuf[w][l31] = ssA; redbuf[w][32 + l31] = ssB; }
  __syncthreads();
  if (w == 0) atomicAdd(&acc2[64+lane], redbuf[0][lane]+redbuf[1][lane]+redbuf[2][lane]+redbuf[3][lane]);
}

// ---------------- finalize BN2 affine ----------------
__global__ void fold2_kernel(const float* __restrict__ acc2, const float* __restrict__ g2,
    const float* __restrict__ be2, float* __restrict__ s2, float* __restrict__ t2) {
  int c = threadIdx.x;
  float cnt = (float)CNT1;
  float m = acc2[c]/cnt;
  float v = acc2[64+c]/cnt - m*m;
  float sc = g2[c]*rsqrtf(v+EPSF);
  s2[c] = sc;
  t2[c] = be2[c] - m*sc;
}

// ---------------- head: Y[b,h] = relu(max_m(f@w_nn1^T)+b) ----------------
// 2 h-channels per thread (h, h+64): halves ds_read_b128 traffic per FLOP.
__global__ __launch_bounds__(256) void head_kernel(const float* __restrict__ maxh2,
    const int* __restrict__ fidxg, const float* __restrict__ s2g, const float* __restrict__ t2g,
    const float* __restrict__ wnn1, const float* __restrict__ bnn1, float* __restrict__ Y) {
  int b = blockIdx.x >> 2;
  int hc = blockIdx.x & 3;
  __shared__ __align__(16) float ftile[128][CC];
  __shared__ float red2[4][128];
  int hl = threadIdx.x & 63, mseg = threadIdx.x >> 6;   // 64 h-lanes x 4 msegs
  int hA = hc*128 + hl, hB = hA + 64;
  float4 wva[16], wvb[16];
  const float4* wrA = (const float4*)(wnn1 + (size_t)hA*CC);
  const float4* wrB = (const float4*)(wnn1 + (size_t)hB*CC);
#pragma unroll
  for (int q = 0; q < 16; ++q) { wva[q] = wrA[q]; wvb[q] = wrB[q]; }
  float bestA = -FLT_MAX, bestB = -FLT_MAX;
  const int* fb = fidxg + b*MM;
  for (int chunk = 0; chunk < 2; ++chunk) {
    {
      int row = threadIdx.x & 127, chal = threadIdx.x >> 7;
      int fi = fb[chunk*128 + row];
      const float* src = maxh2 + (size_t)(b*NN + fi)*CC;
      for (int ci = chal*32; ci < chal*32+32; ++ci)
        ftile[row][ci] = s2g[ci]*src[ci] + t2g[ci];
    }
    __syncthreads();
    for (int m = mseg*32; m < mseg*32+32; ++m) {
      float accA = 0.f, accB = 0.f;
#pragma unroll
      for (int cq = 0; cq < 16; ++cq) {
        float4 f = *((const float4*)&ftile[m][cq*4]);
        accA = fmaf(f.x, wva[cq].x, accA);
        accA = fmaf(f.y, wva[cq].y, accA);
        accA = fmaf(f.z, wva[cq].z, accA);
        accA = fmaf(f.w, wva[cq].w, accA);
        accB = fmaf(f.x, wvb[cq].x, accB);
        accB = fmaf(f.y, wvb[cq].y, accB);
        accB = fmaf(f.z, wvb[cq].z, accB);
        accB = fmaf(f.w, wvb[cq].w, accB);
      }
      bestA = fmaxf(bestA, accA);
      bestB = fmaxf(bestB, accB);
    }
    __syncthreads();
  }
  red2[mseg][hl] = bestA;
  red2[mseg][64 + hl] = bestB;
  __syncthreads();
  if (threadIdx.x < 128) {
    int hh = hc*128 + threadIdx.x;
    float v = fmaxf(fmaxf(red2[0][threadIdx.x], red2[1][threadIdx.x]),
                    fmaxf(red2[2][threadIdx.x], red2[3][threadIdx.x])) + bnn1[hh];
    Y[(size_t)b*HH + hh] = fmaxf(v, 0.f);
  }
}

// ---------------- BN over batch (two-pass) ----------------
__global__ void bn3_kernel(const float* __restrict__ Y, const float* __restrict__ g,
    const float* __restrict__ be, float* __restrict__ s3, float* __restrict__ t3) {
  int h = blockIdx.x*256 + threadIdx.x;
  float s = 0.f;
  for (int b = 0; b < BB; ++b) s += Y[(size_t)b*HH + h];
  float m = s / (float)BB;
  float v = 0.f;
  for (int b = 0; b < BB; ++b) { float d = Y[(size_t)b*HH + h] - m; v += d*d; }
  v /= (float)BB;
  float sc = g[h] * rsqrtf(v + EPSF);
  s3[h] = sc; t3[h] = be[h] - m*sc;
}

// ---------------- logits + log_softmax ----------------
__global__ __launch_bounds__(256) void logits_kernel(const float* __restrict__ Y,
    const float* __restrict__ s3, const float* __restrict__ t3,
    const float* __restrict__ w4, const float* __restrict__ b4, float* __restrict__ out) {
  int b = blockIdx.x;
  __shared__ float ybn[HH];
  __shared__ float lg[NCLS];
  __shared__ float lse;
  for (int hh = threadIdx.x; hh < HH; hh += 256)
    ybn[hh] = Y[(size_t)b*HH + hh]*s3[hh] + t3[hh];
  __syncthreads();
  if (threadIdx.x < NCLS) {
    int j = threadIdx.x;
    float acc = b4[j];
    const float* wr = w4 + (size_t)j*HH;
    for (int ci = 0; ci < HH; ++ci) acc = fmaf(ybn[ci], wr[ci], acc);
    lg[j] = acc;
  }
  __syncthreads();
  if (threadIdx.x == 0) {
    float mx = -FLT_MAX;
    for (int j = 0; j < NCLS; ++j) mx = fmaxf(mx, lg[j]);
    float s = 0.f;
    for (int j = 0; j < NCLS; ++j) s += expf(lg[j] - mx);
    lse = mx + logf(s);
  }
  __syncthreads();
  if (threadIdx.x < NCLS) out[b*NCLS + threadIdx.x] = lg[threadIdx.x] - lse;
}

extern "C" void kernel_launch(void* const* d_in, const int* in_sizes, int n_in,
                              void* d_out, int out_size, void* d_ws, size_t ws_size,
                              hipStream_t stream) {
  const float* pos  = (const float*)d_in[0];
  const float* w1   = (const float*)d_in[1];
  const float* b1   = (const float*)d_in[2];
  const float* g1   = (const float*)d_in[3];
  const float* be1  = (const float*)d_in[4];
  const float* w2   = (const float*)d_in[5];
  const float* b2   = (const float*)d_in[6];
  const float* g2   = (const float*)d_in[7];
  const float* be2  = (const float*)d_in[8];
  const float* wnn1 = (const float*)d_in[9];
  const float* bnn1 = (const float*)d_in[10];
  const float* gbn2 = (const float*)d_in[11];
  const float* bebn2= (const float*)d_in[12];
  const float* wnn4 = (const float*)d_in[13];
  const float* bnn4 = (const float*)d_in[14];
  float* ws = (float*)d_ws;
  int*   idxg  = (int*)(ws + IDX_OFF);
  float* maxh2 = ws + MAXH2_OFF;
  int*   fidxg = (int*)(ws + FIDX_OFF);
  float* Y     = ws + Y_OFF;
  float* acc1  = ws + ACC_OFF;
  float* acc2  = ws + ACC_OFF + 128;
  unsigned short* w2bf = (unsigned short*)(ws + W2T_OFF);
  float* b2f   = ws + B2F_OFF;
  float* s2    = ws + S2_OFF;
  float* t2    = ws + T2_OFF;
  float* s3    = ws + S3_OFF;
  float* t3    = ws + T3_OFF;
  float* outp  = (float*)d_out;

  hipMemsetAsync((void*)(ws + ACC_OFF), 0, 256*sizeof(float), stream);
  knn_fps_kernel<<<BB + BB*32, 256, 0, stream>>>(pos, idxg, fidxg);
  stats1_kernel<<<BB*16, 256, 0, stream>>>(pos, idxg, w1, b1, acc1);
  fold1_kernel<<<1, 512, 0, stream>>>(acc1, g1, be1, w2, b2, w2bf, b2f);
  conv2_kernel<<<BB*16, 256, 0, stream>>>(pos, idxg, w1, b1, w2bf, b2f, maxh2, acc2);
  fold2_kernel<<<1, 64, 0, stream>>>(acc2, g2, be2, s2, t2);
  head_kernel<<<BB*4, 256, 0, stream>>>(maxh2, fidxg, s2, t2, wnn1, bnn1, Y);
  bn3_kernel<<<2, 256, 0, stream>>>(Y, gbn2, bebn2, s3, t3);
  logits_kernel<<<BB, 256, 0, stream>>>(Y, s3, t3, wnn4, bnn4, outp);
}

// Round 8
// 380.125 us; speedup vs baseline: 4.8139x; 1.1120x over previous
//
#include <hip/hip_runtime.h>
#include <hip/hip_bf16.h>
#include <cfloat>
#include <math.h>

#define BB 64
#define NN 1024
#define KNN 20
#define MM 256
#define CC 64
#define HH 512
#define NCLS 40
#define EPSF 1e-5f
#define CNT1 (BB*NN*KNN)

// workspace offsets (in 4-byte elements)
#define IDX_OFF    0
#define MAXH2_OFF  (IDX_OFF + BB*NN*KNN)      // int idx then floats
#define FIDX_OFF   (MAXH2_OFF + BB*NN*CC)
#define Y_OFF      (FIDX_OFF + BB*MM)
#define ACC_OFF    (Y_OFF + BB*HH)            // 256 floats zeroed: sum1[64],sumsq1[64],sum2[64],sumsq2[64]
#define W2T_OFF    (ACC_OFF + 256)            // w2' bf16 B-frags (2048 ushorts) + b2f
#define B2F_OFF    (W2T_OFF + CC*CC)
#define S2_OFF     (B2F_OFF + CC)
#define T2_OFF     (S2_OFF + CC)
#define S3_OFF     (T2_OFF + CC)
#define T3_OFF     (S3_OFF + HH)

typedef __attribute__((ext_vector_type(8)))  short short8;
typedef __attribute__((ext_vector_type(16))) float f32x16;

static __device__ __forceinline__ unsigned short f2bf(float f) {
  unsigned u = __float_as_uint(f);
  unsigned r = (u + 0x7fffu + ((u >> 16) & 1u)) >> 16;   // RNE
  return (unsigned short)r;
}

// ---------------- fused FPS + kNN ----------------
// blocks [0, BB): single-wave FPS. All-float reduction: dist >= +0 so
// fmaxf == u32-bit max and float eq == bit eq. Value reduce via DPP
// v_max_f32, index via descending-q first-match + DPP v_min_u32. Selection
// bit-exact vs numpy (max dist, ties -> smallest index). No barriers.
// blocks [BB, BB + BB*32): kNN, one wave per 8 queries (unchanged R6 logic).
__global__ __launch_bounds__(256) void knn_fps_kernel(const float* __restrict__ pos,
                                                      int* __restrict__ idxg,
                                                      int* __restrict__ fidxg) {
  __shared__ float4 pj[NN];
  if (blockIdx.x >= BB) {
    // ---------------- kNN branch ----------------
    int blk = blockIdx.x - BB;
    int b  = blk >> 5;   // cloud
    int nb = blk & 31;   // 32-point segment of the cloud
    const float* pb = pos + (size_t)b * NN * 3;
    for (int i = threadIdx.x; i < NN; i += 256) {
      float x = pb[i*3+0], y = pb[i*3+1], z = pb[i*3+2];
      pj[i] = make_float4(x, y, z, (x*x + y*y) + z*z);
    }
    __syncthreads();
    int lane = threadIdx.x & 63;
    int wv   = threadIdx.x >> 6;
    unsigned long long lmask_lt = (1ULL << lane) - 1ULL;

    for (int t = 0; t < 8; ++t) {
      int i = nb*32 + wv*8 + t;        // query point (wave-uniform)
      float4 pi = pj[i];               // LDS broadcast
      unsigned u[16];
#pragma unroll
      for (int q = 0; q < 16; ++q) {
        int j = q*64 + lane;
        float4 pw = pj[j];
        float d = pi.w + pw.w - 2.0f*(pi.x*pw.x + pi.y*pw.y + pi.z*pw.z);
        unsigned bits = __float_as_uint(d);
        bits = (bits & 0x80000000u) ? ~bits : (bits | 0x80000000u);
        if (j == i) bits = 0xFFFFFFFFu;   // self excluded (diag = +inf)
        u[q] = bits;
      }
      // per-lane min of 16, then wave-min and wave-max-of-lane-mins via DPP
      unsigned lmin = u[0];
#pragma unroll
      for (int q = 1; q < 16; ++q) lmin = (u[q] < lmin) ? u[q] : lmin;
      unsigned rmin = lmin, rmax = lmin;
#define KNN_DPP_STEP(C) { \
      unsigned t1 = (unsigned)__builtin_amdgcn_update_dpp((int)rmin, (int)rmin, (C), 0xf, 0xf, false); \
      unsigned t2 = (unsigned)__builtin_amdgcn_update_dpp((int)rmax, (int)rmax, (C), 0xf, 0xf, false); \
      rmin = (t1 < rmin) ? t1 : rmin; rmax = (t2 > rmax) ? t2 : rmax; }
      KNN_DPP_STEP(0x111)   // row_shr:1
      KNN_DPP_STEP(0x112)   // row_shr:2
      KNN_DPP_STEP(0x114)   // row_shr:4
      KNN_DPP_STEP(0x118)   // row_shr:8
      KNN_DPP_STEP(0x142)   // row_bcast:15
      KNN_DPP_STEP(0x143)   // row_bcast:31
#undef KNN_DPP_STEP
      unsigned plo = ((unsigned)__builtin_amdgcn_readlane((int)rmin, 63)) >> 16;
      unsigned phi = ((unsigned)__builtin_amdgcn_readlane((int)rmax, 63)) >> 16;
      // narrowed binary search; carry the count measured at the final phi
      int cntHi = -1;
      while (plo < phi) {                 // wave-uniform
        unsigned pmid = (plo + phi) >> 1;
        unsigned tmid = (pmid << 16) | 0xFFFFu;
        int cnt = 0;
#pragma unroll
        for (int q = 0; q < 16; ++q)
          cnt += (int)__popcll(__ballot(u[q] <= tmid));
        if (cnt >= KNN) { phi = pmid; cntHi = cnt; } else plo = pmid + 1;
      }
      unsigned tstar = (phi << 16) | 0xFFFFu;  // bucket top
      unsigned bbase = phi << 16;              // bucket base
      int* op = idxg + (size_t)(b*NN + i) * KNN;
      if (cntHi < 0) {   // phi never measured (rare): recount
        cntHi = 0;
#pragma unroll
        for (int q = 0; q < 16; ++q)
          cntHi += (int)__popcll(__ballot(u[q] <= tstar));
      }
      if (cntHi == KNN) {
        // exact set: emit all <= tstar (index order; set-equivalent)
        int base = 0;
#pragma unroll
        for (int q = 0; q < 16; ++q) {
          bool pred = (u[q] <= tstar);
          unsigned long long mask = __ballot((int)pred);
          if (pred) op[base + (int)__popcll(mask & lmask_lt)] = q*64 + lane;
          base += (int)__popcll(mask);
        }
      } else {
        // slow path: refine low 16 bits -> exact 20th value xstar
        unsigned lo2 = bbase, hi2 = tstar;
        while (lo2 < hi2) {
          unsigned mid = lo2 + ((hi2 - lo2) >> 1);
          int cnt = 0;
#pragma unroll
          for (int q = 0; q < 16; ++q)
            cnt += (int)__popcll(__ballot(u[q] <= mid));
          if (cnt >= KNN) hi2 = mid; else lo2 = mid + 1;
        }
        unsigned xstar = lo2;
        int base = 0;
#pragma unroll
        for (int q = 0; q < 16; ++q) {
          bool pred = (u[q] < xstar);
          unsigned long long mask = __ballot((int)pred);
          if (pred) op[base + (int)__popcll(mask & lmask_lt)] = q*64 + lane;
          base += (int)__popcll(mask);
        }
        for (int q = 0; q < 16 && base < KNN; ++q) {  // ties, ascending index
          bool pred = (u[q] == xstar);
          unsigned long long mask = __ballot((int)pred);
          if (pred) {
            int pos_ = base + (int)__popcll(mask & lmask_lt);
            if (pos_ < KNN) op[pos_] = q*64 + lane;
          }
          base += (int)__popcll(mask);
        }
      }
    }
  } else {
    // ---------------- FPS branch: single wave, float DPP reduce, no barriers ----------------
    int b = blockIdx.x;
    const float* pb = pos + (size_t)b * NN * 3;
    for (int i = threadIdx.x; i < NN; i += 256)
      pj[i] = make_float4(pb[i*3], pb[i*3+1], pb[i*3+2], 0.f);
    __syncthreads();
    if (threadIdx.x >= 64) return;   // waves 1-3 done (after barrier)
    int lane = threadIdx.x;
    float px[16], py[16], pz[16], dist[16];
#pragma unroll
    for (int q = 0; q < 16; ++q) {
      float4 p = pj[q*64 + lane];
      px[q] = p.x; py[q] = p.y; pz[q] = p.z;
      dist[q] = 1e38f;
    }
    if (lane == 0) fidxg[b*MM] = 0;
    int cur = 0;
    for (int m = 1; m < MM; ++m) {
      float4 cp = pj[cur];             // wave-uniform LDS broadcast
#pragma unroll
      for (int q = 0; q < 16; ++q) {
        float dx = __fsub_rn(px[q], cp.x);
        float dy = __fsub_rn(py[q], cp.y);
        float dz = __fsub_rn(pz[q], cp.z);
        float dd = __fadd_rn(__fadd_rn(__fmul_rn(dx,dx), __fmul_rn(dy,dy)), __fmul_rn(dz,dz));
        dist[q] = fminf(dist[q], dd);
      }
      // per-lane max (float; all dist >= +0 so fmax == bit-max)
      float t8[8];
#pragma unroll
      for (int q = 0; q < 8; ++q) t8[q] = fmaxf(dist[q], dist[q + 8]);
#pragma unroll
      for (int q = 0; q < 4; ++q) t8[q] = fmaxf(t8[q], t8[q + 4]);
      float lmax = fmaxf(fmaxf(t8[0], t8[1]), fmaxf(t8[2], t8[3]));
      // wave max via DPP + v_max_f32 (result in lane 63)
      float r = lmax;
#define FPS_VMAX_STEP(C) { \
      int tt = __builtin_amdgcn_update_dpp(__float_as_int(r), __float_as_int(r), (C), 0xf, 0xf, false); \
      r = fmaxf(r, __int_as_float(tt)); }
      FPS_VMAX_STEP(0x111)   // row_shr:1
      FPS_VMAX_STEP(0x112)   // row_shr:2
      FPS_VMAX_STEP(0x114)   // row_shr:4
      FPS_VMAX_STEP(0x118)   // row_shr:8
      FPS_VMAX_STEP(0x142)   // row_bcast:15
      FPS_VMAX_STEP(0x143)   // row_bcast:31
#undef FPS_VMAX_STEP
      float wmax = __int_as_float(__builtin_amdgcn_readlane(__float_as_int(r), 63));
      // per-lane smallest matching index: descending q, last write wins
      unsigned ci = 0xFFFFFFFFu;
#pragma unroll
      for (int q = 15; q >= 0; --q)
        if (dist[q] == wmax) ci = (unsigned)(q*64 + lane);
      // wave min index via DPP + v_min_u32 (result in lane 63)
#define FPS_IMIN_STEP(C) { \
      unsigned tt = (unsigned)__builtin_amdgcn_update_dpp((int)ci, (int)ci, (C), 0xf, 0xf, false); \
      ci = (tt < ci) ? tt : ci; }
      FPS_IMIN_STEP(0x111)
      FPS_IMIN_STEP(0x112)
      FPS_IMIN_STEP(0x114)
      FPS_IMIN_STEP(0x118)
      FPS_IMIN_STEP(0x142)
      FPS_IMIN_STEP(0x143)
#undef FPS_IMIN_STEP
      cur = (int)(unsigned)__builtin_amdgcn_readlane((int)ci, 63);
      if (lane == 0) fidxg[b*MM + m] = cur;
    }
  }
}

// ---------------- stats of h1 = relu(rel@w1+b1) ----------------
__global__ __launch_bounds__(256) void stats1_kernel(const float* __restrict__ pos,
    const int* __restrict__ idxg, const float* __restrict__ w1,
    const float* __restrict__ b1, float* __restrict__ acc) {
  int b = blockIdx.x >> 4;
  int nb = blockIdx.x & 15;
  __shared__ float px[NN], py[NN], pz[NN];
  __shared__ float relx[4][KNN], rely[4][KNN], relz[4][KNN];
  __shared__ float red[4][CC];
  const float* pb = pos + (size_t)b*NN*3;
  for (int i = threadIdx.x; i < NN; i += 256) {
    px[i] = pb[i*3+0]; py[i] = pb[i*3+1]; pz[i] = pb[i*3+2];
  }
  int c = threadIdx.x & 63, w = threadIdx.x >> 6;
  float w1x = w1[c*3+0], w1y = w1[c*3+1], w1z = w1[c*3+2], b1c = b1[c];
  float s = 0.f, ss = 0.f;
  __syncthreads();
  for (int it = 0; it < 16; ++it) {
    int n0 = nb*64 + it*4;
    if (threadIdx.x < 80) {
      int wv = threadIdx.x / KNN, k = threadIdx.x % KNN;
      int n = n0 + wv;
      int j = idxg[(size_t)(b*NN + n)*KNN + k];
      relx[wv][k] = px[j] - px[n];
      rely[wv][k] = py[j] - py[n];
      relz[wv][k] = pz[j] - pz[n];
    }
    __syncthreads();
#pragma unroll
    for (int k = 0; k < KNN; ++k) {
      float h = fmaxf(relx[w][k]*w1x + rely[w][k]*w1y + relz[w][k]*w1z + b1c, 0.f);
      s += h; ss += h*h;
    }
    __syncthreads();
  }
  red[w][c] = s; __syncthreads();
  if (w == 0) atomicAdd(&acc[c], red[0][c]+red[1][c]+red[2][c]+red[3][c]);
  __syncthreads();
  red[w][c] = ss; __syncthreads();
  if (w == 0) atomicAdd(&acc[64+c], red[0][c]+red[1][c]+red[2][c]+red[3][c]);
}

// ---------------- fold BN1 into w2 (bf16 B-fragment layout) ----------------
// w2bf[((nt*4+ks)*64 + lane)*8 + j] = bf16(w2[cout][cin] * s1[cin])
//   cout = nt*32 + (lane&31), cin = ks*16 + (lane>>5)*8 + j
__global__ void fold1_kernel(const float* __restrict__ acc, const float* __restrict__ g1,
    const float* __restrict__ be1, const float* __restrict__ w2, const float* __restrict__ b2,
    unsigned short* __restrict__ w2bf, float* __restrict__ b2f) {
  __shared__ float s1[CC], t1[CC];
  int tid = threadIdx.x;  // 512 threads
  if (tid < CC) {
    float cnt = (float)CNT1;
    float m = acc[tid] / cnt;
    float v = acc[64+tid] / cnt - m*m;
    float sc = g1[tid] * rsqrtf(v + EPSF);
    s1[tid] = sc; t1[tid] = be1[tid] - m*sc;
  }
  __syncthreads();
  int frag = tid >> 6;        // 0..7  (nt = frag>>2, ks = frag&3)
  int lane = tid & 63;
  int nt = frag >> 2, ks = frag & 3;
  int cout = nt*32 + (lane & 31);
  int cin0 = ks*16 + (lane >> 5)*8;
  for (int j = 0; j < 8; ++j) {
    int cin = cin0 + j;
    w2bf[((size_t)frag*64 + lane)*8 + j] = f2bf(w2[cout*CC + cin] * s1[cin]);
  }
  if (tid < CC) {
    float accb = b2[tid];
    for (int ci = 0; ci < CC; ++ci) accb += t1[ci]*w2[tid*CC + ci];
    b2f[tid] = accb;
  }
}

// ---------------- conv2 via MFMA: h2 = relu(h1@w2'+b2'), maxh2 + stats ----------------
__global__ __launch_bounds__(256, 4) void conv2_kernel(const float* __restrict__ pos,
    const int* __restrict__ idxg, const float* __restrict__ w1, const float* __restrict__ b1,
    const unsigned short* __restrict__ w2bf, const float* __restrict__ b2fg,
    float* __restrict__ maxh2, float* __restrict__ acc2) {
  int b = blockIdx.x >> 4;
  int nb = blockIdx.x & 15;
  __shared__ float px[NN], py[NN], pz[NN];
  __shared__ float4 relw[4][KNN];
  __shared__ __align__(16) unsigned short h1s[4][2112];  // 8 groups * 264 ushorts
  __shared__ float redbuf[4][2*CC];
  const float* pb = pos + (size_t)b*NN*3;
  for (int i = threadIdx.x; i < NN; i += 256) {
    px[i] = pb[i*3+0]; py[i] = pb[i*3+1]; pz[i] = pb[i*3+2];
  }
  int lane = threadIdx.x & 63, w = threadIdx.x >> 6;
  int half = lane >> 5, l31 = lane & 31;
  short8 Bf[2][4];
#pragma unroll
  for (int nt = 0; nt < 2; ++nt)
#pragma unroll
    for (int ks = 0; ks < 4; ++ks)
      Bf[nt][ks] = *(const short8*)&w2bf[((size_t)(nt*4+ks)*64 + lane)*8];
  float b2o0 = b2fg[l31], b2o1 = b2fg[32 + l31];
  float w1x = w1[lane*3+0], w1y = w1[lane*3+1], w1z = w1[lane*3+2], b1c = b1[lane];
  unsigned short* hw = h1s[w];
  {
    short8 zz = {0,0,0,0,0,0,0,0};
    for (int z = lane; z < 96; z += 64) {
      int g = z / 12, r = 20 + z % 12;
      *(short8*)&hw[g*264 + r*8] = zz;
    }
  }
  float sA = 0.f, ssA = 0.f, sB = 0.f, ssB = 0.f;
  __syncthreads();
  for (int t = 0; t < 16; ++t) {
    int n = nb*64 + w*16 + t;
    if (lane < KNN) {
      int j = idxg[(size_t)(b*NN + n)*KNN + lane];
      relw[w][lane] = make_float4(px[j]-px[n], py[j]-py[n], pz[j]-pz[n], 0.f);
    }
    int gbase = (lane >> 3)*264 + (lane & 7);
#pragma unroll
    for (int k = 0; k < KNN; ++k) {
      float4 r4 = relw[w][k];   // wave-uniform broadcast read
      float h = fmaxf(fmaf(r4.x, w1x, fmaf(r4.y, w1y, fmaf(r4.z, w1z, b1c))), 0.f);
      hw[gbase + k*8] = f2bf(h);
    }
    f32x16 acc0 = {}; f32x16 acc1 = {};
#pragma unroll
    for (int ks = 0; ks < 4; ++ks) {
      short8 A = *(const short8*)&hw[(ks*2 + half)*264 + l31*8];
      acc0 = __builtin_amdgcn_mfma_f32_32x32x16_bf16(A, Bf[0][ks], acc0, 0, 0, 0);
      acc1 = __builtin_amdgcn_mfma_f32_32x32x16_bf16(A, Bf[1][ks], acc1, 0, 0, 0);
    }
    float mx0 = 0.f, mx1 = 0.f;
#pragma unroll
    for (int reg = 0; reg < 8; ++reg) {
      float v0 = fmaxf(acc0[reg] + b2o0, 0.f);
      float v1 = fmaxf(acc1[reg] + b2o1, 0.f);
      sA += v0; ssA += v0*v0; sB += v1; ssB += v1*v1;
      mx0 = fmaxf(mx0, v0); mx1 = fmaxf(mx1, v1);
    }
    if (half == 0) {
#pragma unroll
      for (int reg = 8; reg < 12; ++reg) {
        float v0 = fmaxf(acc0[reg] + b2o0, 0.f);
        float v1 = fmaxf(acc1[reg] + b2o1, 0.f);
        sA += v0; ssA += v0*v0; sB += v1; ssB += v1*v1;
        mx0 = fmaxf(mx0, v0); mx1 = fmaxf(mx1, v1);
      }
    }
    mx0 = fmaxf(mx0, __shfl_xor(mx0, 32, 64));
    mx1 = fmaxf(mx1, __shfl_xor(mx1, 32, 64));
    if (half == 0) {
      float* mp = maxh2 + (size_t)(b*NN + n)*CC;
      mp[l31] = mx0; mp[32 + l31] = mx1;
    }
  }
  sA += __shfl_xor(sA, 32, 64); ssA += __shfl_xor(ssA, 32, 64);
  sB += __shfl_xor(sB, 32, 64); ssB += __shfl_xor(ssB, 32, 64);
  if (half == 0) { redbuf[w][l31] = sA; redbuf[w][32 + l31] = sB; }
  __syncthreads();
  if (w == 0) atomicAdd(&acc2[lane], redbuf[0][lane]+redbuf[1][lane]+redbuf[2][lane]+redbuf[3][lane]);
  __syncthreads();
  if (half == 0) { redbuf[w][l31] = ssA; redbuf[w][32 + l31] = ssB; }
  __syncthreads();
  if (w == 0) atomicAdd(&acc2[64+lane], redbuf[0][lane]+redbuf[1][lane]+redbuf[2][lane]+redbuf[3][lane]);
}

// ---------------- finalize BN2 affine ----------------
__global__ void fold2_kernel(const float* __restrict__ acc2, const float* __restrict__ g2,
    const float* __restrict__ be2, float* __restrict__ s2, float* __restrict__ t2) {
  int c = threadIdx.x;
  float cnt = (float)CNT1;
  float m = acc2[c]/cnt;
  float v = acc2[64+c]/cnt - m*m;
  float sc = g2[c]*rsqrtf(v+EPSF);
  s2[c] = sc;
  t2[c] = be2[c] - m*sc;
}

// ---------------- head: Y[b,h] = relu(max_m(f@w_nn1^T)+b) ----------------
// 2 h-channels per thread (h, h+64): halves ds_read_b128 traffic per FLOP.
__global__ __launch_bounds__(256) void head_kernel(const float* __restrict__ maxh2,
    const int* __restrict__ fidxg, const float* __restrict__ s2g, const float* __restrict__ t2g,
    const float* __restrict__ wnn1, const float* __restrict__ bnn1, float* __restrict__ Y) {
  int b = blockIdx.x >> 2;
  int hc = blockIdx.x & 3;
  __shared__ __align__(16) float ftile[128][CC];
  __shared__ float red2[4][128];
  int hl = threadIdx.x & 63, mseg = threadIdx.x >> 6;   // 64 h-lanes x 4 msegs
  int hA = hc*128 + hl, hB = hA + 64;
  float4 wva[16], wvb[16];
  const float4* wrA = (const float4*)(wnn1 + (size_t)hA*CC);
  const float4* wrB = (const float4*)(wnn1 + (size_t)hB*CC);
#pragma unroll
  for (int q = 0; q < 16; ++q) { wva[q] = wrA[q]; wvb[q] = wrB[q]; }
  float bestA = -FLT_MAX, bestB = -FLT_MAX;
  const int* fb = fidxg + b*MM;
  for (int chunk = 0; chunk < 2; ++chunk) {
    {
      int row = threadIdx.x & 127, chal = threadIdx.x >> 7;
      int fi = fb[chunk*128 + row];
      const float* src = maxh2 + (size_t)(b*NN + fi)*CC;
      for (int ci = chal*32; ci < chal*32+32; ++ci)
        ftile[row][ci] = s2g[ci]*src[ci] + t2g[ci];
    }
    __syncthreads();
    for (int m = mseg*32; m < mseg*32+32; ++m) {
      float accA = 0.f, accB = 0.f;
#pragma unroll
      for (int cq = 0; cq < 16; ++cq) {
        float4 f = *((const float4*)&ftile[m][cq*4]);
        accA = fmaf(f.x, wva[cq].x, accA);
        accA = fmaf(f.y, wva[cq].y, accA);
        accA = fmaf(f.z, wva[cq].z, accA);
        accA = fmaf(f.w, wva[cq].w, accA);
        accB = fmaf(f.x, wvb[cq].x, accB);
        accB = fmaf(f.y, wvb[cq].y, accB);
        accB = fmaf(f.z, wvb[cq].z, accB);
        accB = fmaf(f.w, wvb[cq].w, accB);
      }
      bestA = fmaxf(bestA, accA);
      bestB = fmaxf(bestB, accB);
    }
    __syncthreads();
  }
  red2[mseg][hl] = bestA;
  red2[mseg][64 + hl] = bestB;
  __syncthreads();
  if (threadIdx.x < 128) {
    int hh = hc*128 + threadIdx.x;
    float v = fmaxf(fmaxf(red2[0][threadIdx.x], red2[1][threadIdx.x]),
                    fmaxf(red2[2][threadIdx.x], red2[3][threadIdx.x])) + bnn1[hh];
    Y[(size_t)b*HH + hh] = fmaxf(v, 0.f);
  }
}

// ---------------- BN over batch (two-pass) ----------------
__global__ void bn3_kernel(const float* __restrict__ Y, const float* __restrict__ g,
    const float* __restrict__ be, float* __restrict__ s3, float* __restrict__ t3) {
  int h = blockIdx.x*256 + threadIdx.x;
  float s = 0.f;
  for (int b = 0; b < BB; ++b) s += Y[(size_t)b*HH + h];
  float m = s / (float)BB;
  float v = 0.f;
  for (int b = 0; b < BB; ++b) { float d = Y[(size_t)b*HH + h] - m; v += d*d; }
  v /= (float)BB;
  float sc = g[h] * rsqrtf(v + EPSF);
  s3[h] = sc; t3[h] = be[h] - m*sc;
}

// ---------------- logits + log_softmax ----------------
__global__ __launch_bounds__(256) void logits_kernel(const float* __restrict__ Y,
    const float* __restrict__ s3, const float* __restrict__ t3,
    const float* __restrict__ w4, const float* __restrict__ b4, float* __restrict__ out) {
  int b = blockIdx.x;
  __shared__ float ybn[HH];
  __shared__ float lg[NCLS];
  __shared__ float lse;
  for (int hh = threadIdx.x; hh < HH; hh += 256)
    ybn[hh] = Y[(size_t)b*HH + hh]*s3[hh] + t3[hh];
  __syncthreads();
  if (threadIdx.x < NCLS) {
    int j = threadIdx.x;
    float acc = b4[j];
    const float* wr = w4 + (size_t)j*HH;
    for (int ci = 0; ci < HH; ++ci) acc = fmaf(ybn[ci], wr[ci], acc);
    lg[j] = acc;
  }
  __syncthreads();
  if (threadIdx.x == 0) {
    float mx = -FLT_MAX;
    for (int j = 0; j < NCLS; ++j) mx = fmaxf(mx, lg[j]);
    float s = 0.f;
    for (int j = 0; j < NCLS; ++j) s += expf(lg[j] - mx);
    lse = mx + logf(s);
  }
  __syncthreads();
  if (threadIdx.x < NCLS) out[b*NCLS + threadIdx.x] = lg[threadIdx.x] - lse;
}

extern "C" void kernel_launch(void* const* d_in, const int* in_sizes, int n_in,
                              void* d_out, int out_size, void* d_ws, size_t ws_size,
                              hipStream_t stream) {
  const float* pos  = (const float*)d_in[0];
  const float* w1   = (const float*)d_in[1];
  const float* b1   = (const float*)d_in[2];
  const float* g1   = (const float*)d_in[3];
  const float* be1  = (const float*)d_in[4];
  const float* w2   = (const float*)d_in[5];
  const float* b2   = (const float*)d_in[6];
  const float* g2   = (const float*)d_in[7];
  const float* be2  = (const float*)d_in[8];
  const float* wnn1 = (const float*)d_in[9];
  const float* bnn1 = (const float*)d_in[10];
  const float* gbn2 = (const float*)d_in[11];
  const float* bebn2= (const float*)d_in[12];
  const float* wnn4 = (const float*)d_in[13];
  const float* bnn4 = (const float*)d_in[14];
  float* ws = (float*)d_ws;
  int*   idxg  = (int*)(ws + IDX_OFF);
  float* maxh2 = ws + MAXH2_OFF;
  int*   fidxg = (int*)(ws + FIDX_OFF);
  float* Y     = ws + Y_OFF;
  float* acc1  = ws + ACC_OFF;
  float* acc2  = ws + ACC_OFF + 128;
  unsigned short* w2bf = (unsigned short*)(ws + W2T_OFF);
  float* b2f   = ws + B2F_OFF;
  float* s2    = ws + S2_OFF;
  float* t2    = ws + T2_OFF;
  float* s3    = ws + S3_OFF;
  float* t3    = ws + T3_OFF;
  float* outp  = (float*)d_out;

  hipMemsetAsync((void*)(ws + ACC_OFF), 0, 256*sizeof(float), stream);
  knn_fps_kernel<<<BB + BB*32, 256, 0, stream>>>(pos, idxg, fidxg);
  stats1_kernel<<<BB*16, 256, 0, stream>>>(pos, idxg, w1, b1, acc1);
  fold1_kernel<<<1, 512, 0, stream>>>(acc1, g1, be1, w2, b2, w2bf, b2f);
  conv2_kernel<<<BB*16, 256, 0, stream>>>(pos, idxg, w1, b1, w2bf, b2f, maxh2, acc2);
  fold2_kernel<<<1, 64, 0, stream>>>(acc2, g2, be2, s2, t2);
  head_kernel<<<BB*4, 256, 0, stream>>>(maxh2, fidxg, s2, t2, wnn1, bnn1, Y);
  bn3_kernel<<<2, 256, 0, stream>>>(Y, gbn2, bebn2, s3, t3);
  logits_kernel<<<BB, 256, 0, stream>>>(Y, s3, t3, wnn4, bnn4, outp);
}

// Round 9
// 371.392 us; speedup vs baseline: 4.9271x; 1.0235x over previous
//
#include <hip/hip_runtime.h>
#include <hip/hip_bf16.h>
#include <cfloat>
#include <math.h>

#define BB 64
#define NN 1024
#define KNN 20
#define MM 256
#define CC 64
#define HH 512
#define NCLS 40
#define EPSF 1e-5f
#define CNT1 (BB*NN*KNN)

// FPS phase boundaries: phase1 rounds [1,FPS_R1), phase2 [FPS_R1,FPS_R2),
// phase3 [FPS_R2,MM). Tuned to hide each slice under its host dispatch.
#define FPS_R1 101
#define FPS_R2 151

// workspace offsets (in 4-byte elements)
#define IDX_OFF    0
#define MAXH2_OFF  (IDX_OFF + BB*NN*KNN)      // int idx then floats
#define FIDX_OFF   (MAXH2_OFF + BB*NN*CC)
#define Y_OFF      (FIDX_OFF + BB*MM)
#define ACC_OFF    (Y_OFF + BB*HH)            // 256 floats zeroed: sum1[64],sumsq1[64],sum2[64],sumsq2[64]
#define W2T_OFF    (ACC_OFF + 256)            // w2' bf16 B-frags (2048 ushorts) + b2f
#define B2F_OFF    (W2T_OFF + CC*CC)
#define S2_OFF     (B2F_OFF + CC)
#define T2_OFF     (S2_OFF + CC)
#define S3_OFF     (T2_OFF + CC)
#define T3_OFF     (S3_OFF + HH)
#define FPSD_OFF   (T3_OFF + HH)              // BB*NN floats: FPS dist state
#define FPSC_OFF   (FPSD_OFF + BB*NN)         // BB ints: FPS cur state

typedef __attribute__((ext_vector_type(8)))  short short8;
typedef __attribute__((ext_vector_type(16))) float f32x16;

static __device__ __forceinline__ unsigned short f2bf(float f) {
  unsigned u = __float_as_uint(f);
  unsigned r = (u + 0x7fffu + ((u >> 16) & 1u)) >> 16;   // RNE
  return (unsigned short)r;
}

// ---------------- FPS phase (single wave; caller: threadIdx.x < 64) ----------------
// All-float reduction (dist >= +0 so fmaxf == bit-max, float eq == bit eq);
// bit-exact vs numpy (max dist, ties -> smallest index). State checkpointed
// to global between phases.
static __device__ __forceinline__ void fps_phase(
    const float* sx, const float* sy, const float* sz,   // LDS, NN each
    float* fpsd, int* fpsc, int* fidxg, int b, int mStart, int mEnd) {
  int lane = threadIdx.x;
  float lx[16], ly[16], lz[16], dist[16];
#pragma unroll
  for (int q = 0; q < 16; ++q) {
    int j = q*64 + lane;
    lx[q] = sx[j]; ly[q] = sy[j]; lz[q] = sz[j];
  }
  int cur;
  if (mStart <= 1) {
#pragma unroll
    for (int q = 0; q < 16; ++q) dist[q] = 1e38f;
    if (lane == 0) fidxg[b*MM] = 0;
    cur = 0;
  } else {
#pragma unroll
    for (int q = 0; q < 16; ++q) dist[q] = fpsd[b*NN + q*64 + lane];
    cur = fpsc[b];
  }
  for (int m = mStart; m < mEnd; ++m) {
    float cpx = sx[cur], cpy = sy[cur], cpz = sz[cur];   // uniform LDS broadcast
#pragma unroll
    for (int q = 0; q < 16; ++q) {
      float dx = __fsub_rn(lx[q], cpx);
      float dy = __fsub_rn(ly[q], cpy);
      float dz = __fsub_rn(lz[q], cpz);
      float dd = __fadd_rn(__fadd_rn(__fmul_rn(dx,dx), __fmul_rn(dy,dy)), __fmul_rn(dz,dz));
      dist[q] = fminf(dist[q], dd);
    }
    float t8[8];
#pragma unroll
    for (int q = 0; q < 8; ++q) t8[q] = fmaxf(dist[q], dist[q + 8]);
#pragma unroll
    for (int q = 0; q < 4; ++q) t8[q] = fmaxf(t8[q], t8[q + 4]);
    float r = fmaxf(fmaxf(t8[0], t8[1]), fmaxf(t8[2], t8[3]));
#define FPS_VMAX_STEP(C) { \
    int tt = __builtin_amdgcn_update_dpp(__float_as_int(r), __float_as_int(r), (C), 0xf, 0xf, false); \
    r = fmaxf(r, __int_as_float(tt)); }
    FPS_VMAX_STEP(0x111)   // row_shr:1
    FPS_VMAX_STEP(0x112)   // row_shr:2
    FPS_VMAX_STEP(0x114)   // row_shr:4
    FPS_VMAX_STEP(0x118)   // row_shr:8
    FPS_VMAX_STEP(0x142)   // row_bcast:15
    FPS_VMAX_STEP(0x143)   // row_bcast:31
#undef FPS_VMAX_STEP
    float wmax = __int_as_float(__builtin_amdgcn_readlane(__float_as_int(r), 63));
    unsigned ci = 0xFFFFFFFFu;
#pragma unroll
    for (int q = 15; q >= 0; --q)
      if (dist[q] == wmax) ci = (unsigned)(q*64 + lane);
#define FPS_IMIN_STEP(C) { \
    unsigned tt = (unsigned)__builtin_amdgcn_update_dpp((int)ci, (int)ci, (C), 0xf, 0xf, false); \
    ci = (tt < ci) ? tt : ci; }
    FPS_IMIN_STEP(0x111)
    FPS_IMIN_STEP(0x112)
    FPS_IMIN_STEP(0x114)
    FPS_IMIN_STEP(0x118)
    FPS_IMIN_STEP(0x142)
    FPS_IMIN_STEP(0x143)
#undef FPS_IMIN_STEP
    cur = (int)(unsigned)__builtin_amdgcn_readlane((int)ci, 63);
    if (lane == 0) fidxg[b*MM + m] = cur;
  }
  if (mEnd < MM) {   // checkpoint
#pragma unroll
    for (int q = 0; q < 16; ++q) fpsd[b*NN + q*64 + lane] = dist[q];
    if (lane == 0) fpsc[b] = cur;
  }
}

// ---------------- fused FPS(phase1) + kNN ----------------
// blocks [0, BB): FPS rounds [1, FPS_R1).
// blocks [BB, BB + BB*32): kNN, one wave per 8 queries (R6/R7-proven logic).
__global__ __launch_bounds__(256) void knn_fps_kernel(const float* __restrict__ pos,
                                                      int* __restrict__ idxg,
                                                      int* __restrict__ fidxg,
                                                      float* __restrict__ fpsd,
                                                      int* __restrict__ fpsc) {
  __shared__ float4 pj[NN];
  if (blockIdx.x >= BB) {
    // ---------------- kNN branch ----------------
    int blk = blockIdx.x - BB;
    int b  = blk >> 5;   // cloud
    int nb = blk & 31;   // 32-point segment of the cloud
    const float* pb = pos + (size_t)b * NN * 3;
    for (int i = threadIdx.x; i < NN; i += 256) {
      float x = pb[i*3+0], y = pb[i*3+1], z = pb[i*3+2];
      pj[i] = make_float4(x, y, z, (x*x + y*y) + z*z);
    }
    __syncthreads();
    int lane = threadIdx.x & 63;
    int wv   = threadIdx.x >> 6;
    unsigned long long lmask_lt = (1ULL << lane) - 1ULL;

    for (int t = 0; t < 8; ++t) {
      int i = nb*32 + wv*8 + t;        // query point (wave-uniform)
      float4 pi = pj[i];               // LDS broadcast
      unsigned u[16];
#pragma unroll
      for (int q = 0; q < 16; ++q) {
        int j = q*64 + lane;
        float4 pw = pj[j];
        float d = pi.w + pw.w - 2.0f*(pi.x*pw.x + pi.y*pw.y + pi.z*pw.z);
        unsigned bits = __float_as_uint(d);
        bits = (bits & 0x80000000u) ? ~bits : (bits | 0x80000000u);
        if (j == i) bits = 0xFFFFFFFFu;   // self excluded (diag = +inf)
        u[q] = bits;
      }
      // per-lane min of 16, then wave-min and wave-max-of-lane-mins via DPP
      unsigned lmin = u[0];
#pragma unroll
      for (int q = 1; q < 16; ++q) lmin = (u[q] < lmin) ? u[q] : lmin;
      unsigned rmin = lmin, rmax = lmin;
#define KNN_DPP_STEP(C) { \
      unsigned t1 = (unsigned)__builtin_amdgcn_update_dpp((int)rmin, (int)rmin, (C), 0xf, 0xf, false); \
      unsigned t2 = (unsigned)__builtin_amdgcn_update_dpp((int)rmax, (int)rmax, (C), 0xf, 0xf, false); \
      rmin = (t1 < rmin) ? t1 : rmin; rmax = (t2 > rmax) ? t2 : rmax; }
      KNN_DPP_STEP(0x111)   // row_shr:1
      KNN_DPP_STEP(0x112)   // row_shr:2
      KNN_DPP_STEP(0x114)   // row_shr:4
      KNN_DPP_STEP(0x118)   // row_shr:8
      KNN_DPP_STEP(0x142)   // row_bcast:15
      KNN_DPP_STEP(0x143)   // row_bcast:31
#undef KNN_DPP_STEP
      unsigned plo = ((unsigned)__builtin_amdgcn_readlane((int)rmin, 63)) >> 16;
      unsigned phi = ((unsigned)__builtin_amdgcn_readlane((int)rmax, 63)) >> 16;
      // narrowed binary search; carry the count measured at the final phi
      int cntHi = -1;
      while (plo < phi) {                 // wave-uniform
        unsigned pmid = (plo + phi) >> 1;
        unsigned tmid = (pmid << 16) | 0xFFFFu;
        int cnt = 0;
#pragma unroll
        for (int q = 0; q < 16; ++q)
          cnt += (int)__popcll(__ballot(u[q] <= tmid));
        if (cnt >= KNN) { phi = pmid; cntHi = cnt; } else plo = pmid + 1;
      }
      unsigned tstar = (phi << 16) | 0xFFFFu;  // bucket top
      unsigned bbase = phi << 16;              // bucket base
      int* op = idxg + (size_t)(b*NN + i) * KNN;
      if (cntHi < 0) {   // phi never measured (rare): recount
        cntHi = 0;
#pragma unroll
        for (int q = 0; q < 16; ++q)
          cntHi += (int)__popcll(__ballot(u[q] <= tstar));
      }
      if (cntHi == KNN) {
        // exact set: emit all <= tstar (index order; set-equivalent)
        int base = 0;
#pragma unroll
        for (int q = 0; q < 16; ++q) {
          bool pred = (u[q] <= tstar);
          unsigned long long mask = __ballot((int)pred);
          if (pred) op[base + (int)__popcll(mask & lmask_lt)] = q*64 + lane;
          base += (int)__popcll(mask);
        }
      } else {
        // slow path: refine low 16 bits -> exact 20th value xstar
        unsigned lo2 = bbase, hi2 = tstar;
        while (lo2 < hi2) {
          unsigned mid = lo2 + ((hi2 - lo2) >> 1);
          int cnt = 0;
#pragma unroll
          for (int q = 0; q < 16; ++q)
            cnt += (int)__popcll(__ballot(u[q] <= mid));
          if (cnt >= KNN) hi2 = mid; else lo2 = mid + 1;
        }
        unsigned xstar = lo2;
        int base = 0;
#pragma unroll
        for (int q = 0; q < 16; ++q) {
          bool pred = (u[q] < xstar);
          unsigned long long mask = __ballot((int)pred);
          if (pred) op[base + (int)__popcll(mask & lmask_lt)] = q*64 + lane;
          base += (int)__popcll(mask);
        }
        for (int q = 0; q < 16 && base < KNN; ++q) {  // ties, ascending index
          bool pred = (u[q] == xstar);
          unsigned long long mask = __ballot((int)pred);
          if (pred) {
            int pos_ = base + (int)__popcll(mask & lmask_lt);
            if (pos_ < KNN) op[pos_] = q*64 + lane;
          }
          base += (int)__popcll(mask);
        }
      }
    }
  } else {
    // ---------------- FPS phase 1 ----------------
    int b = blockIdx.x;
    float* base = (float*)pj;            // reuse 16 KB as 3 x NN floats
    float* sx = base; float* sy = base + NN; float* sz = base + 2*NN;
    const float* pb = pos + (size_t)b * NN * 3;
    for (int i = threadIdx.x; i < NN; i += 256) {
      sx[i] = pb[i*3+0]; sy[i] = pb[i*3+1]; sz[i] = pb[i*3+2];
    }
    __syncthreads();
    if (threadIdx.x >= 64) return;
    fps_phase(sx, sy, sz, fpsd, fpsc, fidxg, b, 1, FPS_R1);
  }
}

// ---------------- stats of h1 + FPS phase 2 ----------------
__global__ __launch_bounds__(256) void stats1_kernel(const float* __restrict__ pos,
    const int* __restrict__ idxg, const float* __restrict__ w1,
    const float* __restrict__ b1, float* __restrict__ acc,
    int* __restrict__ fidxg, float* __restrict__ fpsd, int* __restrict__ fpsc) {
  __shared__ float px[NN], py[NN], pz[NN];
  __shared__ float relx[4][KNN], rely[4][KNN], relz[4][KNN];
  __shared__ float red[4][CC];
  if (blockIdx.x < BB) {
    // ---------------- FPS phase 2 ----------------
    int b = blockIdx.x;
    const float* pb = pos + (size_t)b*NN*3;
    for (int i = threadIdx.x; i < NN; i += 256) {
      px[i] = pb[i*3+0]; py[i] = pb[i*3+1]; pz[i] = pb[i*3+2];
    }
    __syncthreads();
    if (threadIdx.x >= 64) return;
    fps_phase(px, py, pz, fpsd, fpsc, fidxg, b, FPS_R1, FPS_R2);
    return;
  }
  int blk = blockIdx.x - BB;
  int b = blk >> 4;
  int nb = blk & 15;
  const float* pb = pos + (size_t)b*NN*3;
  for (int i = threadIdx.x; i < NN; i += 256) {
    px[i] = pb[i*3+0]; py[i] = pb[i*3+1]; pz[i] = pb[i*3+2];
  }
  int c = threadIdx.x & 63, w = threadIdx.x >> 6;
  float w1x = w1[c*3+0], w1y = w1[c*3+1], w1z = w1[c*3+2], b1c = b1[c];
  float s = 0.f, ss = 0.f;
  __syncthreads();
  for (int it = 0; it < 16; ++it) {
    int n0 = nb*64 + it*4;
    if (threadIdx.x < 80) {
      int wv = threadIdx.x / KNN, k = threadIdx.x % KNN;
      int n = n0 + wv;
      int j = idxg[(size_t)(b*NN + n)*KNN + k];
      relx[wv][k] = px[j] - px[n];
      rely[wv][k] = py[j] - py[n];
      relz[wv][k] = pz[j] - pz[n];
    }
    __syncthreads();
#pragma unroll
    for (int k = 0; k < KNN; ++k) {
      float h = fmaxf(relx[w][k]*w1x + rely[w][k]*w1y + relz[w][k]*w1z + b1c, 0.f);
      s += h; ss += h*h;
    }
    __syncthreads();
  }
  red[w][c] = s; __syncthreads();
  if (w == 0) atomicAdd(&acc[c], red[0][c]+red[1][c]+red[2][c]+red[3][c]);
  __syncthreads();
  red[w][c] = ss; __syncthreads();
  if (w == 0) atomicAdd(&acc[64+c], red[0][c]+red[1][c]+red[2][c]+red[3][c]);
}

// ---------------- fold BN1 into w2 (bf16 B-fragment layout) ----------------
__global__ void fold1_kernel(const float* __restrict__ acc, const float* __restrict__ g1,
    const float* __restrict__ be1, const float* __restrict__ w2, const float* __restrict__ b2,
    unsigned short* __restrict__ w2bf, float* __restrict__ b2f) {
  __shared__ float s1[CC], t1[CC];
  int tid = threadIdx.x;  // 512 threads
  if (tid < CC) {
    float cnt = (float)CNT1;
    float m = acc[tid] / cnt;
    float v = acc[64+tid] / cnt - m*m;
    float sc = g1[tid] * rsqrtf(v + EPSF);
    s1[tid] = sc; t1[tid] = be1[tid] - m*sc;
  }
  __syncthreads();
  int frag = tid >> 6;        // 0..7  (nt = frag>>2, ks = frag&3)
  int lane = tid & 63;
  int nt = frag >> 2, ks = frag & 3;
  int cout = nt*32 + (lane & 31);
  int cin0 = ks*16 + (lane >> 5)*8;
  for (int j = 0; j < 8; ++j) {
    int cin = cin0 + j;
    w2bf[((size_t)frag*64 + lane)*8 + j] = f2bf(w2[cout*CC + cin] * s1[cin]);
  }
  if (tid < CC) {
    float accb = b2[tid];
    for (int ci = 0; ci < CC; ++ci) accb += t1[ci]*w2[tid*CC + ci];
    b2f[tid] = accb;
  }
}

// ---------------- conv2 via MFMA + FPS phase 3 ----------------
__global__ __launch_bounds__(256, 4) void conv2_kernel(const float* __restrict__ pos,
    const int* __restrict__ idxg, const float* __restrict__ w1, const float* __restrict__ b1,
    const unsigned short* __restrict__ w2bf, const float* __restrict__ b2fg,
    float* __restrict__ maxh2, float* __restrict__ acc2,
    int* __restrict__ fidxg, float* __restrict__ fpsd, int* __restrict__ fpsc) {
  __shared__ float px[NN], py[NN], pz[NN];
  __shared__ float4 relw[4][KNN];
  __shared__ __align__(16) unsigned short h1s[4][2112];  // 8 groups * 264 ushorts
  __shared__ float redbuf[4][2*CC];
  if (blockIdx.x < BB) {
    // ---------------- FPS phase 3 ----------------
    int b = blockIdx.x;
    const float* pb = pos + (size_t)b*NN*3;
    for (int i = threadIdx.x; i < NN; i += 256) {
      px[i] = pb[i*3+0]; py[i] = pb[i*3+1]; pz[i] = pb[i*3+2];
    }
    __syncthreads();
    if (threadIdx.x >= 64) return;
    fps_phase(px, py, pz, fpsd, fpsc, fidxg, b, FPS_R2, MM);
    return;
  }
  int blk = blockIdx.x - BB;
  int b = blk >> 4;
  int nb = blk & 15;
  const float* pb = pos + (size_t)b*NN*3;
  for (int i = threadIdx.x; i < NN; i += 256) {
    px[i] = pb[i*3+0]; py[i] = pb[i*3+1]; pz[i] = pb[i*3+2];
  }
  int lane = threadIdx.x & 63, w = threadIdx.x >> 6;
  int half = lane >> 5, l31 = lane & 31;
  short8 Bf[2][4];
#pragma unroll
  for (int nt = 0; nt < 2; ++nt)
#pragma unroll
    for (int ks = 0; ks < 4; ++ks)
      Bf[nt][ks] = *(const short8*)&w2bf[((size_t)(nt*4+ks)*64 + lane)*8];
  float b2o0 = b2fg[l31], b2o1 = b2fg[32 + l31];
  float w1x = w1[lane*3+0], w1y = w1[lane*3+1], w1z = w1[lane*3+2], b1c = b1[lane];
  unsigned short* hw = h1s[w];
  {
    short8 zz = {0,0,0,0,0,0,0,0};
    for (int z = lane; z < 96; z += 64) {
      int g = z / 12, r = 20 + z % 12;
      *(short8*)&hw[g*264 + r*8] = zz;
    }
  }
  float sA = 0.f, ssA = 0.f, sB = 0.f, ssB = 0.f;
  __syncthreads();
  for (int t = 0; t < 16; ++t) {
    int n = nb*64 + w*16 + t;
    if (lane < KNN) {
      int j = idxg[(size_t)(b*NN + n)*KNN + lane];
      relw[w][lane] = make_float4(px[j]-px[n], py[j]-py[n], pz[j]-pz[n], 0.f);
    }
    int gbase = (lane >> 3)*264 + (lane & 7);
#pragma unroll
    for (int k = 0; k < KNN; ++k) {
      float4 r4 = relw[w][k];   // wave-uniform broadcast read
      float h = fmaxf(fmaf(r4.x, w1x, fmaf(r4.y, w1y, fmaf(r4.z, w1z, b1c))), 0.f);
      hw[gbase + k*8] = f2bf(h);
    }
    f32x16 acc0 = {}; f32x16 acc1 = {};
#pragma unroll
    for (int ks = 0; ks < 4; ++ks) {
      short8 A = *(const short8*)&hw[(ks*2 + half)*264 + l31*8];
      acc0 = __builtin_amdgcn_mfma_f32_32x32x16_bf16(A, Bf[0][ks], acc0, 0, 0, 0);
      acc1 = __builtin_amdgcn_mfma_f32_32x32x16_bf16(A, Bf[1][ks], acc1, 0, 0, 0);
    }
    float mx0 = 0.f, mx1 = 0.f;
#pragma unroll
    for (int reg = 0; reg < 8; ++reg) {
      float v0 = fmaxf(acc0[reg] + b2o0, 0.f);
      float v1 = fmaxf(acc1[reg] + b2o1, 0.f);
      sA += v0; ssA += v0*v0; sB += v1; ssB += v1*v1;
      mx0 = fmaxf(mx0, v0); mx1 = fmaxf(mx1, v1);
    }
    if (half == 0) {
#pragma unroll
      for (int reg = 8; reg < 12; ++reg) {
        float v0 = fmaxf(acc0[reg] + b2o0, 0.f);
        float v1 = fmaxf(acc1[reg] + b2o1, 0.f);
        sA += v0; ssA += v0*v0; sB += v1; ssB += v1*v1;
        mx0 = fmaxf(mx0, v0); mx1 = fmaxf(mx1, v1);
      }
    }
    mx0 = fmaxf(mx0, __shfl_xor(mx0, 32, 64));
    mx1 = fmaxf(mx1, __shfl_xor(mx1, 32, 64));
    if (half == 0) {
      float* mp = maxh2 + (size_t)(b*NN + n)*CC;
      mp[l31] = mx0; mp[32 + l31] = mx1;
    }
  }
  sA += __shfl_xor(sA, 32, 64); ssA += __shfl_xor(ssA, 32, 64);
  sB += __shfl_xor(sB, 32, 64); ssB += __shfl_xor(ssB, 32, 64);
  if (half == 0) { redbuf[w][l31] = sA; redbuf[w][32 + l31] = sB; }
  __syncthreads();
  if (w == 0) atomicAdd(&acc2[lane], redbuf[0][lane]+redbuf[1][lane]+redbuf[2][lane]+redbuf[3][lane]);
  __syncthreads();
  if (half == 0) { redbuf[w][l31] = ssA; redbuf[w][32 + l31] = ssB; }
  __syncthreads();
  if (w == 0) atomicAdd(&acc2[64+lane], redbuf[0][lane]+redbuf[1][lane]+redbuf[2][lane]+redbuf[3][lane]);
}

// ---------------- finalize BN2 affine ----------------
__global__ void fold2_kernel(const float* __restrict__ acc2, const float* __restrict__ g2,
    const float* __restrict__ be2, float* __restrict__ s2, float* __restrict__ t2) {
  int c = threadIdx.x;
  float cnt = (float)CNT1;
  float m = acc2[c]/cnt;
  float v = acc2[64+c]/cnt - m*m;
  float sc = g2[c]*rsqrtf(v+EPSF);
  s2[c] = sc;
  t2[c] = be2[c] - m*sc;
}

// ---------------- head: Y[b,h] = relu(max_m(f@w_nn1^T)+b) ----------------
// 2 h-channels per thread (h, h+64): halves ds_read_b128 traffic per FLOP.
__global__ __launch_bounds__(256) void head_kernel(const float* __restrict__ maxh2,
    const int* __restrict__ fidxg, const float* __restrict__ s2g, const float* __restrict__ t2g,
    const float* __restrict__ wnn1, const float* __restrict__ bnn1, float* __restrict__ Y) {
  int b = blockIdx.x >> 2;
  int hc = blockIdx.x & 3;
  __shared__ __align__(16) float ftile[128][CC];
  __shared__ float red2[4][128];
  int hl = threadIdx.x & 63, mseg = threadIdx.x >> 6;   // 64 h-lanes x 4 msegs
  int hA = hc*128 + hl, hB = hA + 64;
  float4 wva[16], wvb[16];
  const float4* wrA = (const float4*)(wnn1 + (size_t)hA*CC);
  const float4* wrB = (const float4*)(wnn1 + (size_t)hB*CC);
#pragma unroll
  for (int q = 0; q < 16; ++q) { wva[q] = wrA[q]; wvb[q] = wrB[q]; }
  float bestA = -FLT_MAX, bestB = -FLT_MAX;
  const int* fb = fidxg + b*MM;
  for (int chunk = 0; chunk < 2; ++chunk) {
    {
      int row = threadIdx.x & 127, chal = threadIdx.x >> 7;
      int fi = fb[chunk*128 + row];
      const float* src = maxh2 + (size_t)(b*NN + fi)*CC;
      for (int ci = chal*32; ci < chal*32+32; ++ci)
        ftile[row][ci] = s2g[ci]*src[ci] + t2g[ci];
    }
    __syncthreads();
    for (int m = mseg*32; m < mseg*32+32; ++m) {
      float accA = 0.f, accB = 0.f;
#pragma unroll
      for (int cq = 0; cq < 16; ++cq) {
        float4 f = *((const float4*)&ftile[m][cq*4]);
        accA = fmaf(f.x, wva[cq].x, accA);
        accA = fmaf(f.y, wva[cq].y, accA);
        accA = fmaf(f.z, wva[cq].z, accA);
        accA = fmaf(f.w, wva[cq].w, accA);
        accB = fmaf(f.x, wvb[cq].x, accB);
        accB = fmaf(f.y, wvb[cq].y, accB);
        accB = fmaf(f.z, wvb[cq].z, accB);
        accB = fmaf(f.w, wvb[cq].w, accB);
      }
      bestA = fmaxf(bestA, accA);
      bestB = fmaxf(bestB, accB);
    }
    __syncthreads();
  }
  red2[mseg][hl] = bestA;
  red2[mseg][64 + hl] = bestB;
  __syncthreads();
  if (threadIdx.x < 128) {
    int hh = hc*128 + threadIdx.x;
    float v = fmaxf(fmaxf(red2[0][threadIdx.x], red2[1][threadIdx.x]),
                    fmaxf(red2[2][threadIdx.x], red2[3][threadIdx.x])) + bnn1[hh];
    Y[(size_t)b*HH + hh] = fmaxf(v, 0.f);
  }
}

// ---------------- BN over batch (two-pass) ----------------
__global__ void bn3_kernel(const float* __restrict__ Y, const float* __restrict__ g,
    const float* __restrict__ be, float* __restrict__ s3, float* __restrict__ t3) {
  int h = blockIdx.x*256 + threadIdx.x;
  float s = 0.f;
  for (int b = 0; b < BB; ++b) s += Y[(size_t)b*HH + h];
  float m = s / (float)BB;
  float v = 0.f;
  for (int b = 0; b < BB; ++b) { float d = Y[(size_t)b*HH + h] - m; v += d*d; }
  v /= (float)BB;
  float sc = g[h] * rsqrtf(v + EPSF);
  s3[h] = sc; t3[h] = be[h] - m*sc;
}

// ---------------- logits + log_softmax ----------------
__global__ __launch_bounds__(256) void logits_kernel(const float* __restrict__ Y,
    const float* __restrict__ s3, const float* __restrict__ t3,
    const float* __restrict__ w4, const float* __restrict__ b4, float* __restrict__ out) {
  int b = blockIdx.x;
  __shared__ float ybn[HH];
  __shared__ float lg[NCLS];
  __shared__ float lse;
  for (int hh = threadIdx.x; hh < HH; hh += 256)
    ybn[hh] = Y[(size_t)b*HH + hh]*s3[hh] + t3[hh];
  __syncthreads();
  if (threadIdx.x < NCLS) {
    int j = threadIdx.x;
    float acc = b4[j];
    const float* wr = w4 + (size_t)j*HH;
    for (int ci = 0; ci < HH; ++ci) acc = fmaf(ybn[ci], wr[ci], acc);
    lg[j] = acc;
  }
  __syncthreads();
  if (threadIdx.x == 0) {
    float mx = -FLT_MAX;
    for (int j = 0; j < NCLS; ++j) mx = fmaxf(mx, lg[j]);
    float s = 0.f;
    for (int j = 0; j < NCLS; ++j) s += expf(lg[j] - mx);
    lse = mx + logf(s);
  }
  __syncthreads();
  if (threadIdx.x < NCLS) out[b*NCLS + threadIdx.x] = lg[threadIdx.x] - lse;
}

extern "C" void kernel_launch(void* const* d_in, const int* in_sizes, int n_in,
                              void* d_out, int out_size, void* d_ws, size_t ws_size,
                              hipStream_t stream) {
  const float* pos  = (const float*)d_in[0];
  const float* w1   = (const float*)d_in[1];
  const float* b1   = (const float*)d_in[2];
  const float* g1   = (const float*)d_in[3];
  const float* be1  = (const float*)d_in[4];
  const float* w2   = (const float*)d_in[5];
  const float* b2   = (const float*)d_in[6];
  const float* g2   = (const float*)d_in[7];
  const float* be2  = (const float*)d_in[8];
  const float* wnn1 = (const float*)d_in[9];
  const float* bnn1 = (const float*)d_in[10];
  const float* gbn2 = (const float*)d_in[11];
  const float* bebn2= (const float*)d_in[12];
  const float* wnn4 = (const float*)d_in[13];
  const float* bnn4 = (const float*)d_in[14];
  float* ws = (float*)d_ws;
  int*   idxg  = (int*)(ws + IDX_OFF);
  float* maxh2 = ws + MAXH2_OFF;
  int*   fidxg = (int*)(ws + FIDX_OFF);
  float* Y     = ws + Y_OFF;
  float* acc1  = ws + ACC_OFF;
  float* acc2  = ws + ACC_OFF + 128;
  unsigned short* w2bf = (unsigned short*)(ws + W2T_OFF);
  float* b2f   = ws + B2F_OFF;
  float* s2    = ws + S2_OFF;
  float* t2    = ws + T2_OFF;
  float* s3    = ws + S3_OFF;
  float* t3    = ws + T3_OFF;
  float* fpsd  = ws + FPSD_OFF;
  int*   fpsc  = (int*)(ws + FPSC_OFF);
  float* outp  = (float*)d_out;

  hipMemsetAsync((void*)(ws + ACC_OFF), 0, 256*sizeof(float), stream);
  knn_fps_kernel<<<BB + BB*32, 256, 0, stream>>>(pos, idxg, fidxg, fpsd, fpsc);
  stats1_kernel<<<BB + BB*16, 256, 0, stream>>>(pos, idxg, w1, b1, acc1, fidxg, fpsd, fpsc);
  fold1_kernel<<<1, 512, 0, stream>>>(acc1, g1, be1, w2, b2, w2bf, b2f);
  conv2_kernel<<<BB + BB*16, 256, 0, stream>>>(pos, idxg, w1, b1, w2bf, b2f, maxh2, acc2, fidxg, fpsd, fpsc);
  fold2_kernel<<<1, 64, 0, stream>>>(acc2, g2, be2, s2, t2);
  head_kernel<<<BB*4, 256, 0, stream>>>(maxh2, fidxg, s2, t2, wnn1, bnn1, Y);
  bn3_kernel<<<2, 256, 0, stream>>>(Y, gbn2, bebn2, s3, t3);
  logits_kernel<<<BB, 256, 0, stream>>>(Y, s3, t3, wnn4, bnn4, outp);
}